// Round 4
// baseline (2140.628 us; speedup 1.0000x reference)
//
#include <hip/hip_runtime.h>
#include <cstdint>
#include <cstdio>

#define B_   8
#define L_   4096
#define DM_  1024
#define H_   16
#define D_   64
#define U_   45
#define BH_  (B_*H_)
#define ML_  (B_*L_)
#define NSPLIT 8

using f32x4  = __attribute__((ext_vector_type(4))) float;
using short8 = __attribute__((ext_vector_type(8))) short;

__device__ __forceinline__ unsigned short f2bf(float f) {
  uint32_t u = __float_as_uint(f);
  u += 0x7fffu + ((u >> 16) & 1u);      // RNE; inputs finite
  return (unsigned short)(u >> 16);
}
__device__ __forceinline__ float bf2f(unsigned short h) {
  return __uint_as_float(((uint32_t)h) << 16);
}

__device__ __forceinline__ void gload16(const void* g, void* l) {
  __builtin_amdgcn_global_load_lds((const __attribute__((address_space(1))) void*)g,
                                   (__attribute__((address_space(3))) void*)l,
                                   16, 0, 0);
}

struct Split3Args {
  const float* X[3];
  unsigned short* Hh[3];
  unsigned short* Ll[3];
};

// fused split: one batch (4M elems) of q,k,v -> bf16 hi/lo
__global__ __launch_bounds__(256) void split_x3(Split3Args A, int n4) {
  const int z = blockIdx.y;
  const float* __restrict__ X = A.X[z];
  unsigned short* __restrict__ Xh = A.Hh[z];
  unsigned short* __restrict__ Xl = A.Ll[z];
  int i = blockIdx.x * 256 + threadIdx.x;
  const int stride = gridDim.x * 256;
  for (; i < n4; i += stride) {
    const float4 v = ((const float4*)X)[i];
    ushort4 hv, lv;
    hv.x = f2bf(v.x); lv.x = f2bf(v.x - bf2f(hv.x));
    hv.y = f2bf(v.y); lv.y = f2bf(v.y - bf2f(hv.y));
    hv.z = f2bf(v.z); lv.z = f2bf(v.z - bf2f(hv.z));
    hv.w = f2bf(v.w); lv.w = f2bf(v.w - bf2f(hv.w));
    ((ushort4*)Xh)[i] = hv;
    ((ushort4*)Xl)[i] = lv;
  }
}

// W (K x N, row-major) -> W^T hi/lo (N x K, row-major)
__global__ __launch_bounds__(256) void split_wT(const float* __restrict__ W,
                                                unsigned short* __restrict__ WTh,
                                                unsigned short* __restrict__ WTl) {
  const int idx = blockIdx.x * 256 + threadIdx.x;   // 1M threads
  const int n = idx >> 10, k = idx & 1023;
  const float v = W[k * 1024 + n];
  const unsigned short h = f2bf(v);
  WTh[idx] = h;
  WTl[idx] = f2bf(v - bf2f(h));
}

struct Gemm3Args {
  const unsigned short* Ah[3];
  const unsigned short* Al[3];
  const unsigned short* Bh[3];
  const unsigned short* Bl[3];
  const float* bias[3];
  float* C[3];
};

// batched split-bf16 GEMM (3 products): C[z] = X[z]*W[z] + bias[z], M=4096
// grid (8, 32, 3) = 768 blocks; XCD-bijective swizzle (768 % 8 == 0)
__global__ __launch_bounds__(256) void gemm_split3(Gemm3Args P) {
  constexpr int K = 1024, N = 1024;
  const int flat = blockIdx.x + 8 * (blockIdx.y + 32 * blockIdx.z);  // 0..767
  const int swz = (flat & 7) * 96 + (flat >> 3);
  const int bx = swz & 7;
  const int tmp = swz >> 3;        // 0..95
  const int by = tmp & 31;
  const int bz = tmp >> 5;         // 0..2
  const unsigned short* __restrict__ Agh = P.Ah[bz];
  const unsigned short* __restrict__ Agl = P.Al[bz];
  const unsigned short* __restrict__ Bgh = P.Bh[bz];
  const unsigned short* __restrict__ Bgl = P.Bl[bz];
  const float* __restrict__ bias = P.bias[bz];
  float* __restrict__ C = P.C[bz];

  __shared__ unsigned short sA[2][128 * 32];
  __shared__ unsigned short sB[2][128 * 32];
  const int tid = threadIdx.x, wid = tid >> 6, lane = tid & 63;
  const int m0 = by * 128, n0 = bx * 128;
  const int wr = wid >> 1, wc = wid & 1;
  const int fr = lane & 15, fq = lane >> 4;
  const int srow = lane >> 2, scol = (lane & 3) * 8;
  f32x4 acc[4][4];
#pragma unroll
  for (int i = 0; i < 4; i++)
#pragma unroll
    for (int j = 0; j < 4; j++) acc[i][j] = f32x4{0.f, 0.f, 0.f, 0.f};

  for (int k0 = 0; k0 < K; k0 += 32) {
#pragma unroll
    for (int c = 0; c < 2; c++) {
      const int ch = wid * 2 + c;            // wave-uniform
      const int row = ch * 16 + srow;
      const size_t ga = (size_t)(m0 + row) * K + (k0 + scol);
      const size_t gb = (size_t)(n0 + row) * K + (k0 + scol);
      gload16(Agh + ga, &sA[0][ch * 512]);
      gload16(Agl + ga, &sA[1][ch * 512]);
      gload16(Bgh + gb, &sB[0][ch * 512]);
      gload16(Bgl + gb, &sB[1][ch * 512]);
    }
    __syncthreads();
    short8 ah[4], al[4], bh[4], bl[4];
#pragma unroll
    for (int i = 0; i < 4; i++) {
      ah[i] = *(const short8*)&sA[0][(wr * 64 + i * 16 + fr) * 32 + fq * 8];
      al[i] = *(const short8*)&sA[1][(wr * 64 + i * 16 + fr) * 32 + fq * 8];
      bh[i] = *(const short8*)&sB[0][(wc * 64 + i * 16 + fr) * 32 + fq * 8];
      bl[i] = *(const short8*)&sB[1][(wc * 64 + i * 16 + fr) * 32 + fq * 8];
    }
#pragma unroll
    for (int i = 0; i < 4; i++)
#pragma unroll
      for (int j = 0; j < 4; j++) {
        acc[i][j] = __builtin_amdgcn_mfma_f32_16x16x32_bf16(ah[i], bh[j], acc[i][j], 0, 0, 0);
        acc[i][j] = __builtin_amdgcn_mfma_f32_16x16x32_bf16(ah[i], bl[j], acc[i][j], 0, 0, 0);
        acc[i][j] = __builtin_amdgcn_mfma_f32_16x16x32_bf16(al[i], bh[j], acc[i][j], 0, 0, 0);
      }
    __syncthreads();
  }
#pragma unroll
  for (int j = 0; j < 4; j++) {
    const int col = n0 + wc * 64 + j * 16 + fr;
    const float bv = bias[col];
#pragma unroll
    for (int i = 0; i < 4; i++) {
      const int row = m0 + wr * 64 + i * 16 + fq * 4;
#pragma unroll
      for (int r = 0; r < 4; r++) C[(size_t)(row + r) * N + col] = acc[i][j][r] + bv;
    }
  }
}

// ---------------- exact fp32 sampled-K rows: Ksamp[bh][u][64] ----------------
__global__ __launch_bounds__(256) void ksel_k(const float* __restrict__ X,
    const float* __restrict__ Wk, const float* __restrict__ bk,
    const int* __restrict__ sidx, float* __restrict__ Ksamp) {
  const int bh = blockIdx.x, b = bh >> 4, h = bh & 15;
  __shared__ float Xs[1024];
  __shared__ float red[256];
  const int t = threadIdx.x, d = t & 63, p = t >> 6;
  for (int u = 0; u < U_; u++) {
    const int l = sidx[u];
    *(float4*)&Xs[t * 4] = *(const float4*)&X[((size_t)b * L_ + l) * DM_ + t * 4];
    __syncthreads();
    float acc = 0.f;
    const float* wp = Wk + (size_t)(p * 256) * DM_ + h * 64 + d;
    for (int i = 0; i < 256; i++) acc += Xs[p * 256 + i] * wp[(size_t)i * DM_];
    red[t] = acc;
    __syncthreads();
    if (p == 0)
      Ksamp[((size_t)bh * U_ + u) * 64 + d] =
          red[d] + red[64 + d] + red[128 + d] + red[192 + d] + bk[h * 64 + d];
    __syncthreads();
  }
}

// ---------------- M = max_u(QK_sample) - mean_u, one batch chunk ----------------
__global__ __launch_bounds__(256) void qk_sample_M(const float* __restrict__ Qc,
    const float* __restrict__ Ksamp, float* __restrict__ Mout, int b0) {
  const int h = blockIdx.x;
  const int bh = b0 * 16 + h;
  __shared__ float Qs[256][65];   // stride 65: conflict-free scalar reads
  __shared__ float Ks[U_][68];
  for (int e = threadIdx.x; e < U_ * 64; e += 256) {
    const int u = e >> 6, d = e & 63;
    Ks[u][d] = Ksamp[((size_t)bh * U_ + u) * 64 + d];
  }
  const int l0 = blockIdx.y * 256;
  for (int e = threadIdx.x; e < 256 * 64; e += 256) {
    const int r = e >> 6, d = e & 63;
    Qs[r][d] = Qc[((size_t)(l0 + r)) * DM_ + h * 64 + d];
  }
  __syncthreads();
  const int t = threadIdx.x;
  float acc[U_];
#pragma unroll
  for (int u = 0; u < U_; u++) acc[u] = 0.f;
  for (int d = 0; d < 64; d += 4) {
    const float q0 = Qs[t][d], q1 = Qs[t][d + 1], q2 = Qs[t][d + 2], q3 = Qs[t][d + 3];
#pragma unroll
    for (int u = 0; u < U_; u++) {
      const float4 kk = *(const float4*)&Ks[u][d];
      acc[u] += q0 * kk.x + q1 * kk.y + q2 * kk.z + q3 * kk.w;
    }
  }
  float mx = acc[0], sm = acc[0];
#pragma unroll
  for (int u = 1; u < U_; u++) { mx = fmaxf(mx, acc[u]); sm += acc[u]; }
  Mout[(size_t)bh * L_ + l0 + t] = mx - sm * (1.f / (float)U_);
}

// ---------------- top-45 per (b,h), lower-index tie-break ----------------
__global__ __launch_bounds__(256) void topk45(const float* __restrict__ Mbuf,
                                              int* __restrict__ topidx) {
  const int bh = blockIdx.x, t = threadIdx.x;
  __shared__ float vals[L_];
  __shared__ float rv[256];
  __shared__ int   ri[256];
  for (int i = t; i < L_; i += 256) vals[i] = Mbuf[(size_t)bh * L_ + i];
  __syncthreads();
  for (int it = 0; it < U_; it++) {
    float bv = vals[t * 16]; int bi = t * 16;
#pragma unroll
    for (int jj = 1; jj < 16; jj++) {
      const float v = vals[t * 16 + jj];
      if (v > bv) { bv = v; bi = t * 16 + jj; }
    }
    rv[t] = bv; ri[t] = bi;
    __syncthreads();
    for (int s = 128; s > 0; s >>= 1) {
      if (t < s) {
        if (rv[t + s] > rv[t] || (rv[t + s] == rv[t] && ri[t + s] < ri[t])) {
          rv[t] = rv[t + s]; ri[t] = ri[t + s];
        }
      }
      __syncthreads();
    }
    if (t == 0) { topidx[bh * U_ + it] = ri[0]; vals[ri[0]] = -3.4e38f; }
    __syncthreads();
  }
}

// ---------------- recompute selected Q rows: Qsel[bh][u][64] ----------------
__global__ __launch_bounds__(256) void qsel_k(const float* __restrict__ X,
    const float* __restrict__ Wq, const float* __restrict__ bq,
    const int* __restrict__ topidx, float* __restrict__ Qsel) {
  const int bh = blockIdx.x, b = bh >> 4, h = bh & 15;
  __shared__ float Xs[1024];
  __shared__ float red[256];
  const int t = threadIdx.x, d = t & 63, p = t >> 6;
  for (int u = 0; u < U_; u++) {
    const int l = topidx[bh * U_ + u];
    *(float4*)&Xs[t * 4] = *(const float4*)&X[((size_t)b * L_ + l) * DM_ + t * 4];
    __syncthreads();
    float acc = 0.f;
    const float* wp = Wq + (size_t)(p * 256) * DM_ + h * 64 + d;
    for (int i = 0; i < 256; i++) acc += Xs[p * 256 + i] * wp[(size_t)i * DM_];
    red[t] = acc;
    __syncthreads();
    if (p == 0)
      Qsel[((size_t)bh * U_ + u) * 64 + d] =
          red[d] + red[64 + d] + red[128 + d] + red[192 + d] + bq[h * 64 + d];
    __syncthreads();
  }
}

// ---------------- V mean: two-phase deterministic ----------------
__global__ __launch_bounds__(256) void vmean_partial(const float* __restrict__ Vf,
                                                     float* __restrict__ partial) {
  const int col = blockIdx.x * 256 + threadIdx.x;
  const int s = blockIdx.y, b = blockIdx.z;
  const float* src = Vf + ((size_t)b * L_ + s * 64) * DM_ + col;
  float acc = 0.f;
#pragma unroll 8
  for (int l = 0; l < 64; l++) acc += src[(size_t)l * DM_];
  partial[((size_t)b * 64 + s) * DM_ + col] = acc;
}
__global__ __launch_bounds__(256) void vmean_combine(const float* __restrict__ partial,
                                                     float* __restrict__ Vm) {
  const int idx = blockIdx.x * 256 + threadIdx.x;  // 8192 = B_*DM_
  const int b = idx >> 10, col = idx & 1023;
  float acc = 0.f;
  for (int s = 0; s < 64; s++) acc += partial[((size_t)b * 64 + s) * DM_ + col];
  Vm[idx] = acc * (1.f / (float)L_);
}

// ---------------- selected-row attention, no-max softmax, 8-way k-split ----------------
// |scores| <= |q||k|/8 ~ 1.4  => exp() safe without max subtraction (matches
// reference softmax exactly up to fp32 rounding).
__global__ __launch_bounds__(256) void attn_stage1(const float* __restrict__ Qsel,
    const float* __restrict__ Kf, const float* __restrict__ Vf, float* __restrict__ part) {
  const int bh = blockIdx.x, split = blockIdx.y;
  const int b = bh >> 4, h = bh & 15;
  __shared__ float Qs[48][64];        // broadcast reads: no padding needed
  __shared__ float Kt[64][68];
  __shared__ float es[4][64][12];     // 48B rows: float4-aligned, modest write conflicts
  for (int e = threadIdx.x; e < 48 * 64; e += 256) {
    const int u = e >> 6, d = e & 63;
    Qs[u][d] = (u < U_) ? Qsel[((size_t)bh * U_ + u) * 64 + d] : 0.f;
  }
  const int wid = threadIdx.x >> 6, lane = threadIdx.x & 63;
  float S[12], ctx[12];
#pragma unroll
  for (int i = 0; i < 12; i++) { S[i] = 0.f; ctx[i] = 0.f; }
  for (int t = 0; t < 8; t++) {
    const int k0 = split * 512 + t * 64;
    __syncthreads();
    for (int e = threadIdx.x; e < 64 * 16; e += 256) {
      const int r = e >> 4, c4 = (e & 15) * 4;
      *(float4*)&Kt[r][c4] = *(const float4*)&Kf[((size_t)b * L_ + k0 + r) * DM_ + h * 64 + c4];
    }
    __syncthreads();
    float sc[12];
#pragma unroll
    for (int i = 0; i < 12; i++) sc[i] = 0.f;
    for (int d4 = 0; d4 < 16; d4++) {
      const float4 kk = *(const float4*)&Kt[lane][d4 * 4];
#pragma unroll
      for (int i = 0; i < 12; i++) {
        const float4 q = *(const float4*)&Qs[wid + 4 * i][d4 * 4];
        sc[i] += q.x * kk.x + q.y * kk.y + q.z * kk.z + q.w * kk.w;
      }
    }
#pragma unroll
    for (int i = 0; i < 12; i++) {
      const float e = expf(sc[i] * 0.125f);    // 1/sqrt(64)
      float sum = e;
      for (int off = 32; off > 0; off >>= 1) sum += __shfl_xor(sum, off);
      S[i] += sum;
      es[wid][lane][i] = e;                    // wave-private: no barrier needed
    }
    const float* vbase = Vf + ((size_t)b * L_ + k0) * DM_ + h * 64 + lane;
#pragma unroll 4
    for (int k = 0; k < 64; k++) {
      const float v = vbase[(size_t)k * DM_];  // lane=d: coalesced 256B, L1/L2-hot
      const float4 e0 = *(const float4*)&es[wid][k][0];
      const float4 e1 = *(const float4*)&es[wid][k][4];
      const float4 e2 = *(const float4*)&es[wid][k][8];
      ctx[0] += e0.x * v; ctx[1] += e0.y * v; ctx[2]  += e0.z * v; ctx[3]  += e0.w * v;
      ctx[4] += e1.x * v; ctx[5] += e1.y * v; ctx[6]  += e1.z * v; ctx[7]  += e1.w * v;
      ctx[8] += e2.x * v; ctx[9] += e2.y * v; ctx[10] += e2.z * v; ctx[11] += e2.w * v;
    }
  }
#pragma unroll
  for (int i = 0; i < 12; i++) {
    const int u = wid + 4 * i;
    if (u < U_) {
      float* pb = part + ((size_t)(bh * NSPLIT + split) * U_ + u) * 65;
      if (lane == 0) pb[0] = S[i];
      pb[1 + lane] = ctx[i];
    }
  }
}

// combine splits (plain sums); dctx = ctx/S - Vmean
__global__ __launch_bounds__(256) void attn_stage2(const float* __restrict__ part,
    const float* __restrict__ Vm, float* __restrict__ dctx) {
  const int bh = blockIdx.x;
  const int wid = threadIdx.x >> 6, lane = threadIdx.x & 63;
  for (int u = wid; u < U_; u += 4) {
    float S = 0.f, c = 0.f;
#pragma unroll
    for (int sp = 0; sp < NSPLIT; sp++) {
      const float* pb = part + ((size_t)(bh * NSPLIT + sp) * U_ + u) * 65;
      S += pb[0];
      c += pb[1 + lane];
    }
    dctx[((size_t)bh * U_ + u) * 64 + lane] = c / S - Vm[bh * 64 + lane];
  }
}

// base[b][:] = concat_h(Vmean) @ Wo + bo
__global__ __launch_bounds__(256) void base_k(const float* __restrict__ Vm,
    const float* __restrict__ Wo, const float* __restrict__ bo, float* __restrict__ base) {
  const int b = blockIdx.y;
  const int j = blockIdx.x * 256 + threadIdx.x;
  float acc = bo[j];
#pragma unroll 8
  for (int i = 0; i < DM_; i++) acc += Vm[b * DM_ + i] * Wo[(size_t)i * DM_ + j];
  base[b * DM_ + j] = acc;
}

// out[b,l,:] = base[b,:]  (broadcast fill; overwrites Kf scratch)
__global__ __launch_bounds__(256) void fill_out(const float* __restrict__ base,
                                                float* __restrict__ out) {
  const size_t g = ((size_t)blockIdx.x * 256 + threadIdx.x) * 4;
  const int b = (int)(g >> 22), j = (int)(g & 1023);
  *(float4*)&out[g] = *(const float4*)&base[(b << 10) + j];
}

// out[b,l,:] += (ctx_upd - Vmean) @ Wo_block[h] for selected rows
__global__ __launch_bounds__(256) void scatter_k(const float* __restrict__ dctx,
    const float* __restrict__ Wo, const int* __restrict__ topidx, float* __restrict__ out) {
  const int bh = blockIdx.x, b = bh >> 4, h = bh & 15;
  __shared__ float dc[U_ * 64];
  __shared__ int topl[U_];
  for (int e = threadIdx.x; e < U_ * 64; e += 256) dc[e] = dctx[(size_t)bh * U_ * 64 + e];
  if (threadIdx.x < U_) topl[threadIdx.x] = topidx[bh * U_ + threadIdx.x];
  __syncthreads();
  const int j4 = threadIdx.x * 4;
  for (int up = 0; up < 6; up++) {
    f32x4 a[8];
#pragma unroll
    for (int i = 0; i < 8; i++) a[i] = f32x4{0.f, 0.f, 0.f, 0.f};
    for (int d = 0; d < 64; d++) {
      const float4 w = *(const float4*)&Wo[(size_t)(h * 64 + d) * DM_ + j4];
#pragma unroll
      for (int i = 0; i < 8; i++) {
        const int u = up * 8 + i;
        if (u < U_) {
          const float cc = dc[u * 64 + d];
          a[i].x += cc * w.x; a[i].y += cc * w.y; a[i].z += cc * w.z; a[i].w += cc * w.w;
        }
      }
    }
#pragma unroll
    for (int i = 0; i < 8; i++) {
      const int u = up * 8 + i;
      if (u < U_) {
        float* row = out + ((size_t)b * L_ + topl[u]) * DM_ + j4;
        atomicAdd(row + 0, a[i].x); atomicAdd(row + 1, a[i].y);
        atomicAdd(row + 2, a[i].z); atomicAdd(row + 3, a[i].w);
      }
    }
  }
}

extern "C" void kernel_launch(void* const* d_in, const int* in_sizes, int n_in,
                              void* d_out, int out_size, void* d_ws, size_t ws_size,
                              hipStream_t stream) {
  const float* queries = (const float*)d_in[0];
  const float* keys    = (const float*)d_in[1];
  const float* values  = (const float*)d_in[2];
  const float* Wq = (const float*)d_in[3]; const float* bq = (const float*)d_in[4];
  const float* Wk = (const float*)d_in[5]; const float* bk = (const float*)d_in[6];
  const float* Wv = (const float*)d_in[7]; const float* bv = (const float*)d_in[8];
  const float* Wo = (const float*)d_in[9]; const float* bo = (const float*)d_in[10];
  const int* sidx = (const int*)d_in[11];

  const size_t LDMsz = (size_t)L_ * DM_;            // 4M elems per batch
  uint8_t* p = (uint8_t*)d_ws;
  auto carve = [&](size_t bytes) { uint8_t* r = p; p += (bytes + 255) & ~(size_t)255; return r; };
  float* Kf = (float*)d_out;                         // K lives in d_out until epilogue

  float* Vf = (float*)carve((size_t)ML_ * DM_ * 4);                 // 134.2 MB
  uint8_t* xbase = (uint8_t*)carve(6 * LDMsz * 2);                  // 50.3 MB (6 split arrays)
  unsigned short* Sp[6];
  for (int i = 0; i < 6; i++) Sp[i] = (unsigned short*)(xbase + (size_t)i * LDMsz * 2);
  unsigned short* WTbuf = (unsigned short*)carve(6 * (size_t)DM_ * DM_ * 2);  // 12.6 MB
  unsigned short* WT[6];
  for (int i = 0; i < 6; i++) WT[i] = WTbuf + (size_t)i * DM_ * DM_;
  float* Qc    = (float*)carve(LDMsz * 4);                          // 16.8 MB
  float* Mbuf  = (float*)carve((size_t)BH_ * L_ * 4);               // 2 MB
  int*   topidx = (int*)carve((size_t)BH_ * U_ * 4);
  float* Vm    = (float*)carve((size_t)BH_ * 64 * 4);
  float* Ksamp = (float*)carve((size_t)BH_ * U_ * 64 * 4);          // 1.5 MB
  const size_t need = (size_t)(p - (uint8_t*)d_ws);
  if (ws_size < need)
    fprintf(stderr, "ATHENA_WS: need %zu have %zu (WILL FAULT)\n", need, ws_size);

  // post-GEMM buffers alias the (then-dead) split-array region
  uint8_t* ap = xbase;
  auto acarve = [&](size_t bytes) { uint8_t* r = ap; ap += (bytes + 255) & ~(size_t)255; return r; };
  float* Qsel  = (float*)acarve((size_t)BH_ * U_ * 64 * 4);                 // 1.5 MB
  float* part  = (float*)acarve((size_t)BH_ * NSPLIT * U_ * 65 * 4);        // 9.6 MB
  float* dctx  = (float*)acarve((size_t)BH_ * U_ * 64 * 4);                 // 1.5 MB
  float* vpart = (float*)acarve((size_t)B_ * 64 * DM_ * 4);                 // 2 MB
  float* base  = (float*)acarve((size_t)B_ * DM_ * 4);

  // exact sampled-K rows (input-only dependency)
  ksel_k<<<BH_, 256, 0, stream>>>(keys, Wk, bk, sidx, Ksamp);

  // weight splits: order {q,k,v}
  split_wT<<<4096, 256, 0, stream>>>(Wq, WT[0], WT[1]);
  split_wT<<<4096, 256, 0, stream>>>(Wk, WT[2], WT[3]);
  split_wT<<<4096, 256, 0, stream>>>(Wv, WT[4], WT[5]);

  const int n4 = (int)(LDMsz / 4);
  for (int b0 = 0; b0 < B_; b0++) {
    Split3Args SA;
    SA.X[0] = queries + (size_t)b0 * LDMsz;
    SA.X[1] = keys    + (size_t)b0 * LDMsz;
    SA.X[2] = values  + (size_t)b0 * LDMsz;
    for (int z = 0; z < 3; z++) { SA.Hh[z] = Sp[2 * z]; SA.Ll[z] = Sp[2 * z + 1]; }
    split_x3<<<dim3(512, 3), 256, 0, stream>>>(SA, n4);

    Gemm3Args GA;
    for (int z = 0; z < 3; z++) {
      GA.Ah[z] = Sp[2 * z]; GA.Al[z] = Sp[2 * z + 1];
      GA.Bh[z] = WT[2 * z]; GA.Bl[z] = WT[2 * z + 1];
    }
    GA.bias[0] = bq; GA.bias[1] = bk; GA.bias[2] = bv;
    GA.C[0] = Qc;
    GA.C[1] = Kf + (size_t)b0 * LDMsz;
    GA.C[2] = Vf + (size_t)b0 * LDMsz;
    gemm_split3<<<dim3(8, 32, 3), 256, 0, stream>>>(GA);

    qk_sample_M<<<dim3(16, L_ / 256), 256, 0, stream>>>(Qc, Ksamp, Mbuf, b0);
  }

  topk45<<<BH_, 256, 0, stream>>>(Mbuf, topidx);
  qsel_k<<<BH_, 256, 0, stream>>>(queries, Wq, bq, topidx, Qsel);
  vmean_partial<<<dim3(DM_ / 256, 64, B_), 256, 0, stream>>>(Vf, vpart);
  vmean_combine<<<(B_ * DM_) / 256, 256, 0, stream>>>(vpart, Vm);
  attn_stage1<<<dim3(BH_, NSPLIT), 256, 0, stream>>>(Qsel, Kf, Vf, part);
  attn_stage2<<<BH_, 256, 0, stream>>>(part, Vm, dctx);
  base_k<<<dim3(DM_ / 256, B_), 256, 0, stream>>>(Vm, Wo, bo, base);
  fill_out<<<(int)((size_t)ML_ * DM_ / 4 / 256), 256, 0, stream>>>(base, (float*)d_out);
  scatter_k<<<BH_, 256, 0, stream>>>(dctx, Wo, topidx, (float*)d_out);
}

// Round 5
// 1621.516 us; speedup vs baseline: 1.3201x; 1.3201x over previous
//
#include <hip/hip_runtime.h>
#include <cstdint>
#include <cstdio>

#define B_   8
#define L_   4096
#define DM_  1024
#define H_   16
#define D_   64
#define U_   45
#define BH_  (B_*H_)
#define ML_  (B_*L_)
#define NSPLIT 8
#define NP_  768           // padded QK-sample width: 16 heads * 48
#define CB_  4             // batches per chunk
#define CROWS_ (CB_*L_)    // 16384 rows per chunk

using f32x4   = __attribute__((ext_vector_type(4))) float;
using short8  = __attribute__((ext_vector_type(8))) short;
using ushort8 = __attribute__((ext_vector_type(8))) unsigned short;

__device__ __forceinline__ unsigned short f2bf(float f) {
  uint32_t u = __float_as_uint(f);
  u += 0x7fffu + ((u >> 16) & 1u);      // RNE; inputs finite
  return (unsigned short)(u >> 16);
}
__device__ __forceinline__ float bf2f(unsigned short h) {
  return __uint_as_float(((uint32_t)h) << 16);
}

__device__ __forceinline__ void gload16(const void* g, void* l) {
  __builtin_amdgcn_global_load_lds((const __attribute__((address_space(1))) void*)g,
                                   (__attribute__((address_space(3))) void*)l,
                                   16, 0, 0);
}

// ---------- split: q -> hi+lo; k,v -> hi only ----------
__global__ __launch_bounds__(256) void split4(const float* __restrict__ q,
    const float* __restrict__ k, const float* __restrict__ v,
    unsigned short* __restrict__ Xqh, unsigned short* __restrict__ Xql,
    unsigned short* __restrict__ Xkh, unsigned short* __restrict__ Xvh, int n4) {
  const int z = blockIdx.y;
  const float* __restrict__ X = (z == 0) ? q : ((z == 1) ? k : v);
  int i = blockIdx.x * 256 + threadIdx.x;
  const int stride = gridDim.x * 256;
  for (; i < n4; i += stride) {
    const float4 w = ((const float4*)X)[i];
    ushort4 hv;
    hv.x = f2bf(w.x); hv.y = f2bf(w.y); hv.z = f2bf(w.z); hv.w = f2bf(w.w);
    if (z == 0) {
      ushort4 lv;
      lv.x = f2bf(w.x - bf2f(hv.x)); lv.y = f2bf(w.y - bf2f(hv.y));
      lv.z = f2bf(w.z - bf2f(hv.z)); lv.w = f2bf(w.w - bf2f(hv.w));
      ((ushort4*)Xqh)[i] = hv;
      ((ushort4*)Xql)[i] = lv;
    } else if (z == 1) {
      ((ushort4*)Xkh)[i] = hv;
    } else {
      ((ushort4*)Xvh)[i] = hv;
    }
  }
}

// ---------- W (KxN) -> W^T bf16 (NxK) ----------
__global__ __launch_bounds__(256) void wT_single(const float* __restrict__ W,
                                                 unsigned short* __restrict__ WT) {
  const int idx = blockIdx.x * 256 + threadIdx.x;   // 1M threads
  const int n = idx >> 10, kk = idx & 1023;
  WT[idx] = f2bf(W[kk * 1024 + n]);
}

// ---------- plain bf16 GEMM, bf16 out: C = bf16(X*W + bias) ----------
__global__ __launch_bounds__(256) void gemm_plain(const unsigned short* __restrict__ Agh,
    const unsigned short* __restrict__ Bgh, const float* __restrict__ bias,
    unsigned short* __restrict__ C) {
  constexpr int K = 1024, N = 1024;
  __shared__ unsigned short sA[128 * 32];
  __shared__ unsigned short sB[128 * 32];
  const int tid = threadIdx.x, wid = tid >> 6, lane = tid & 63;
  const int m0 = blockIdx.y * 128, n0 = blockIdx.x * 128;
  const int wr = wid >> 1, wc = wid & 1;
  const int fr = lane & 15, fq = lane >> 4;
  const int srow = lane >> 2, scol = (lane & 3) * 8;
  f32x4 acc[4][4];
#pragma unroll
  for (int i = 0; i < 4; i++)
#pragma unroll
    for (int j = 0; j < 4; j++) acc[i][j] = f32x4{0.f, 0.f, 0.f, 0.f};

  for (int k0 = 0; k0 < K; k0 += 32) {
#pragma unroll
    for (int c = 0; c < 2; c++) {
      const int ch = wid * 2 + c;
      const int row = ch * 16 + srow;
      gload16(Agh + (size_t)(m0 + row) * K + (k0 + scol), &sA[ch * 512]);
      gload16(Bgh + (size_t)(n0 + row) * K + (k0 + scol), &sB[ch * 512]);
    }
    __syncthreads();
    short8 ah[4], bh[4];
#pragma unroll
    for (int i = 0; i < 4; i++) {
      ah[i] = *(const short8*)&sA[(wr * 64 + i * 16 + fr) * 32 + fq * 8];
      bh[i] = *(const short8*)&sB[(wc * 64 + i * 16 + fr) * 32 + fq * 8];
    }
#pragma unroll
    for (int i = 0; i < 4; i++)
#pragma unroll
      for (int j = 0; j < 4; j++)
        acc[i][j] = __builtin_amdgcn_mfma_f32_16x16x32_bf16(ah[i], bh[j], acc[i][j], 0, 0, 0);
    __syncthreads();
  }
#pragma unroll
  for (int j = 0; j < 4; j++) {
    const int col = n0 + wc * 64 + j * 16 + fr;
    const float bv = bias[col];
#pragma unroll
    for (int i = 0; i < 4; i++) {
      const int row = m0 + wr * 64 + i * 16 + fq * 4;
#pragma unroll
      for (int r = 0; r < 4; r++) C[(size_t)(row + r) * N + col] = f2bf(acc[i][j][r] + bv);
    }
  }
}

// ---------- split-3 GEMM: QKs = Xq * P_b  (fp32 out, N=768, per-batch B) ----------
__global__ __launch_bounds__(256) void gemm_qk3(const unsigned short* __restrict__ Agh,
    const unsigned short* __restrict__ Agl, const unsigned short* __restrict__ Pall_h,
    const unsigned short* __restrict__ Pall_l, float* __restrict__ C, int chunk) {
  constexpr int K = 1024;
  __shared__ unsigned short sA[2][128 * 32];
  __shared__ unsigned short sB[2][128 * 32];
  const int tid = threadIdx.x, wid = tid >> 6, lane = tid & 63;
  const int m0 = blockIdx.y * 128, n0 = blockIdx.x * 128;
  const int batch = chunk * CB_ + (blockIdx.y >> 5);
  const unsigned short* __restrict__ Bgh = Pall_h + (size_t)batch * NP_ * K;
  const unsigned short* __restrict__ Bgl = Pall_l + (size_t)batch * NP_ * K;
  const int wr = wid >> 1, wc = wid & 1;
  const int fr = lane & 15, fq = lane >> 4;
  const int srow = lane >> 2, scol = (lane & 3) * 8;
  f32x4 acc[4][4];
#pragma unroll
  for (int i = 0; i < 4; i++)
#pragma unroll
    for (int j = 0; j < 4; j++) acc[i][j] = f32x4{0.f, 0.f, 0.f, 0.f};

  for (int k0 = 0; k0 < K; k0 += 32) {
#pragma unroll
    for (int c = 0; c < 2; c++) {
      const int ch = wid * 2 + c;
      const int row = ch * 16 + srow;
      const size_t ga = (size_t)(m0 + row) * K + (k0 + scol);
      const size_t gb = (size_t)(n0 + row) * K + (k0 + scol);
      gload16(Agh + ga, &sA[0][ch * 512]);
      gload16(Agl + ga, &sA[1][ch * 512]);
      gload16(Bgh + gb, &sB[0][ch * 512]);
      gload16(Bgl + gb, &sB[1][ch * 512]);
    }
    __syncthreads();
    short8 ah[4], al[4], bh[4], bl[4];
#pragma unroll
    for (int i = 0; i < 4; i++) {
      ah[i] = *(const short8*)&sA[0][(wr * 64 + i * 16 + fr) * 32 + fq * 8];
      al[i] = *(const short8*)&sA[1][(wr * 64 + i * 16 + fr) * 32 + fq * 8];
      bh[i] = *(const short8*)&sB[0][(wc * 64 + i * 16 + fr) * 32 + fq * 8];
      bl[i] = *(const short8*)&sB[1][(wc * 64 + i * 16 + fr) * 32 + fq * 8];
    }
#pragma unroll
    for (int i = 0; i < 4; i++)
#pragma unroll
      for (int j = 0; j < 4; j++) {
        acc[i][j] = __builtin_amdgcn_mfma_f32_16x16x32_bf16(ah[i], bh[j], acc[i][j], 0, 0, 0);
        acc[i][j] = __builtin_amdgcn_mfma_f32_16x16x32_bf16(ah[i], bl[j], acc[i][j], 0, 0, 0);
        acc[i][j] = __builtin_amdgcn_mfma_f32_16x16x32_bf16(al[i], bh[j], acc[i][j], 0, 0, 0);
      }
    __syncthreads();
  }
#pragma unroll
  for (int j = 0; j < 4; j++) {
    const int col = n0 + wc * 64 + j * 16 + fr;
#pragma unroll
    for (int i = 0; i < 4; i++) {
      const int row = m0 + wr * 64 + i * 16 + fq * 4;
#pragma unroll
      for (int r = 0; r < 4; r++) C[(size_t)(row + r) * NP_ + col] = acc[i][j][r];
    }
  }
}

// ---------- exact fp32 sampled-K rows: Ksamp[bh][u][64] ----------
__global__ __launch_bounds__(256) void ksel_k(const float* __restrict__ X,
    const float* __restrict__ Wk, const float* __restrict__ bk,
    const int* __restrict__ sidx, float* __restrict__ Ksamp) {
  const int bh = blockIdx.x, b = bh >> 4, h = bh & 15;
  __shared__ float Xs[1024];
  __shared__ float red[256];
  const int t = threadIdx.x, d = t & 63, p = t >> 6;
  for (int u = 0; u < U_; u++) {
    const int l = sidx[u];
    *(float4*)&Xs[t * 4] = *(const float4*)&X[((size_t)b * L_ + l) * DM_ + t * 4];
    __syncthreads();
    float acc = 0.f;
    const float* wp = Wk + (size_t)(p * 256) * DM_ + h * 64 + d;
    for (int i = 0; i < 256; i++) acc += Xs[p * 256 + i] * wp[(size_t)i * DM_];
    red[t] = acc;
    __syncthreads();
    if (p == 0)
      Ksamp[((size_t)bh * U_ + u) * 64 + d] =
          red[d] + red[64 + d] + red[128 + d] + red[192 + d] + bk[h * 64 + d];
    __syncthreads();
  }
}

// ---------- P^T[b][n=h*48+u][k] = sum_d Wq[k][h*64+d]*Ksamp[b][h][u][d], split hi/lo ---
__global__ __launch_bounds__(256) void pform_k(const float* __restrict__ Wq,
    const float* __restrict__ Ksamp, unsigned short* __restrict__ Ph,
    unsigned short* __restrict__ Pl) {
  const int bh = blockIdx.x, b = bh >> 4, h = bh & 15;
  __shared__ float Ks[U_][68];
  const int t = threadIdx.x;
  for (int e = t; e < U_ * 64; e += 256) {
    const int u = e >> 6, d = e & 63;
    Ks[u][d] = Ksamp[((size_t)bh * U_ + u) * 64 + d];
  }
  __syncthreads();
  for (int kc = 0; kc < 4; kc++) {
    const int k = kc * 256 + t;
    float wr[64];
#pragma unroll
    for (int dd = 0; dd < 16; dd++) {
      const float4 w4 = *(const float4*)&Wq[(size_t)k * DM_ + h * 64 + dd * 4];
      wr[dd * 4 + 0] = w4.x; wr[dd * 4 + 1] = w4.y;
      wr[dd * 4 + 2] = w4.z; wr[dd * 4 + 3] = w4.w;
    }
    for (int u = 0; u < 48; u++) {
      size_t o = ((size_t)b * NP_ + h * 48 + u) * 1024 + k;
      if (u < U_) {
        float acc = 0.f;
#pragma unroll
        for (int d = 0; d < 64; d++) acc += wr[d] * Ks[u][d];
        const unsigned short hi = f2bf(acc);
        Ph[o] = hi;
        Pl[o] = f2bf(acc - bf2f(hi));
      } else {
        Ph[o] = 0; Pl[o] = 0;
      }
    }
  }
}

// ---------- M = max - mean over u of QKs ----------
__global__ __launch_bounds__(256) void mpass_k(const float* __restrict__ QKs,
                                               float* __restrict__ Mbuf, int chunk) {
  const int idx = blockIdx.x * 256 + threadIdx.x;   // < CROWS_*16
  const int ll = idx >> 4, h = idx & 15;
  const float* row = QKs + (size_t)ll * NP_ + h * 48;
  float mx = row[0], sm = row[0];
#pragma unroll
  for (int u = 1; u < U_; u++) { const float v = row[u]; mx = fmaxf(mx, v); sm += v; }
  const int lg = chunk * CROWS_ + ll;
  const int b = lg >> 12, l = lg & 4095;
  Mbuf[((size_t)(b * 16 + h)) * L_ + l] = mx - sm * (1.f / (float)U_);
}

// ---------- top-45 per (b,h), lower-index tie-break ----------
__global__ __launch_bounds__(256) void topk45(const float* __restrict__ Mbuf,
                                              int* __restrict__ topidx) {
  const int bh = blockIdx.x, t = threadIdx.x;
  __shared__ float vals[L_];
  __shared__ float rv[256];
  __shared__ int   ri[256];
  for (int i = t; i < L_; i += 256) vals[i] = Mbuf[(size_t)bh * L_ + i];
  __syncthreads();
  for (int it = 0; it < U_; it++) {
    float bv = vals[t * 16]; int bi = t * 16;
#pragma unroll
    for (int jj = 1; jj < 16; jj++) {
      const float v = vals[t * 16 + jj];
      if (v > bv) { bv = v; bi = t * 16 + jj; }
    }
    rv[t] = bv; ri[t] = bi;
    __syncthreads();
    for (int s = 128; s > 0; s >>= 1) {
      if (t < s) {
        if (rv[t + s] > rv[t] || (rv[t + s] == rv[t] && ri[t + s] < ri[t])) {
          rv[t] = rv[t + s]; ri[t] = ri[t + s];
        }
      }
      __syncthreads();
    }
    if (t == 0) { topidx[bh * U_ + it] = ri[0]; vals[ri[0]] = -3.4e38f; }
    __syncthreads();
  }
}

// ---------- recompute selected Q rows exactly: Qsel[bh][u][64] ----------
__global__ __launch_bounds__(256) void qsel_k(const float* __restrict__ X,
    const float* __restrict__ Wq, const float* __restrict__ bq,
    const int* __restrict__ topidx, float* __restrict__ Qsel) {
  const int bh = blockIdx.x, b = bh >> 4, h = bh & 15;
  __shared__ float Xs[1024];
  __shared__ float red[256];
  const int t = threadIdx.x, d = t & 63, p = t >> 6;
  for (int u = 0; u < U_; u++) {
    const int l = topidx[bh * U_ + u];
    *(float4*)&Xs[t * 4] = *(const float4*)&X[((size_t)b * L_ + l) * DM_ + t * 4];
    __syncthreads();
    float acc = 0.f;
    const float* wp = Wq + (size_t)(p * 256) * DM_ + h * 64 + d;
    for (int i = 0; i < 256; i++) acc += Xs[p * 256 + i] * wp[(size_t)i * DM_];
    red[t] = acc;
    __syncthreads();
    if (p == 0)
      Qsel[((size_t)bh * U_ + u) * 64 + d] =
          red[d] + red[64 + d] + red[128 + d] + red[192 + d] + bq[h * 64 + d];
    __syncthreads();
  }
}

// ---------- V mean from bf16 V: two-phase deterministic ----------
__global__ __launch_bounds__(256) void vmean_partial(const unsigned short* __restrict__ Vbf,
                                                     float* __restrict__ partial) {
  const int col = blockIdx.x * 256 + threadIdx.x;
  const int s = blockIdx.y, b = blockIdx.z;
  const unsigned short* src = Vbf + ((size_t)b * L_ + s * 64) * DM_ + col;
  float acc = 0.f;
#pragma unroll 8
  for (int l = 0; l < 64; l++) acc += bf2f(src[(size_t)l * DM_]);
  partial[((size_t)b * 64 + s) * DM_ + col] = acc;
}
__global__ __launch_bounds__(256) void vmean_combine(const float* __restrict__ partial,
                                                     float* __restrict__ Vm) {
  const int idx = blockIdx.x * 256 + threadIdx.x;  // 8192
  const int b = idx >> 10, col = idx & 1023;
  float acc = 0.f;
  for (int s = 0; s < 64; s++) acc += partial[((size_t)b * 64 + s) * DM_ + col];
  Vm[idx] = acc * (1.f / (float)L_);
}

// ---------- selected-row attention over bf16 K/V, no-max softmax ----------
__global__ __launch_bounds__(256) void attn_stage1(const float* __restrict__ Qsel,
    const unsigned short* __restrict__ Kbf, const unsigned short* __restrict__ Vbf,
    float* __restrict__ part) {
  const int bh = blockIdx.x, split = blockIdx.y;
  const int b = bh >> 4, h = bh & 15;
  __shared__ float Qs[48][64];
  __shared__ float Kt[64][68];
  __shared__ float es[4][64][12];
  for (int e = threadIdx.x; e < 48 * 64; e += 256) {
    const int u = e >> 6, d = e & 63;
    Qs[u][d] = (u < U_) ? Qsel[((size_t)bh * U_ + u) * 64 + d] : 0.f;
  }
  const int wid = threadIdx.x >> 6, lane = threadIdx.x & 63;
  float S[12], ctx[12];
#pragma unroll
  for (int i = 0; i < 12; i++) { S[i] = 0.f; ctx[i] = 0.f; }
  for (int t = 0; t < 8; t++) {
    const int k0 = split * 512 + t * 64;
    __syncthreads();
    for (int e = threadIdx.x; e < 64 * 8; e += 256) {
      const int r = e >> 3, c8 = (e & 7) * 8;
      const ushort8 kv = *(const ushort8*)&Kbf[((size_t)b * L_ + k0 + r) * DM_ + h * 64 + c8];
#pragma unroll
      for (int x = 0; x < 8; x++) Kt[r][c8 + x] = bf2f(kv[x]);
    }
    __syncthreads();
    float sc[12];
#pragma unroll
    for (int i = 0; i < 12; i++) sc[i] = 0.f;
    for (int d4 = 0; d4 < 16; d4++) {
      const float4 kk = *(const float4*)&Kt[lane][d4 * 4];
#pragma unroll
      for (int i = 0; i < 12; i++) {
        const float4 q = *(const float4*)&Qs[wid + 4 * i][d4 * 4];
        sc[i] += q.x * kk.x + q.y * kk.y + q.z * kk.z + q.w * kk.w;
      }
    }
#pragma unroll
    for (int i = 0; i < 12; i++) {
      const float e = expf(sc[i] * 0.125f);    // |s|<=1.4: no max needed
      float sum = e;
      for (int off = 32; off > 0; off >>= 1) sum += __shfl_xor(sum, off);
      S[i] += sum;
      es[wid][lane][i] = e;                    // wave-private
    }
    const unsigned short* vbase = Vbf + ((size_t)b * L_ + k0) * DM_ + h * 64 + lane;
#pragma unroll 4
    for (int k = 0; k < 64; k++) {
      const float v = bf2f(vbase[(size_t)k * DM_]);
      const float4 e0 = *(const float4*)&es[wid][k][0];
      const float4 e1 = *(const float4*)&es[wid][k][4];
      const float4 e2 = *(const float4*)&es[wid][k][8];
      ctx[0] += e0.x * v; ctx[1] += e0.y * v; ctx[2]  += e0.z * v; ctx[3]  += e0.w * v;
      ctx[4] += e1.x * v; ctx[5] += e1.y * v; ctx[6]  += e1.z * v; ctx[7]  += e1.w * v;
      ctx[8] += e2.x * v; ctx[9] += e2.y * v; ctx[10] += e2.z * v; ctx[11] += e2.w * v;
    }
  }
#pragma unroll
  for (int i = 0; i < 12; i++) {
    const int u = wid + 4 * i;
    if (u < U_) {
      float* pb = part + ((size_t)(bh * NSPLIT + split) * U_ + u) * 65;
      if (lane == 0) pb[0] = S[i];
      pb[1 + lane] = ctx[i];
    }
  }
}

// ---------- combine splits; dctx = ctx/S - Vmean ----------
__global__ __launch_bounds__(256) void attn_stage2(const float* __restrict__ part,
    const float* __restrict__ Vm, float* __restrict__ dctx) {
  const int bh = blockIdx.x;
  const int wid = threadIdx.x >> 6, lane = threadIdx.x & 63;
  for (int u = wid; u < U_; u += 4) {
    float S = 0.f, c = 0.f;
#pragma unroll
    for (int sp = 0; sp < NSPLIT; sp++) {
      const float* pb = part + ((size_t)(bh * NSPLIT + sp) * U_ + u) * 65;
      S += pb[0];
      c += pb[1 + lane];
    }
    dctx[((size_t)bh * U_ + u) * 64 + lane] = c / S - Vm[bh * 64 + lane];
  }
}

// ---------- base[b][:] = concat_h(Vmean) @ Wo + bo ----------
__global__ __launch_bounds__(256) void base_k(const float* __restrict__ Vm,
    const float* __restrict__ Wo, const float* __restrict__ bo, float* __restrict__ base) {
  const int b = blockIdx.y;
  const int j = blockIdx.x * 256 + threadIdx.x;
  float acc = bo[j];
#pragma unroll 8
  for (int i = 0; i < DM_; i++) acc += Vm[b * DM_ + i] * Wo[(size_t)i * DM_ + j];
  base[b * DM_ + j] = acc;
}

// ---------- out[b,l,:] = base[b,:] ----------
__global__ __launch_bounds__(256) void fill_out(const float* __restrict__ base,
                                                float* __restrict__ out) {
  const size_t g = ((size_t)blockIdx.x * 256 + threadIdx.x) * 4;
  const int b = (int)(g >> 22), j = (int)(g & 1023);
  *(float4*)&out[g] = *(const float4*)&base[(b << 10) + j];
}

// ---------- out += (ctx-Vmean) @ Wo_block[h] on selected rows ----------
__global__ __launch_bounds__(256) void scatter_k(const float* __restrict__ dctx,
    const float* __restrict__ Wo, const int* __restrict__ topidx, float* __restrict__ out) {
  const int bh = blockIdx.x, b = bh >> 4, h = bh & 15;
  __shared__ float dc[U_ * 64];
  __shared__ int topl[U_];
  for (int e = threadIdx.x; e < U_ * 64; e += 256) dc[e] = dctx[(size_t)bh * U_ * 64 + e];
  if (threadIdx.x < U_) topl[threadIdx.x] = topidx[bh * U_ + threadIdx.x];
  __syncthreads();
  const int j4 = threadIdx.x * 4;
  for (int up = 0; up < 6; up++) {
    f32x4 a[8];
#pragma unroll
    for (int i = 0; i < 8; i++) a[i] = f32x4{0.f, 0.f, 0.f, 0.f};
    for (int d = 0; d < 64; d++) {
      const float4 w = *(const float4*)&Wo[(size_t)(h * 64 + d) * DM_ + j4];
#pragma unroll
      for (int i = 0; i < 8; i++) {
        const int u = up * 8 + i;
        if (u < U_) {
          const float cc = dc[u * 64 + d];
          a[i].x += cc * w.x; a[i].y += cc * w.y; a[i].z += cc * w.z; a[i].w += cc * w.w;
        }
      }
    }
#pragma unroll
    for (int i = 0; i < 8; i++) {
      const int u = up * 8 + i;
      if (u < U_) {
        float* row = out + ((size_t)b * L_ + topl[u]) * DM_ + j4;
        atomicAdd(row + 0, a[i].x); atomicAdd(row + 1, a[i].y);
        atomicAdd(row + 2, a[i].z); atomicAdd(row + 3, a[i].w);
      }
    }
  }
}

extern "C" void kernel_launch(void* const* d_in, const int* in_sizes, int n_in,
                              void* d_out, int out_size, void* d_ws, size_t ws_size,
                              hipStream_t stream) {
  const float* queries = (const float*)d_in[0];
  const float* keys    = (const float*)d_in[1];
  const float* values  = (const float*)d_in[2];
  const float* Wq = (const float*)d_in[3]; const float* bq = (const float*)d_in[4];
  const float* Wk = (const float*)d_in[5]; const float* bk = (const float*)d_in[6];
  const float* Wv = (const float*)d_in[7]; const float* bv = (const float*)d_in[8];
  const float* Wo = (const float*)d_in[9]; const float* bo = (const float*)d_in[10];
  const int* sidx = (const int*)d_in[11];

  // K,V live as bf16 in d_out (67.1 MB each) until the epilogue
  unsigned short* Kbf = (unsigned short*)d_out;
  unsigned short* Vbf = Kbf + (size_t)ML_ * DM_;

  uint8_t* p = (uint8_t*)d_ws;
  auto carve = [&](size_t bytes) { uint8_t* r = p; p += (bytes + 255) & ~(size_t)255; return r; };
  unsigned short* Xqh = (unsigned short*)carve((size_t)CROWS_ * DM_ * 2);   // 33.6 MB
  unsigned short* Xql = (unsigned short*)carve((size_t)CROWS_ * DM_ * 2);
  unsigned short* Xkh = (unsigned short*)carve((size_t)CROWS_ * DM_ * 2);
  unsigned short* Xvh = (unsigned short*)carve((size_t)CROWS_ * DM_ * 2);
  float* QKs = (float*)carve((size_t)CROWS_ * NP_ * 4);                     // 50.3 MB
  unsigned short* Ph = (unsigned short*)carve((size_t)B_ * NP_ * DM_ * 2);  // 12.6 MB
  unsigned short* Pl = (unsigned short*)carve((size_t)B_ * NP_ * DM_ * 2);
  unsigned short* WkT = (unsigned short*)carve((size_t)DM_ * DM_ * 2);
  unsigned short* WvT = (unsigned short*)carve((size_t)DM_ * DM_ * 2);
  float* Mbuf  = (float*)carve((size_t)BH_ * L_ * 4);                       // 2.1 MB
  float* Ksamp = (float*)carve((size_t)BH_ * U_ * 64 * 4);                  // 1.5 MB
  int*   topidx = (int*)carve((size_t)BH_ * U_ * 4);
  float* Vm    = (float*)carve((size_t)BH_ * 64 * 4);
  const size_t need = (size_t)(p - (uint8_t*)d_ws);
  if (ws_size < need)
    fprintf(stderr, "ATHENA_WS: need %zu have %zu (WILL FAULT)\n", need, ws_size);

  // late-phase buffers alias QKs (dead after mpass)
  uint8_t* ap = (uint8_t*)QKs;
  auto acarve = [&](size_t bytes) { uint8_t* r = ap; ap += (bytes + 255) & ~(size_t)255; return r; };
  float* Qsel  = (float*)acarve((size_t)BH_ * U_ * 64 * 4);
  float* part  = (float*)acarve((size_t)BH_ * NSPLIT * U_ * 65 * 4);        // 12 MB
  float* dctx  = (float*)acarve((size_t)BH_ * U_ * 64 * 4);
  float* vpart = (float*)acarve((size_t)B_ * 64 * DM_ * 4);                 // 2.1 MB
  float* base  = (float*)acarve((size_t)B_ * DM_ * 4);

  // exact sampled-K rows, then P = Wq @ Ksamp^T (split hi/lo)
  ksel_k<<<BH_, 256, 0, stream>>>(keys, Wk, bk, sidx, Ksamp);
  pform_k<<<BH_, 256, 0, stream>>>(Wq, Ksamp, Ph, Pl);
  wT_single<<<4096, 256, 0, stream>>>(Wk, WkT);
  wT_single<<<4096, 256, 0, stream>>>(Wv, WvT);

  const int n4 = (int)((size_t)CROWS_ * DM_ / 4);
  for (int c = 0; c < 2; c++) {
    const size_t off = (size_t)c * CROWS_ * DM_;
    split4<<<dim3(2048, 3), 256, 0, stream>>>(queries + off, keys + off, values + off,
                                              Xqh, Xql, Xkh, Xvh, n4);
    gemm_plain<<<dim3(8, 128), 256, 0, stream>>>(Xkh, WkT, bk, Kbf + off);
    gemm_plain<<<dim3(8, 128), 256, 0, stream>>>(Xvh, WvT, bv, Vbf + off);
    gemm_qk3<<<dim3(6, 128), 256, 0, stream>>>(Xqh, Xql, Ph, Pl, QKs, c);
    mpass_k<<<(CROWS_ * 16) / 256, 256, 0, stream>>>(QKs, Mbuf, c);
  }

  topk45<<<BH_, 256, 0, stream>>>(Mbuf, topidx);
  qsel_k<<<BH_, 256, 0, stream>>>(queries, Wq, bq, topidx, Qsel);
  vmean_partial<<<dim3(DM_ / 256, 64, B_), 256, 0, stream>>>(Vbf, vpart);
  vmean_combine<<<(B_ * DM_) / 256, 256, 0, stream>>>(vpart, Vm);
  attn_stage1<<<dim3(BH_, NSPLIT), 256, 0, stream>>>(Qsel, Kbf, Vbf, part);
  attn_stage2<<<BH_, 256, 0, stream>>>(part, Vm, dctx);
  base_k<<<dim3(DM_ / 256, B_), 256, 0, stream>>>(Vm, Wo, bo, base);
  fill_out<<<(int)((size_t)ML_ * DM_ / 4 / 256), 256, 0, stream>>>(base, (float*)d_out);
  scatter_k<<<BH_, 256, 0, stream>>>(dctx, Wo, topidx, (float*)d_out);
}

// Round 6
// 1513.347 us; speedup vs baseline: 1.4145x; 1.0715x over previous
//
#include <hip/hip_runtime.h>
#include <cstdint>
#include <cstdio>

#define B_   8
#define L_   4096
#define DM_  1024
#define H_   16
#define D_   64
#define U_   45
#define BH_  (B_*H_)
#define ML_  (B_*L_)
#define NSPLIT 8
#define NP_  768           // padded QK-sample width: 16 heads * 48
#define CB_  4             // batches per chunk
#define CROWS_ (CB_*L_)    // 16384 rows per chunk
#define CAP_ 512           // candidate cap per (b,h)
#define DELTA_ 0.12f       // exact-recompute band (~9 sigma of bf16 GEMM err)

using f32x4   = __attribute__((ext_vector_type(4))) float;
using short8  = __attribute__((ext_vector_type(8))) short;
using ushort8 = __attribute__((ext_vector_type(8))) unsigned short;

__device__ __forceinline__ unsigned short f2bf(float f) {
  uint32_t u = __float_as_uint(f);
  u += 0x7fffu + ((u >> 16) & 1u);      // RNE; inputs finite
  return (unsigned short)(u >> 16);
}
__device__ __forceinline__ float bf2f(unsigned short h) {
  return __uint_as_float(((uint32_t)h) << 16);
}

__device__ __forceinline__ void gload16(const void* g, void* l) {
  __builtin_amdgcn_global_load_lds((const __attribute__((address_space(1))) void*)g,
                                   (__attribute__((address_space(3))) void*)l,
                                   16, 0, 0);
}

// ---------- split: q,k,v -> bf16 hi only ----------
__global__ __launch_bounds__(256) void split3h(const float* __restrict__ q,
    const float* __restrict__ k, const float* __restrict__ v,
    unsigned short* __restrict__ Xqh, unsigned short* __restrict__ Xkh,
    unsigned short* __restrict__ Xvh, int n4) {
  const int z = blockIdx.y;
  const float* __restrict__ X = (z == 0) ? q : ((z == 1) ? k : v);
  unsigned short* __restrict__ O = (z == 0) ? Xqh : ((z == 1) ? Xkh : Xvh);
  int i = blockIdx.x * 256 + threadIdx.x;
  const int stride = gridDim.x * 256;
  for (; i < n4; i += stride) {
    const float4 w = ((const float4*)X)[i];
    ushort4 hv;
    hv.x = f2bf(w.x); hv.y = f2bf(w.y); hv.z = f2bf(w.z); hv.w = f2bf(w.w);
    ((ushort4*)O)[i] = hv;
  }
}

// ---------- W (KxN) -> W^T bf16 (NxK) ----------
__global__ __launch_bounds__(256) void wT_single(const float* __restrict__ W,
                                                 unsigned short* __restrict__ WT) {
  const int idx = blockIdx.x * 256 + threadIdx.x;   // 1M threads
  const int n = idx >> 10, kk = idx & 1023;
  WT[idx] = f2bf(W[kk * 1024 + n]);
}

// ---------- plain bf16 GEMM, bf16 out: C = bf16(X*W + bias) ----------
__global__ __launch_bounds__(256) void gemm_plain(const unsigned short* __restrict__ Agh,
    const unsigned short* __restrict__ Bgh, const float* __restrict__ bias,
    unsigned short* __restrict__ C) {
  constexpr int K = 1024, N = 1024;
  __shared__ unsigned short sA[128 * 32];
  __shared__ unsigned short sB[128 * 32];
  const int tid = threadIdx.x, wid = tid >> 6, lane = tid & 63;
  const int m0 = blockIdx.y * 128, n0 = blockIdx.x * 128;
  const int wr = wid >> 1, wc = wid & 1;
  const int fr = lane & 15, fq = lane >> 4;
  const int srow = lane >> 2, scol = (lane & 3) * 8;
  f32x4 acc[4][4];
#pragma unroll
  for (int i = 0; i < 4; i++)
#pragma unroll
    for (int j = 0; j < 4; j++) acc[i][j] = f32x4{0.f, 0.f, 0.f, 0.f};

  for (int k0 = 0; k0 < K; k0 += 32) {
#pragma unroll
    for (int c = 0; c < 2; c++) {
      const int ch = wid * 2 + c;
      const int row = ch * 16 + srow;
      gload16(Agh + (size_t)(m0 + row) * K + (k0 + scol), &sA[ch * 512]);
      gload16(Bgh + (size_t)(n0 + row) * K + (k0 + scol), &sB[ch * 512]);
    }
    __syncthreads();
    short8 ah[4], bh[4];
#pragma unroll
    for (int i = 0; i < 4; i++) {
      ah[i] = *(const short8*)&sA[(wr * 64 + i * 16 + fr) * 32 + fq * 8];
      bh[i] = *(const short8*)&sB[(wc * 64 + i * 16 + fr) * 32 + fq * 8];
    }
#pragma unroll
    for (int i = 0; i < 4; i++)
#pragma unroll
      for (int j = 0; j < 4; j++)
        acc[i][j] = __builtin_amdgcn_mfma_f32_16x16x32_bf16(ah[i], bh[j], acc[i][j], 0, 0, 0);
    __syncthreads();
  }
#pragma unroll
  for (int j = 0; j < 4; j++) {
    const int col = n0 + wc * 64 + j * 16 + fr;
    const float bv = bias[col];
#pragma unroll
    for (int i = 0; i < 4; i++) {
      const int row = m0 + wr * 64 + i * 16 + fq * 4;
#pragma unroll
      for (int r = 0; r < 4; r++) C[(size_t)(row + r) * N + col] = f2bf(acc[i][j][r] + bv);
    }
  }
}

// ---------- plain bf16 GEMM: QKs = Xq * P_b (fp32 out, N=768) ----------
__global__ __launch_bounds__(256) void gemm_qk1(const unsigned short* __restrict__ Agh,
    const unsigned short* __restrict__ Pall_h, float* __restrict__ C, int chunk) {
  constexpr int K = 1024;
  __shared__ unsigned short sA[128 * 32];
  __shared__ unsigned short sB[128 * 32];
  const int tid = threadIdx.x, wid = tid >> 6, lane = tid & 63;
  const int m0 = blockIdx.y * 128, n0 = blockIdx.x * 128;
  const int batch = chunk * CB_ + (blockIdx.y >> 5);
  const unsigned short* __restrict__ Bgh = Pall_h + (size_t)batch * NP_ * K;
  const int wr = wid >> 1, wc = wid & 1;
  const int fr = lane & 15, fq = lane >> 4;
  const int srow = lane >> 2, scol = (lane & 3) * 8;
  f32x4 acc[4][4];
#pragma unroll
  for (int i = 0; i < 4; i++)
#pragma unroll
    for (int j = 0; j < 4; j++) acc[i][j] = f32x4{0.f, 0.f, 0.f, 0.f};

  for (int k0 = 0; k0 < K; k0 += 32) {
#pragma unroll
    for (int c = 0; c < 2; c++) {
      const int ch = wid * 2 + c;
      const int row = ch * 16 + srow;
      gload16(Agh + (size_t)(m0 + row) * K + (k0 + scol), &sA[ch * 512]);
      gload16(Bgh + (size_t)(n0 + row) * K + (k0 + scol), &sB[ch * 512]);
    }
    __syncthreads();
    short8 ah[4], bh[4];
#pragma unroll
    for (int i = 0; i < 4; i++) {
      ah[i] = *(const short8*)&sA[(wr * 64 + i * 16 + fr) * 32 + fq * 8];
      bh[i] = *(const short8*)&sB[(wc * 64 + i * 16 + fr) * 32 + fq * 8];
    }
#pragma unroll
    for (int i = 0; i < 4; i++)
#pragma unroll
      for (int j = 0; j < 4; j++)
        acc[i][j] = __builtin_amdgcn_mfma_f32_16x16x32_bf16(ah[i], bh[j], acc[i][j], 0, 0, 0);
    __syncthreads();
  }
#pragma unroll
  for (int j = 0; j < 4; j++) {
    const int col = n0 + wc * 64 + j * 16 + fr;
#pragma unroll
    for (int i = 0; i < 4; i++) {
      const int row = m0 + wr * 64 + i * 16 + fq * 4;
#pragma unroll
      for (int r = 0; r < 4; r++) C[(size_t)(row + r) * NP_ + col] = acc[i][j][r];
    }
  }
}

// ---------- exact fp32 sampled-K rows: Ksamp[bh][u][64] ----------
__global__ __launch_bounds__(256) void ksel_k(const float* __restrict__ X,
    const float* __restrict__ Wk, const float* __restrict__ bk,
    const int* __restrict__ sidx, float* __restrict__ Ksamp) {
  const int bh = blockIdx.x, b = bh >> 4, h = bh & 15;
  __shared__ float Xs[1024];
  __shared__ float red[256];
  const int t = threadIdx.x, d = t & 63, p = t >> 6;
  for (int u = 0; u < U_; u++) {
    const int l = sidx[u];
    *(float4*)&Xs[t * 4] = *(const float4*)&X[((size_t)b * L_ + l) * DM_ + t * 4];
    __syncthreads();
    float acc = 0.f;
    const float* wp = Wk + (size_t)(p * 256) * DM_ + h * 64 + d;
    for (int i = 0; i < 256; i++) acc += Xs[p * 256 + i] * wp[(size_t)i * DM_];
    red[t] = acc;
    __syncthreads();
    if (p == 0)
      Ksamp[((size_t)bh * U_ + u) * 64 + d] =
          red[d] + red[64 + d] + red[128 + d] + red[192 + d] + bk[h * 64 + d];
    __syncthreads();
  }
}

// ---------- P^T[b][h*48+u][k] = sum_d Wq[k][h*64+d]*Ksamp (bf16 hi) ----------
__global__ __launch_bounds__(256) void pform_k(const float* __restrict__ Wq,
    const float* __restrict__ Ksamp, unsigned short* __restrict__ Ph) {
  const int bh = blockIdx.x, b = bh >> 4, h = bh & 15;
  __shared__ float Ks[U_][68];
  const int t = threadIdx.x;
  for (int e = t; e < U_ * 64; e += 256) {
    const int u = e >> 6, d = e & 63;
    Ks[u][d] = Ksamp[((size_t)bh * U_ + u) * 64 + d];
  }
  __syncthreads();
  for (int kc = 0; kc < 4; kc++) {
    const int k = kc * 256 + t;
    float wr[64];
#pragma unroll
    for (int dd = 0; dd < 16; dd++) {
      const float4 w4 = *(const float4*)&Wq[(size_t)k * DM_ + h * 64 + dd * 4];
      wr[dd * 4 + 0] = w4.x; wr[dd * 4 + 1] = w4.y;
      wr[dd * 4 + 2] = w4.z; wr[dd * 4 + 3] = w4.w;
    }
    for (int u = 0; u < 48; u++) {
      size_t o = ((size_t)b * NP_ + h * 48 + u) * 1024 + k;
      if (u < U_) {
        float acc = 0.f;
#pragma unroll
        for (int d = 0; d < 64; d++) acc += wr[d] * Ks[u][d];
        Ph[o] = f2bf(acc);
      } else {
        Ph[o] = 0;
      }
    }
  }
}

// ---------- M_approx = max - mean over u ----------
__global__ __launch_bounds__(256) void mpass_k(const float* __restrict__ QKs,
                                               float* __restrict__ Mbuf, int chunk) {
  const int idx = blockIdx.x * 256 + threadIdx.x;   // < CROWS_*16
  const int ll = idx >> 4, h = idx & 15;
  const float* row = QKs + (size_t)ll * NP_ + h * 48;
  float mx = row[0], sm = row[0];
#pragma unroll
  for (int u = 1; u < U_; u++) { const float v = row[u]; mx = fmaxf(mx, v); sm += v; }
  const int lg = chunk * CROWS_ + ll;
  const int b = lg >> 12, l = lg & 4095;
  Mbuf[((size_t)(b * 16 + h)) * L_ + l] = mx - sm * (1.f / (float)U_);
}

// ---------- select_a: approx top-45 -> thr; candidates = {M >= thr - DELTA} ----------
__global__ __launch_bounds__(256) void select_a(const float* __restrict__ Mbuf,
    int* __restrict__ list, int* __restrict__ cnt) {
  const int bh = blockIdx.x, t = threadIdx.x;
  __shared__ float vals[L_];
  __shared__ float rv[256];
  __shared__ int   ri[256];
  __shared__ int   scnt;
  __shared__ float sthr;
  if (t == 0) scnt = 0;
  for (int i = t; i < L_; i += 256) vals[i] = Mbuf[(size_t)bh * L_ + i];
  __syncthreads();
  for (int it = 0; it < U_; it++) {
    float bv = vals[t * 16]; int bi = t * 16;
#pragma unroll
    for (int jj = 1; jj < 16; jj++) {
      const float v = vals[t * 16 + jj];
      if (v > bv) { bv = v; bi = t * 16 + jj; }
    }
    rv[t] = bv; ri[t] = bi;
    __syncthreads();
    for (int s = 128; s > 0; s >>= 1) {
      if (t < s) {
        if (rv[t + s] > rv[t] || (rv[t + s] == rv[t] && ri[t + s] < ri[t])) {
          rv[t] = rv[t + s]; ri[t] = ri[t + s];
        }
      }
      __syncthreads();
    }
    if (t == 0) {
      list[(size_t)bh * CAP_ + it] = ri[0];
      vals[ri[0]] = -3.4e38f;
      if (it == U_ - 1) sthr = rv[0];
    }
    __syncthreads();
  }
  const float lim = sthr - DELTA_;
  for (int i = t; i < L_; i += 256) {
    if (vals[i] >= lim) {
      const int j = atomicAdd(&scnt, 1);
      if (U_ + j < CAP_) list[(size_t)bh * CAP_ + U_ + j] = i;
    }
  }
  __syncthreads();
  if (t == 0) cnt[bh] = min(U_ + scnt, CAP_);
}

// ---------- exactM: fp32 recompute of M for candidates ----------
__global__ __launch_bounds__(256) void exactM(const float* __restrict__ X,
    const float* __restrict__ Wq, const float* __restrict__ bq,
    const float* __restrict__ Ksamp, const int* __restrict__ list,
    const int* __restrict__ cnt, float* __restrict__ candM) {
  const int bh = blockIdx.x, g = blockIdx.y, b = bh >> 4, h = bh & 15;
  __shared__ float Ks[U_][68];
  __shared__ float Xs[1024];
  __shared__ float red[256];
  __shared__ float qd[64];
  __shared__ float sc[U_];
  const int t = threadIdx.x, d = t & 63, p = t >> 6;
  for (int e = t; e < U_ * 64; e += 256) {
    const int u = e >> 6, dd = e & 63;
    Ks[u][dd] = Ksamp[((size_t)bh * U_ + u) * 64 + dd];
  }
  const int n = cnt[bh];
  for (int c = g; c < n; c += 8) {
    const int l = list[(size_t)bh * CAP_ + c];
    __syncthreads();
    *(float4*)&Xs[t * 4] = *(const float4*)&X[((size_t)b * L_ + l) * DM_ + t * 4];
    __syncthreads();
    float acc = 0.f;
    const float* wp = Wq + (size_t)(p * 256) * DM_ + h * 64 + d;
    for (int i = 0; i < 256; i++) acc += Xs[p * 256 + i] * wp[(size_t)i * DM_];
    red[t] = acc;
    __syncthreads();
    if (p == 0) qd[d] = red[d] + red[64 + d] + red[128 + d] + red[192 + d] + bq[h * 64 + d];
    __syncthreads();
    if (t < U_) {
      float s = 0.f;
#pragma unroll 8
      for (int dd = 0; dd < 64; dd++) s += qd[dd] * Ks[t][dd];
      sc[t] = s;
    }
    __syncthreads();
    if (t == 0) {
      float mx = sc[0], sm = sc[0];
      for (int u = 1; u < U_; u++) { mx = fmaxf(mx, sc[u]); sm += sc[u]; }
      candM[(size_t)bh * CAP_ + c] = mx - sm * (1.f / (float)U_);
    }
  }
}

// ---------- select_b: final top-45 over candidates (exact M, idx tie-break) ----------
__global__ __launch_bounds__(256) void select_b(const float* __restrict__ candM,
    const int* __restrict__ list, const int* __restrict__ cnt, int* __restrict__ topidx) {
  const int bh = blockIdx.x, t = threadIdx.x;
  __shared__ float mv[CAP_];
  __shared__ int   ml[CAP_];
  __shared__ float rv[256];
  __shared__ int   ri[256];
  const int n = cnt[bh];
  for (int i = t; i < CAP_; i += 256) {
    mv[i] = (i < n) ? candM[(size_t)bh * CAP_ + i] : -3.4e38f;
    ml[i] = (i < n) ? list[(size_t)bh * CAP_ + i] : 0x7fffffff;
  }
  __syncthreads();
  for (int it = 0; it < U_; it++) {
    float bv = mv[t]; int bi = ml[t]; int bj = t;
    {
      const float v = mv[t + 256]; const int l2 = ml[t + 256];
      if (v > bv || (v == bv && l2 < bi)) { bv = v; bi = l2; bj = t + 256; }
    }
    rv[t] = bv; ri[t] = (bj << 0); // store slot; tie-break on ml value below
    __syncthreads();
    for (int s = 128; s > 0; s >>= 1) {
      if (t < s) {
        const float v2 = rv[t + s];
        const int slot2 = ri[t + s];
        if (v2 > rv[t] || (v2 == rv[t] && ml[slot2] < ml[ri[t]])) {
          rv[t] = v2; ri[t] = slot2;
        }
      }
      __syncthreads();
    }
    if (t == 0) {
      topidx[bh * U_ + it] = ml[ri[0]];
      mv[ri[0]] = -3.4e38f;
    }
    __syncthreads();
  }
}

// ---------- recompute selected Q rows exactly -> bf16 Qbf[bh][48][64] ----------
__global__ __launch_bounds__(256) void qsel_k(const float* __restrict__ X,
    const float* __restrict__ Wq, const float* __restrict__ bq,
    const int* __restrict__ topidx, unsigned short* __restrict__ Qbf) {
  const int bh = blockIdx.x, b = bh >> 4, h = bh & 15;
  __shared__ float Xs[1024];
  __shared__ float red[256];
  const int t = threadIdx.x, d = t & 63, p = t >> 6;
  for (int u = 0; u < U_; u++) {
    const int l = topidx[bh * U_ + u];
    *(float4*)&Xs[t * 4] = *(const float4*)&X[((size_t)b * L_ + l) * DM_ + t * 4];
    __syncthreads();
    float acc = 0.f;
    const float* wp = Wq + (size_t)(p * 256) * DM_ + h * 64 + d;
    for (int i = 0; i < 256; i++) acc += Xs[p * 256 + i] * wp[(size_t)i * DM_];
    red[t] = acc;
    __syncthreads();
    if (p == 0)
      Qbf[((size_t)bh * 48 + u) * 64 + d] =
          f2bf(red[d] + red[64 + d] + red[128 + d] + red[192 + d] + bq[h * 64 + d]);
    __syncthreads();
  }
  if (t < 192) Qbf[((size_t)bh * 48 + U_) * 64 + t] = 0;  // zero pad rows 45..47
}

// ---------- V mean from bf16 V ----------
__global__ __launch_bounds__(256) void vmean_partial(const unsigned short* __restrict__ Vbf,
                                                     float* __restrict__ partial) {
  const int col = blockIdx.x * 256 + threadIdx.x;
  const int s = blockIdx.y, b = blockIdx.z;
  const unsigned short* src = Vbf + ((size_t)b * L_ + s * 64) * DM_ + col;
  float acc = 0.f;
#pragma unroll 8
  for (int l = 0; l < 64; l++) acc += bf2f(src[(size_t)l * DM_]);
  partial[((size_t)b * 64 + s) * DM_ + col] = acc;
}
__global__ __launch_bounds__(256) void vmean_combine(const float* __restrict__ partial,
                                                     float* __restrict__ Vm) {
  const int idx = blockIdx.x * 256 + threadIdx.x;  // 8192
  const int b = idx >> 10, col = idx & 1023;
  float acc = 0.f;
  for (int s = 0; s < 64; s++) acc += partial[((size_t)b * 64 + s) * DM_ + col];
  Vm[idx] = acc * (1.f / (float)L_);
}

// ---------- stage1: MFMA QK^T (swapped), VALU softmax+PV; no-max softmax ----------
__global__ __launch_bounds__(256) void attn_stage1(const unsigned short* __restrict__ Qbf,
    const unsigned short* __restrict__ Kbf, const unsigned short* __restrict__ Vbf,
    float* __restrict__ part) {
  const int bh = blockIdx.x, split = blockIdx.y;
  const int b = bh >> 4, h = bh & 15;
  __shared__ unsigned short sQ[48][72];
  __shared__ unsigned short sK[64][72];
  __shared__ unsigned short sV[64][72];
  __shared__ float es[64][52];
  const int tid = threadIdx.x, wid = tid >> 6, lane = tid & 63;
  const int fr = lane & 15, fq = lane >> 4;
  for (int e = tid; e < 48 * 8; e += 256) {
    const int r = e >> 3, c8 = (e & 7) * 8;
    *(ushort8*)&sQ[r][c8] = *(const ushort8*)&Qbf[((size_t)bh * 48 + r) * 64 + c8];
  }
  __syncthreads();
  short8 qf[3][2];
#pragma unroll
  for (int nt = 0; nt < 3; nt++)
#pragma unroll
    for (int kh = 0; kh < 2; kh++)
      qf[nt][kh] = *(const short8*)&sQ[nt * 16 + fr][kh * 32 + fq * 8];

  float S[12], ctx[12];
#pragma unroll
  for (int i = 0; i < 12; i++) { S[i] = 0.f; ctx[i] = 0.f; }

  for (int t = 0; t < 8; t++) {
    const int k0 = split * 512 + t * 64;
    if (t) __syncthreads();                 // prev tile's es/sV fully consumed
    for (int e = tid; e < 64 * 8; e += 256) {
      const int r = e >> 3, c8 = (e & 7) * 8;
      const size_t gsrc = ((size_t)b * L_ + k0 + r) * DM_ + h * 64 + c8;
      *(ushort8*)&sK[r][c8] = *(const ushort8*)&Kbf[gsrc];
      *(ushort8*)&sV[r][c8] = *(const ushort8*)&Vbf[gsrc];
    }
    __syncthreads();
    // QK^T: this wave's 16 keys (m = wid*16..+15), all 48 q (3 n-tiles)
    short8 kf0 = *(const short8*)&sK[wid * 16 + fr][fq * 8];
    short8 kf1 = *(const short8*)&sK[wid * 16 + fr][32 + fq * 8];
    f32x4 accq[3];
#pragma unroll
    for (int nt = 0; nt < 3; nt++) {
      accq[nt] = f32x4{0.f, 0.f, 0.f, 0.f};
      accq[nt] = __builtin_amdgcn_mfma_f32_16x16x32_bf16(kf0, qf[nt][0], accq[nt], 0, 0, 0);
      accq[nt] = __builtin_amdgcn_mfma_f32_16x16x32_bf16(kf1, qf[nt][1], accq[nt], 0, 0, 0);
    }
    // es[key][q] = exp(score/8); |score| bounded (~3.3) -> no max subtraction
#pragma unroll
    for (int nt = 0; nt < 3; nt++)
#pragma unroll
      for (int r = 0; r < 4; r++)
        es[wid * 16 + fq * 4 + r][nt * 16 + fr] = expf(accq[nt][r] * 0.125f);
    __syncthreads();
    // PV + S: this wave's 12 q (q = wid*12..+11), lane = d
    const int q0 = wid * 12;
    for (int k = 0; k < 64; k++) {
      const float v = bf2f(sV[k][lane]);
      const float4 e0 = *(const float4*)&es[k][q0];
      const float4 e1 = *(const float4*)&es[k][q0 + 4];
      const float4 e2 = *(const float4*)&es[k][q0 + 8];
      S[0] += e0.x; S[1] += e0.y; S[2]  += e0.z; S[3]  += e0.w;
      S[4] += e1.x; S[5] += e1.y; S[6]  += e1.z; S[7]  += e1.w;
      S[8] += e2.x; S[9] += e2.y; S[10] += e2.z; S[11] += e2.w;
      ctx[0] += e0.x * v; ctx[1] += e0.y * v; ctx[2]  += e0.z * v; ctx[3]  += e0.w * v;
      ctx[4] += e1.x * v; ctx[5] += e1.y * v; ctx[6]  += e1.z * v; ctx[7]  += e1.w * v;
      ctx[8] += e2.x * v; ctx[9] += e2.y * v; ctx[10] += e2.z * v; ctx[11] += e2.w * v;
    }
  }
#pragma unroll
  for (int i = 0; i < 12; i++) {
    const int u = wid * 12 + i;
    if (u < U_) {
      float* pb = part + ((size_t)(bh * NSPLIT + split) * U_ + u) * 65;
      if (lane == 0) pb[0] = S[i];
      pb[1 + lane] = ctx[i];
    }
  }
}

// ---------- combine splits; dctx = ctx/S - Vmean ----------
__global__ __launch_bounds__(256) void attn_stage2(const float* __restrict__ part,
    const float* __restrict__ Vm, float* __restrict__ dctx) {
  const int bh = blockIdx.x;
  const int wid = threadIdx.x >> 6, lane = threadIdx.x & 63;
  for (int u = wid; u < U_; u += 4) {
    float S = 0.f, c = 0.f;
#pragma unroll
    for (int sp = 0; sp < NSPLIT; sp++) {
      const float* pb = part + ((size_t)(bh * NSPLIT + sp) * U_ + u) * 65;
      S += pb[0];
      c += pb[1 + lane];
    }
    dctx[((size_t)bh * U_ + u) * 64 + lane] = c / S - Vm[bh * 64 + lane];
  }
}

// ---------- base[b][:] = concat_h(Vmean) @ Wo + bo ----------
__global__ __launch_bounds__(256) void base_k(const float* __restrict__ Vm,
    const float* __restrict__ Wo, const float* __restrict__ bo, float* __restrict__ base) {
  const int b = blockIdx.y;
  const int j = blockIdx.x * 256 + threadIdx.x;
  float acc = bo[j];
#pragma unroll 8
  for (int i = 0; i < DM_; i++) acc += Vm[b * DM_ + i] * Wo[(size_t)i * DM_ + j];
  base[b * DM_ + j] = acc;
}

// ---------- out[b,l,:] = base[b,:] ----------
__global__ __launch_bounds__(256) void fill_out(const float* __restrict__ base,
                                                float* __restrict__ out) {
  const size_t g = ((size_t)blockIdx.x * 256 + threadIdx.x) * 4;
  const int b = (int)(g >> 22), j = (int)(g & 1023);
  *(float4*)&out[g] = *(const float4*)&base[(b << 10) + j];
}

// ---------- out += (ctx-Vmean) @ Wo_block[h] on selected rows ----------
__global__ __launch_bounds__(256) void scatter_k(const float* __restrict__ dctx,
    const float* __restrict__ Wo, const int* __restrict__ topidx, float* __restrict__ out) {
  const int bh = blockIdx.x, b = bh >> 4, h = bh & 15;
  __shared__ float dc[U_ * 64];
  __shared__ int topl[U_];
  for (int e = threadIdx.x; e < U_ * 64; e += 256) dc[e] = dctx[(size_t)bh * U_ * 64 + e];
  if (threadIdx.x < U_) topl[threadIdx.x] = topidx[bh * U_ + threadIdx.x];
  __syncthreads();
  const int j4 = threadIdx.x * 4;
  for (int up = 0; up < 6; up++) {
    f32x4 a[8];
#pragma unroll
    for (int i = 0; i < 8; i++) a[i] = f32x4{0.f, 0.f, 0.f, 0.f};
    for (int d = 0; d < 64; d++) {
      const float4 w = *(const float4*)&Wo[(size_t)(h * 64 + d) * DM_ + j4];
#pragma unroll
      for (int i = 0; i < 8; i++) {
        const int u = up * 8 + i;
        if (u < U_) {
          const float cc = dc[u * 64 + d];
          a[i].x += cc * w.x; a[i].y += cc * w.y; a[i].z += cc * w.z; a[i].w += cc * w.w;
        }
      }
    }
#pragma unroll
    for (int i = 0; i < 8; i++) {
      const int u = up * 8 + i;
      if (u < U_) {
        float* row = out + ((size_t)b * L_ + topl[u]) * DM_ + j4;
        atomicAdd(row + 0, a[i].x); atomicAdd(row + 1, a[i].y);
        atomicAdd(row + 2, a[i].z); atomicAdd(row + 3, a[i].w);
      }
    }
  }
}

extern "C" void kernel_launch(void* const* d_in, const int* in_sizes, int n_in,
                              void* d_out, int out_size, void* d_ws, size_t ws_size,
                              hipStream_t stream) {
  const float* queries = (const float*)d_in[0];
  const float* keys    = (const float*)d_in[1];
  const float* values  = (const float*)d_in[2];
  const float* Wq = (const float*)d_in[3]; const float* bq = (const float*)d_in[4];
  const float* Wk = (const float*)d_in[5]; const float* bk = (const float*)d_in[6];
  const float* Wv = (const float*)d_in[7]; const float* bv = (const float*)d_in[8];
  const float* Wo = (const float*)d_in[9]; const float* bo = (const float*)d_in[10];
  const int* sidx = (const int*)d_in[11];

  // K,V live as bf16 in d_out (67.1 MB each) until the epilogue
  unsigned short* Kbf = (unsigned short*)d_out;
  unsigned short* Vbf = Kbf + (size_t)ML_ * DM_;

  uint8_t* p = (uint8_t*)d_ws;
  auto carve = [&](size_t bytes) { uint8_t* r = p; p += (bytes + 255) & ~(size_t)255; return r; };
  unsigned short* Xqh = (unsigned short*)carve((size_t)CROWS_ * DM_ * 2);   // 33.6 MB
  unsigned short* Xkh = (unsigned short*)carve((size_t)CROWS_ * DM_ * 2);
  unsigned short* Xvh = (unsigned short*)carve((size_t)CROWS_ * DM_ * 2);
  float* QKs = (float*)carve((size_t)CROWS_ * NP_ * 4);                     // 50.3 MB
  unsigned short* Ph = (unsigned short*)carve((size_t)B_ * NP_ * DM_ * 2);  // 12.6 MB
  unsigned short* WkT = (unsigned short*)carve((size_t)DM_ * DM_ * 2);
  unsigned short* WvT = (unsigned short*)carve((size_t)DM_ * DM_ * 2);
  float* Mbuf  = (float*)carve((size_t)BH_ * L_ * 4);                       // 2.1 MB
  float* Ksamp = (float*)carve((size_t)BH_ * U_ * 64 * 4);                  // 1.5 MB
  int*   list  = (int*)carve((size_t)BH_ * CAP_ * 4);                       // 256 KB
  float* candM = (float*)carve((size_t)BH_ * CAP_ * 4);                     // 256 KB
  int*   cntb  = (int*)carve((size_t)BH_ * 4);
  int*   topidx = (int*)carve((size_t)BH_ * U_ * 4);
  float* Vm    = (float*)carve((size_t)BH_ * 64 * 4);
  unsigned short* Qbf = (unsigned short*)carve((size_t)BH_ * 48 * 64 * 2);  // 786 KB
  const size_t need = (size_t)(p - (uint8_t*)d_ws);
  if (ws_size < need)
    fprintf(stderr, "ATHENA_WS: need %zu have %zu (WILL FAULT)\n", need, ws_size);

  // late-phase buffers alias QKs (dead after mpass)
  uint8_t* ap = (uint8_t*)QKs;
  auto acarve = [&](size_t bytes) { uint8_t* r = ap; ap += (bytes + 255) & ~(size_t)255; return r; };
  float* part  = (float*)acarve((size_t)BH_ * NSPLIT * U_ * 65 * 4);        // 12 MB
  float* dctx  = (float*)acarve((size_t)BH_ * U_ * 64 * 4);
  float* vpart = (float*)acarve((size_t)B_ * 64 * DM_ * 4);                 // 2.1 MB
  float* base  = (float*)acarve((size_t)B_ * DM_ * 4);

  ksel_k<<<BH_, 256, 0, stream>>>(keys, Wk, bk, sidx, Ksamp);
  pform_k<<<BH_, 256, 0, stream>>>(Wq, Ksamp, Ph);
  wT_single<<<4096, 256, 0, stream>>>(Wk, WkT);
  wT_single<<<4096, 256, 0, stream>>>(Wv, WvT);

  const int n4 = (int)((size_t)CROWS_ * DM_ / 4);
  for (int c = 0; c < 2; c++) {
    const size_t off = (size_t)c * CROWS_ * DM_;
    split3h<<<dim3(2048, 3), 256, 0, stream>>>(queries + off, keys + off, values + off,
                                               Xqh, Xkh, Xvh, n4);
    gemm_plain<<<dim3(8, 128), 256, 0, stream>>>(Xkh, WkT, bk, Kbf + off);
    gemm_plain<<<dim3(8, 128), 256, 0, stream>>>(Xvh, WvT, bv, Vbf + off);
    gemm_qk1<<<dim3(6, 128), 256, 0, stream>>>(Xqh, Ph, QKs, c);
    mpass_k<<<(CROWS_ * 16) / 256, 256, 0, stream>>>(QKs, Mbuf, c);
  }

  select_a<<<BH_, 256, 0, stream>>>(Mbuf, list, cntb);
  exactM<<<dim3(BH_, 8), 256, 0, stream>>>(queries, Wq, bq, Ksamp, list, cntb, candM);
  select_b<<<BH_, 256, 0, stream>>>(candM, list, cntb, topidx);
  qsel_k<<<BH_, 256, 0, stream>>>(queries, Wq, bq, topidx, Qbf);
  vmean_partial<<<dim3(DM_ / 256, 64, B_), 256, 0, stream>>>(Vbf, vpart);
  vmean_combine<<<(B_ * DM_) / 256, 256, 0, stream>>>(vpart, Vm);
  attn_stage1<<<dim3(BH_, NSPLIT), 256, 0, stream>>>(Qbf, Kbf, Vbf, part);
  attn_stage2<<<BH_, 256, 0, stream>>>(part, Vm, dctx);
  base_k<<<dim3(DM_ / 256, B_), 256, 0, stream>>>(Vm, Wo, bo, base);
  fill_out<<<(int)((size_t)ML_ * DM_ / 4 / 256), 256, 0, stream>>>(base, (float*)d_out);
  scatter_k<<<BH_, 256, 0, stream>>>(dctx, Wo, topidx, (float*)d_out);
}

// Round 7
// 1291.738 us; speedup vs baseline: 1.6572x; 1.1716x over previous
//
#include <hip/hip_runtime.h>
#include <cstdint>
#include <cstdio>

#define B_   8
#define L_   4096
#define DM_  1024
#define H_   16
#define D_   64
#define U_   45
#define BH_  (B_*H_)
#define ML_  (B_*L_)
#define NSPLIT 8
#define NP_  768           // padded QK-sample width: 16 heads * 48
#define CB_  4             // batches per chunk
#define CROWS_ (CB_*L_)    // 16384 rows per chunk
#define CAP_ 512           // candidate cap per (b,h)
#define DELTA_ 0.12f       // exact-recompute band (~9 sigma of bf16 GEMM err)

using f32x4   = __attribute__((ext_vector_type(4))) float;
using short8  = __attribute__((ext_vector_type(8))) short;
using ushort8 = __attribute__((ext_vector_type(8))) unsigned short;

__device__ __forceinline__ unsigned short f2bf(float f) {
  uint32_t u = __float_as_uint(f);
  u += 0x7fffu + ((u >> 16) & 1u);      // RNE; inputs finite
  return (unsigned short)(u >> 16);
}
__device__ __forceinline__ float bf2f(unsigned short h) {
  return __uint_as_float(((uint32_t)h) << 16);
}

__device__ __forceinline__ void gload16(const void* g, void* l) {
  __builtin_amdgcn_global_load_lds((const __attribute__((address_space(1))) void*)g,
                                   (__attribute__((address_space(3))) void*)l,
                                   16, 0, 0);
}

// ---------- split: q,k,v -> bf16 hi only ----------
__global__ __launch_bounds__(256) void split3h(const float* __restrict__ q,
    const float* __restrict__ k, const float* __restrict__ v,
    unsigned short* __restrict__ Xqh, unsigned short* __restrict__ Xkh,
    unsigned short* __restrict__ Xvh, int n4) {
  const int z = blockIdx.y;
  const float* __restrict__ X = (z == 0) ? q : ((z == 1) ? k : v);
  unsigned short* __restrict__ O = (z == 0) ? Xqh : ((z == 1) ? Xkh : Xvh);
  int i = blockIdx.x * 256 + threadIdx.x;
  const int stride = gridDim.x * 256;
  for (; i < n4; i += stride) {
    const float4 w = ((const float4*)X)[i];
    ushort4 hv;
    hv.x = f2bf(w.x); hv.y = f2bf(w.y); hv.z = f2bf(w.z); hv.w = f2bf(w.w);
    ((ushort4*)O)[i] = hv;
  }
}

// ---------- W (KxN) -> W^T bf16 (NxK) ----------
__global__ __launch_bounds__(256) void wT_single(const float* __restrict__ W,
                                                 unsigned short* __restrict__ WT) {
  const int idx = blockIdx.x * 256 + threadIdx.x;   // 1M threads
  const int n = idx >> 10, kk = idx & 1023;
  WT[idx] = f2bf(W[kk * 1024 + n]);
}

// ---------- plain bf16 GEMM, bf16 out: C = bf16(X*W + bias) ----------
__global__ __launch_bounds__(256) void gemm_plain(const unsigned short* __restrict__ Agh,
    const unsigned short* __restrict__ Bgh, const float* __restrict__ bias,
    unsigned short* __restrict__ C) {
  constexpr int K = 1024, N = 1024;
  __shared__ unsigned short sA[128 * 32];
  __shared__ unsigned short sB[128 * 32];
  const int tid = threadIdx.x, wid = tid >> 6, lane = tid & 63;
  const int m0 = blockIdx.y * 128, n0 = blockIdx.x * 128;
  const int wr = wid >> 1, wc = wid & 1;
  const int fr = lane & 15, fq = lane >> 4;
  const int srow = lane >> 2, scol = (lane & 3) * 8;
  f32x4 acc[4][4];
#pragma unroll
  for (int i = 0; i < 4; i++)
#pragma unroll
    for (int j = 0; j < 4; j++) acc[i][j] = f32x4{0.f, 0.f, 0.f, 0.f};

  for (int k0 = 0; k0 < K; k0 += 32) {
#pragma unroll
    for (int c = 0; c < 2; c++) {
      const int ch = wid * 2 + c;
      const int row = ch * 16 + srow;
      gload16(Agh + (size_t)(m0 + row) * K + (k0 + scol), &sA[ch * 512]);
      gload16(Bgh + (size_t)(n0 + row) * K + (k0 + scol), &sB[ch * 512]);
    }
    __syncthreads();
    short8 ah[4], bh[4];
#pragma unroll
    for (int i = 0; i < 4; i++) {
      ah[i] = *(const short8*)&sA[(wr * 64 + i * 16 + fr) * 32 + fq * 8];
      bh[i] = *(const short8*)&sB[(wc * 64 + i * 16 + fr) * 32 + fq * 8];
    }
#pragma unroll
    for (int i = 0; i < 4; i++)
#pragma unroll
      for (int j = 0; j < 4; j++)
        acc[i][j] = __builtin_amdgcn_mfma_f32_16x16x32_bf16(ah[i], bh[j], acc[i][j], 0, 0, 0);
    __syncthreads();
  }
#pragma unroll
  for (int j = 0; j < 4; j++) {
    const int col = n0 + wc * 64 + j * 16 + fr;
    const float bv = bias[col];
#pragma unroll
    for (int i = 0; i < 4; i++) {
      const int row = m0 + wr * 64 + i * 16 + fq * 4;
#pragma unroll
      for (int r = 0; r < 4; r++) C[(size_t)(row + r) * N + col] = f2bf(acc[i][j][r] + bv);
    }
  }
}

// ---------- plain bf16 GEMM: QKs = Xq * P_b (fp32 out, N=768) ----------
__global__ __launch_bounds__(256) void gemm_qk1(const unsigned short* __restrict__ Agh,
    const unsigned short* __restrict__ Pall_h, float* __restrict__ C, int chunk) {
  constexpr int K = 1024;
  __shared__ unsigned short sA[128 * 32];
  __shared__ unsigned short sB[128 * 32];
  const int tid = threadIdx.x, wid = tid >> 6, lane = tid & 63;
  const int m0 = blockIdx.y * 128, n0 = blockIdx.x * 128;
  const int batch = chunk * CB_ + (blockIdx.y >> 5);
  const unsigned short* __restrict__ Bgh = Pall_h + (size_t)batch * NP_ * K;
  const int wr = wid >> 1, wc = wid & 1;
  const int fr = lane & 15, fq = lane >> 4;
  const int srow = lane >> 2, scol = (lane & 3) * 8;
  f32x4 acc[4][4];
#pragma unroll
  for (int i = 0; i < 4; i++)
#pragma unroll
    for (int j = 0; j < 4; j++) acc[i][j] = f32x4{0.f, 0.f, 0.f, 0.f};

  for (int k0 = 0; k0 < K; k0 += 32) {
#pragma unroll
    for (int c = 0; c < 2; c++) {
      const int ch = wid * 2 + c;
      const int row = ch * 16 + srow;
      gload16(Agh + (size_t)(m0 + row) * K + (k0 + scol), &sA[ch * 512]);
      gload16(Bgh + (size_t)(n0 + row) * K + (k0 + scol), &sB[ch * 512]);
    }
    __syncthreads();
    short8 ah[4], bh[4];
#pragma unroll
    for (int i = 0; i < 4; i++) {
      ah[i] = *(const short8*)&sA[(wr * 64 + i * 16 + fr) * 32 + fq * 8];
      bh[i] = *(const short8*)&sB[(wc * 64 + i * 16 + fr) * 32 + fq * 8];
    }
#pragma unroll
    for (int i = 0; i < 4; i++)
#pragma unroll
      for (int j = 0; j < 4; j++)
        acc[i][j] = __builtin_amdgcn_mfma_f32_16x16x32_bf16(ah[i], bh[j], acc[i][j], 0, 0, 0);
    __syncthreads();
  }
#pragma unroll
  for (int j = 0; j < 4; j++) {
    const int col = n0 + wc * 64 + j * 16 + fr;
#pragma unroll
    for (int i = 0; i < 4; i++) {
      const int row = m0 + wr * 64 + i * 16 + fq * 4;
#pragma unroll
      for (int r = 0; r < 4; r++) C[(size_t)(row + r) * NP_ + col] = acc[i][j][r];
    }
  }
}

// ---------- exact fp32 sampled-K rows, column-parallel ----------
// grid (4 col-stripes, 8 batches, 3 u-groups); thread owns one Wk column.
__global__ __launch_bounds__(256) void ksel2(const float* __restrict__ X,
    const float* __restrict__ Wk, const float* __restrict__ bk,
    const int* __restrict__ sidx, float* __restrict__ Ksamp) {
  const int t = threadIdx.x;
  const int col = blockIdx.x * 256 + t;
  const int b = blockIdx.y, ug = blockIdx.z;
  __shared__ float Xs[15][256];
  __shared__ int rows[15];
  if (t < 15) rows[t] = sidx[ug * 15 + t];
  float acc[15];
#pragma unroll
  for (int r = 0; r < 15; r++) acc[r] = 0.f;
  for (int kc = 0; kc < 4; kc++) {
    __syncthreads();
#pragma unroll
    for (int i = 0; i < 15; i++)
      Xs[i][t] = X[((size_t)b * L_ + rows[i]) * DM_ + kc * 256 + t];
    __syncthreads();
#pragma unroll 4
    for (int kk = 0; kk < 256; kk++) {
      const float w = Wk[(size_t)(kc * 256 + kk) * DM_ + col];
#pragma unroll
      for (int r = 0; r < 15; r++) acc[r] += Xs[r][kk] * w;
    }
  }
  const int h = col >> 6, d = col & 63;
  const float bias = bk[col];
#pragma unroll
  for (int r = 0; r < 15; r++)
    Ksamp[((size_t)(b * 16 + h) * U_ + ug * 15 + r) * 64 + d] = acc[r] + bias;
}

// ---------- P^T[b][h*48+u][k] = sum_d Wq[k][h*64+d]*Ksamp (bf16 hi) ----------
__global__ __launch_bounds__(256) void pform_k(const float* __restrict__ Wq,
    const float* __restrict__ Ksamp, unsigned short* __restrict__ Ph) {
  const int bh = blockIdx.x, b = bh >> 4, h = bh & 15;
  __shared__ float Ks[U_][68];
  const int t = threadIdx.x;
  for (int e = t; e < U_ * 64; e += 256) {
    const int u = e >> 6, d = e & 63;
    Ks[u][d] = Ksamp[((size_t)bh * U_ + u) * 64 + d];
  }
  __syncthreads();
  for (int kc = 0; kc < 4; kc++) {
    const int k = kc * 256 + t;
    float wr[64];
#pragma unroll
    for (int dd = 0; dd < 16; dd++) {
      const float4 w4 = *(const float4*)&Wq[(size_t)k * DM_ + h * 64 + dd * 4];
      wr[dd * 4 + 0] = w4.x; wr[dd * 4 + 1] = w4.y;
      wr[dd * 4 + 2] = w4.z; wr[dd * 4 + 3] = w4.w;
    }
    for (int u = 0; u < 48; u++) {
      size_t o = ((size_t)b * NP_ + h * 48 + u) * 1024 + k;
      if (u < U_) {
        float acc = 0.f;
#pragma unroll
        for (int d = 0; d < 64; d++) acc += wr[d] * Ks[u][d];
        Ph[o] = f2bf(acc);
      } else {
        Ph[o] = 0;
      }
    }
  }
}

// ---------- M_approx = max - mean over u ----------
__global__ __launch_bounds__(256) void mpass_k(const float* __restrict__ QKs,
                                               float* __restrict__ Mbuf, int chunk) {
  const int idx = blockIdx.x * 256 + threadIdx.x;   // < CROWS_*16
  const int ll = idx >> 4, h = idx & 15;
  const float* row = QKs + (size_t)ll * NP_ + h * 48;
  float mx = row[0], sm = row[0];
#pragma unroll
  for (int u = 1; u < U_; u++) { const float v = row[u]; mx = fmaxf(mx, v); sm += v; }
  const int lg = chunk * CROWS_ + ll;
  const int b = lg >> 12, l = lg & 4095;
  Mbuf[((size_t)(b * 16 + h)) * L_ + l] = mx - sm * (1.f / (float)U_);
}

// ---------- select_a: approx top-45 -> thr; candidates = {M >= thr - DELTA} ----------
__global__ __launch_bounds__(256) void select_a(const float* __restrict__ Mbuf,
    int* __restrict__ list, int* __restrict__ cnt) {
  const int bh = blockIdx.x, t = threadIdx.x;
  __shared__ float vals[L_];
  __shared__ float rv[256];
  __shared__ int   ri[256];
  __shared__ int   scnt;
  __shared__ float sthr;
  if (t == 0) scnt = 0;
  for (int i = t; i < L_; i += 256) vals[i] = Mbuf[(size_t)bh * L_ + i];
  __syncthreads();
  for (int it = 0; it < U_; it++) {
    float bv = vals[t * 16]; int bi = t * 16;
#pragma unroll
    for (int jj = 1; jj < 16; jj++) {
      const float v = vals[t * 16 + jj];
      if (v > bv) { bv = v; bi = t * 16 + jj; }
    }
    rv[t] = bv; ri[t] = bi;
    __syncthreads();
    for (int s = 128; s > 0; s >>= 1) {
      if (t < s) {
        if (rv[t + s] > rv[t] || (rv[t + s] == rv[t] && ri[t + s] < ri[t])) {
          rv[t] = rv[t + s]; ri[t] = ri[t + s];
        }
      }
      __syncthreads();
    }
    if (t == 0) {
      list[(size_t)bh * CAP_ + it] = ri[0];
      vals[ri[0]] = -3.4e38f;
      if (it == U_ - 1) sthr = rv[0];
    }
    __syncthreads();
  }
  const float lim = sthr - DELTA_;
  for (int i = t; i < L_; i += 256) {
    if (vals[i] >= lim) {
      const int j = atomicAdd(&scnt, 1);
      if (U_ + j < CAP_) list[(size_t)bh * CAP_ + U_ + j] = i;
    }
  }
  __syncthreads();
  if (t == 0) cnt[bh] = min(U_ + scnt, CAP_);
}

// ---------- exactM2: fp32 recompute of M for candidates, 8 per block-group ----------
__global__ __launch_bounds__(256) void exactM2(const float* __restrict__ X,
    const float* __restrict__ Wq, const float* __restrict__ bq,
    const float* __restrict__ Ksamp, const int* __restrict__ list,
    const int* __restrict__ cnt, float* __restrict__ candM) {
  const int bh = blockIdx.x, g = blockIdx.y, b = bh >> 4, h = bh & 15;
  __shared__ float Ks[U_][68];
  __shared__ float Xs[8][256];
  __shared__ float red[4][8][64];
  __shared__ float qd[8][68];
  __shared__ float sc[8][45];
  __shared__ int rows[8];
  const int t = threadIdx.x, p = t >> 6, d = t & 63;
  for (int e = t; e < U_ * 64; e += 256) {
    const int u = e >> 6, dd = e & 63;
    Ks[u][dd] = Ksamp[((size_t)bh * U_ + u) * 64 + dd];
  }
  const int n = cnt[bh];
  for (int c0 = g * 8; c0 < n; c0 += 64) {
    const int nc = min(8, n - c0);
    __syncthreads();
    if (t < 8) rows[t] = list[(size_t)bh * CAP_ + c0 + min(t, nc - 1)];
    float acc[8];
#pragma unroll
    for (int r = 0; r < 8; r++) acc[r] = 0.f;
    for (int kc = 0; kc < 4; kc++) {
      __syncthreads();
#pragma unroll
      for (int i = 0; i < 8; i++)
        Xs[i][t] = X[((size_t)b * L_ + rows[i]) * DM_ + kc * 256 + t];
      __syncthreads();
#pragma unroll 4
      for (int kk = 0; kk < 64; kk++) {
        const float w = Wq[(size_t)(kc * 256 + p * 64 + kk) * DM_ + h * 64 + d];
#pragma unroll
        for (int r = 0; r < 8; r++) acc[r] += Xs[r][p * 64 + kk] * w;
      }
    }
#pragma unroll
    for (int r = 0; r < 8; r++) red[p][r][d] = acc[r];
    __syncthreads();
    if (p == 0) {
#pragma unroll
      for (int r = 0; r < 8; r++)
        qd[r][d] = red[0][r][d] + red[1][r][d] + red[2][r][d] + red[3][r][d] + bq[h * 64 + d];
    }
    __syncthreads();
    for (int idx = t; idx < 8 * U_; idx += 256) {
      const int c = idx / U_, u = idx - c * U_;
      float s = 0.f;
#pragma unroll 8
      for (int dd = 0; dd < 64; dd++) s += qd[c][dd] * Ks[u][dd];
      sc[c][u] = s;
    }
    __syncthreads();
    if (t < nc) {
      float mx = sc[t][0], sm = sc[t][0];
      for (int u = 1; u < U_; u++) { mx = fmaxf(mx, sc[t][u]); sm += sc[t][u]; }
      candM[(size_t)bh * CAP_ + c0 + t] = mx - sm * (1.f / (float)U_);
    }
  }
}

// ---------- select_b: final top-45 over candidates (exact M, idx tie-break) ----------
__global__ __launch_bounds__(256) void select_b(const float* __restrict__ candM,
    const int* __restrict__ list, const int* __restrict__ cnt, int* __restrict__ topidx) {
  const int bh = blockIdx.x, t = threadIdx.x;
  __shared__ float mv[CAP_];
  __shared__ int   ml[CAP_];
  __shared__ float rv[256];
  __shared__ int   ri[256];
  const int n = cnt[bh];
  for (int i = t; i < CAP_; i += 256) {
    mv[i] = (i < n) ? candM[(size_t)bh * CAP_ + i] : -3.4e38f;
    ml[i] = (i < n) ? list[(size_t)bh * CAP_ + i] : 0x7fffffff;
  }
  __syncthreads();
  for (int it = 0; it < U_; it++) {
    float bv = mv[t]; int bi = ml[t]; int bj = t;
    {
      const float v = mv[t + 256]; const int l2 = ml[t + 256];
      if (v > bv || (v == bv && l2 < bi)) { bv = v; bi = l2; bj = t + 256; }
    }
    rv[t] = bv; ri[t] = bj;
    __syncthreads();
    for (int s = 128; s > 0; s >>= 1) {
      if (t < s) {
        const float v2 = rv[t + s];
        const int slot2 = ri[t + s];
        if (v2 > rv[t] || (v2 == rv[t] && ml[slot2] < ml[ri[t]])) {
          rv[t] = v2; ri[t] = slot2;
        }
      }
      __syncthreads();
    }
    if (t == 0) {
      topidx[bh * U_ + it] = ml[ri[0]];
      mv[ri[0]] = -3.4e38f;
    }
    __syncthreads();
  }
}

// ---------- qsel2: exact selected Q rows -> bf16, column-parallel ----------
// grid (BH_, 3 u-groups); thread = (k-quarter p, head-col d).
__global__ __launch_bounds__(256) void qsel2(const float* __restrict__ X,
    const float* __restrict__ Wq, const float* __restrict__ bq,
    const int* __restrict__ topidx, unsigned short* __restrict__ Qbf) {
  const int bh = blockIdx.x, ug = blockIdx.y;
  const int b = bh >> 4, h = bh & 15;
  __shared__ float Xs[15][256];
  __shared__ float red[4][15][64];
  __shared__ int rows[15];
  const int t = threadIdx.x, p = t >> 6, d = t & 63;
  if (t < 15) rows[t] = topidx[bh * U_ + ug * 15 + t];
  float acc[15];
#pragma unroll
  for (int r = 0; r < 15; r++) acc[r] = 0.f;
  for (int kc = 0; kc < 4; kc++) {
    __syncthreads();
#pragma unroll
    for (int i = 0; i < 15; i++)
      Xs[i][t] = X[((size_t)b * L_ + rows[i]) * DM_ + kc * 256 + t];
    __syncthreads();
#pragma unroll 4
    for (int kk = 0; kk < 64; kk++) {
      const float w = Wq[(size_t)(kc * 256 + p * 64 + kk) * DM_ + h * 64 + d];
#pragma unroll
      for (int r = 0; r < 15; r++) acc[r] += Xs[r][p * 64 + kk] * w;
    }
  }
#pragma unroll
  for (int r = 0; r < 15; r++) red[p][r][d] = acc[r];
  __syncthreads();
  if (p == 0) {
    const float bias = bq[h * 64 + d];
#pragma unroll
    for (int r = 0; r < 15; r++)
      Qbf[((size_t)bh * 48 + ug * 15 + r) * 64 + d] =
          f2bf(red[0][r][d] + red[1][r][d] + red[2][r][d] + red[3][r][d] + bias);
  }
  if (ug == 2 && t < 192) Qbf[((size_t)bh * 48 + U_) * 64 + t] = 0;  // pad rows 45..47
}

// ---------- V mean from bf16 V ----------
__global__ __launch_bounds__(256) void vmean_partial(const unsigned short* __restrict__ Vbf,
                                                     float* __restrict__ partial) {
  const int col = blockIdx.x * 256 + threadIdx.x;
  const int s = blockIdx.y, b = blockIdx.z;
  const unsigned short* src = Vbf + ((size_t)b * L_ + s * 64) * DM_ + col;
  float acc = 0.f;
#pragma unroll 8
  for (int l = 0; l < 64; l++) acc += bf2f(src[(size_t)l * DM_]);
  partial[((size_t)b * 64 + s) * DM_ + col] = acc;
}
__global__ __launch_bounds__(256) void vmean_combine(const float* __restrict__ partial,
                                                     float* __restrict__ Vm) {
  const int idx = blockIdx.x * 256 + threadIdx.x;  // 8192
  const int b = idx >> 10, col = idx & 1023;
  float acc = 0.f;
  for (int s = 0; s < 64; s++) acc += partial[((size_t)b * 64 + s) * DM_ + col];
  Vm[idx] = acc * (1.f / (float)L_);
}

// ---------- stage1: MFMA QK^T (swapped), VALU softmax+PV; no-max softmax ----------
__global__ __launch_bounds__(256) void attn_stage1(const unsigned short* __restrict__ Qbf,
    const unsigned short* __restrict__ Kbf, const unsigned short* __restrict__ Vbf,
    float* __restrict__ part) {
  const int bh = blockIdx.x, split = blockIdx.y;
  const int b = bh >> 4, h = bh & 15;
  __shared__ unsigned short sQ[48][72];
  __shared__ unsigned short sK[64][72];
  __shared__ unsigned short sV[64][72];
  __shared__ float es[64][52];
  const int tid = threadIdx.x, wid = tid >> 6, lane = tid & 63;
  const int fr = lane & 15, fq = lane >> 4;
  for (int e = tid; e < 48 * 8; e += 256) {
    const int r = e >> 3, c8 = (e & 7) * 8;
    *(ushort8*)&sQ[r][c8] = *(const ushort8*)&Qbf[((size_t)bh * 48 + r) * 64 + c8];
  }
  __syncthreads();
  short8 qf[3][2];
#pragma unroll
  for (int nt = 0; nt < 3; nt++)
#pragma unroll
    for (int kh = 0; kh < 2; kh++)
      qf[nt][kh] = *(const short8*)&sQ[nt * 16 + fr][kh * 32 + fq * 8];

  float S[12], ctx[12];
#pragma unroll
  for (int i = 0; i < 12; i++) { S[i] = 0.f; ctx[i] = 0.f; }

  for (int t = 0; t < 8; t++) {
    const int k0 = split * 512 + t * 64;
    if (t) __syncthreads();                 // prev tile's es/sV fully consumed
    for (int e = tid; e < 64 * 8; e += 256) {
      const int r = e >> 3, c8 = (e & 7) * 8;
      const size_t gsrc = ((size_t)b * L_ + k0 + r) * DM_ + h * 64 + c8;
      *(ushort8*)&sK[r][c8] = *(const ushort8*)&Kbf[gsrc];
      *(ushort8*)&sV[r][c8] = *(const ushort8*)&Vbf[gsrc];
    }
    __syncthreads();
    // QK^T: this wave's 16 keys (m = wid*16..+15), all 48 q (3 n-tiles)
    short8 kf0 = *(const short8*)&sK[wid * 16 + fr][fq * 8];
    short8 kf1 = *(const short8*)&sK[wid * 16 + fr][32 + fq * 8];
    f32x4 accq[3];
#pragma unroll
    for (int nt = 0; nt < 3; nt++) {
      accq[nt] = f32x4{0.f, 0.f, 0.f, 0.f};
      accq[nt] = __builtin_amdgcn_mfma_f32_16x16x32_bf16(kf0, qf[nt][0], accq[nt], 0, 0, 0);
      accq[nt] = __builtin_amdgcn_mfma_f32_16x16x32_bf16(kf1, qf[nt][1], accq[nt], 0, 0, 0);
    }
    // es[key][q] = exp(score/8); |score| bounded (~3.3) -> no max subtraction
#pragma unroll
    for (int nt = 0; nt < 3; nt++)
#pragma unroll
      for (int r = 0; r < 4; r++)
        es[wid * 16 + fq * 4 + r][nt * 16 + fr] = expf(accq[nt][r] * 0.125f);
    __syncthreads();
    // PV + S: this wave's 12 q (q = wid*12..+11), lane = d
    const int q0 = wid * 12;
    for (int k = 0; k < 64; k++) {
      const float v = bf2f(sV[k][lane]);
      const float4 e0 = *(const float4*)&es[k][q0];
      const float4 e1 = *(const float4*)&es[k][q0 + 4];
      const float4 e2 = *(const float4*)&es[k][q0 + 8];
      S[0] += e0.x; S[1] += e0.y; S[2]  += e0.z; S[3]  += e0.w;
      S[4] += e1.x; S[5] += e1.y; S[6]  += e1.z; S[7]  += e1.w;
      S[8] += e2.x; S[9] += e2.y; S[10] += e2.z; S[11] += e2.w;
      ctx[0] += e0.x * v; ctx[1] += e0.y * v; ctx[2]  += e0.z * v; ctx[3]  += e0.w * v;
      ctx[4] += e1.x * v; ctx[5] += e1.y * v; ctx[6]  += e1.z * v; ctx[7]  += e1.w * v;
      ctx[8] += e2.x * v; ctx[9] += e2.y * v; ctx[10] += e2.z * v; ctx[11] += e2.w * v;
    }
  }
#pragma unroll
  for (int i = 0; i < 12; i++) {
    const int u = wid * 12 + i;
    if (u < U_) {
      float* pb = part + ((size_t)(bh * NSPLIT + split) * U_ + u) * 65;
      if (lane == 0) pb[0] = S[i];
      pb[1 + lane] = ctx[i];
    }
  }
}

// ---------- combine splits; dctx = ctx/S - Vmean ----------
__global__ __launch_bounds__(256) void attn_stage2(const float* __restrict__ part,
    const float* __restrict__ Vm, float* __restrict__ dctx) {
  const int bh = blockIdx.x;
  const int wid = threadIdx.x >> 6, lane = threadIdx.x & 63;
  for (int u = wid; u < U_; u += 4) {
    float S = 0.f, c = 0.f;
#pragma unroll
    for (int sp = 0; sp < NSPLIT; sp++) {
      const float* pb = part + ((size_t)(bh * NSPLIT + sp) * U_ + u) * 65;
      S += pb[0];
      c += pb[1 + lane];
    }
    dctx[((size_t)bh * U_ + u) * 64 + lane] = c / S - Vm[bh * 64 + lane];
  }
}

// ---------- base[b][:] = concat_h(Vmean) @ Wo + bo ----------
__global__ __launch_bounds__(256) void base_k(const float* __restrict__ Vm,
    const float* __restrict__ Wo, const float* __restrict__ bo, float* __restrict__ base) {
  const int b = blockIdx.y;
  const int j = blockIdx.x * 256 + threadIdx.x;
  float acc = bo[j];
#pragma unroll 8
  for (int i = 0; i < DM_; i++) acc += Vm[b * DM_ + i] * Wo[(size_t)i * DM_ + j];
  base[b * DM_ + j] = acc;
}

// ---------- out[b,l,:] = base[b,:] ----------
__global__ __launch_bounds__(256) void fill_out(const float* __restrict__ base,
                                                float* __restrict__ out) {
  const size_t g = ((size_t)blockIdx.x * 256 + threadIdx.x) * 4;
  const int b = (int)(g >> 22), j = (int)(g & 1023);
  *(float4*)&out[g] = *(const float4*)&base[(b << 10) + j];
}

// ---------- out += (ctx-Vmean) @ Wo_block[h] on selected rows ----------
__global__ __launch_bounds__(256) void scatter_k(const float* __restrict__ dctx,
    const float* __restrict__ Wo, const int* __restrict__ topidx, float* __restrict__ out) {
  const int bh = blockIdx.x, b = bh >> 4, h = bh & 15;
  __shared__ float dc[U_ * 64];
  __shared__ int topl[U_];
  for (int e = threadIdx.x; e < U_ * 64; e += 256) dc[e] = dctx[(size_t)bh * U_ * 64 + e];
  if (threadIdx.x < U_) topl[threadIdx.x] = topidx[bh * U_ + threadIdx.x];
  __syncthreads();
  const int j4 = threadIdx.x * 4;
  for (int up = 0; up < 6; up++) {
    f32x4 a[8];
#pragma unroll
    for (int i = 0; i < 8; i++) a[i] = f32x4{0.f, 0.f, 0.f, 0.f};
    for (int d = 0; d < 64; d++) {
      const float4 w = *(const float4*)&Wo[(size_t)(h * 64 + d) * DM_ + j4];
#pragma unroll
      for (int i = 0; i < 8; i++) {
        const int u = up * 8 + i;
        if (u < U_) {
          const float cc = dc[u * 64 + d];
          a[i].x += cc * w.x; a[i].y += cc * w.y; a[i].z += cc * w.z; a[i].w += cc * w.w;
        }
      }
    }
#pragma unroll
    for (int i = 0; i < 8; i++) {
      const int u = up * 8 + i;
      if (u < U_) {
        float* row = out + ((size_t)b * L_ + topl[u]) * DM_ + j4;
        atomicAdd(row + 0, a[i].x); atomicAdd(row + 1, a[i].y);
        atomicAdd(row + 2, a[i].z); atomicAdd(row + 3, a[i].w);
      }
    }
  }
}

extern "C" void kernel_launch(void* const* d_in, const int* in_sizes, int n_in,
                              void* d_out, int out_size, void* d_ws, size_t ws_size,
                              hipStream_t stream) {
  const float* queries = (const float*)d_in[0];
  const float* keys    = (const float*)d_in[1];
  const float* values  = (const float*)d_in[2];
  const float* Wq = (const float*)d_in[3]; const float* bq = (const float*)d_in[4];
  const float* Wk = (const float*)d_in[5]; const float* bk = (const float*)d_in[6];
  const float* Wv = (const float*)d_in[7]; const float* bv = (const float*)d_in[8];
  const float* Wo = (const float*)d_in[9]; const float* bo = (const float*)d_in[10];
  const int* sidx = (const int*)d_in[11];

  // K,V live as bf16 in d_out (67.1 MB each) until the epilogue
  unsigned short* Kbf = (unsigned short*)d_out;
  unsigned short* Vbf = Kbf + (size_t)ML_ * DM_;

  uint8_t* p = (uint8_t*)d_ws;
  auto carve = [&](size_t bytes) { uint8_t* r = p; p += (bytes + 255) & ~(size_t)255; return r; };
  unsigned short* Xqh = (unsigned short*)carve((size_t)CROWS_ * DM_ * 2);   // 33.6 MB
  unsigned short* Xkh = (unsigned short*)carve((size_t)CROWS_ * DM_ * 2);
  unsigned short* Xvh = (unsigned short*)carve((size_t)CROWS_ * DM_ * 2);
  float* QKs = (float*)carve((size_t)CROWS_ * NP_ * 4);                     // 50.3 MB
  unsigned short* Ph = (unsigned short*)carve((size_t)B_ * NP_ * DM_ * 2);  // 12.6 MB
  unsigned short* WkT = (unsigned short*)carve((size_t)DM_ * DM_ * 2);
  unsigned short* WvT = (unsigned short*)carve((size_t)DM_ * DM_ * 2);
  float* Mbuf  = (float*)carve((size_t)BH_ * L_ * 4);                       // 2.1 MB
  float* Ksamp = (float*)carve((size_t)BH_ * U_ * 64 * 4);                  // 1.5 MB
  int*   list  = (int*)carve((size_t)BH_ * CAP_ * 4);                       // 256 KB
  float* candM = (float*)carve((size_t)BH_ * CAP_ * 4);                     // 256 KB
  int*   cntb  = (int*)carve((size_t)BH_ * 4);
  int*   topidx = (int*)carve((size_t)BH_ * U_ * 4);
  float* Vm    = (float*)carve((size_t)BH_ * 64 * 4);
  unsigned short* Qbf = (unsigned short*)carve((size_t)BH_ * 48 * 64 * 2);  // 786 KB
  const size_t need = (size_t)(p - (uint8_t*)d_ws);
  if (ws_size < need)
    fprintf(stderr, "ATHENA_WS: need %zu have %zu (WILL FAULT)\n", need, ws_size);

  // late-phase buffers alias QKs (dead after mpass)
  uint8_t* ap = (uint8_t*)QKs;
  auto acarve = [&](size_t bytes) { uint8_t* r = ap; ap += (bytes + 255) & ~(size_t)255; return r; };
  float* part  = (float*)acarve((size_t)BH_ * NSPLIT * U_ * 65 * 4);        // 12 MB
  float* dctx  = (float*)acarve((size_t)BH_ * U_ * 64 * 4);
  float* vpart = (float*)acarve((size_t)B_ * 64 * DM_ * 4);                 // 2.1 MB
  float* base  = (float*)acarve((size_t)B_ * DM_ * 4);

  ksel2<<<dim3(4, B_, 3), 256, 0, stream>>>(keys, Wk, bk, sidx, Ksamp);
  pform_k<<<BH_, 256, 0, stream>>>(Wq, Ksamp, Ph);
  wT_single<<<4096, 256, 0, stream>>>(Wk, WkT);
  wT_single<<<4096, 256, 0, stream>>>(Wv, WvT);

  const int n4 = (int)((size_t)CROWS_ * DM_ / 4);
  for (int c = 0; c < 2; c++) {
    const size_t off = (size_t)c * CROWS_ * DM_;
    split3h<<<dim3(2048, 3), 256, 0, stream>>>(queries + off, keys + off, values + off,
                                               Xqh, Xkh, Xvh, n4);
    gemm_plain<<<dim3(8, 128), 256, 0, stream>>>(Xkh, WkT, bk, Kbf + off);
    gemm_plain<<<dim3(8, 128), 256, 0, stream>>>(Xvh, WvT, bv, Vbf + off);
    gemm_qk1<<<dim3(6, 128), 256, 0, stream>>>(Xqh, Ph, QKs, c);
    mpass_k<<<(CROWS_ * 16) / 256, 256, 0, stream>>>(QKs, Mbuf, c);
  }

  select_a<<<BH_, 256, 0, stream>>>(Mbuf, list, cntb);
  exactM2<<<dim3(BH_, 8), 256, 0, stream>>>(queries, Wq, bq, Ksamp, list, cntb, candM);
  select_b<<<BH_, 256, 0, stream>>>(candM, list, cntb, topidx);
  qsel2<<<dim3(BH_, 3), 256, 0, stream>>>(queries, Wq, bq, topidx, Qbf);
  vmean_partial<<<dim3(DM_ / 256, 64, B_), 256, 0, stream>>>(Vbf, vpart);
  vmean_combine<<<(B_ * DM_) / 256, 256, 0, stream>>>(vpart, Vm);
  attn_stage1<<<dim3(BH_, NSPLIT), 256, 0, stream>>>(Qbf, Kbf, Vbf, part);
  attn_stage2<<<BH_, 256, 0, stream>>>(part, Vm, dctx);
  base_k<<<dim3(DM_ / 256, B_), 256, 0, stream>>>(Vm, Wo, bo, base);
  fill_out<<<(int)((size_t)ML_ * DM_ / 4 / 256), 256, 0, stream>>>(base, (float*)d_out);
  scatter_k<<<BH_, 256, 0, stream>>>(dctx, Wo, topidx, (float*)d_out);
}

// Round 8
// 1205.634 us; speedup vs baseline: 1.7755x; 1.0714x over previous
//
#include <hip/hip_runtime.h>
#include <cstdint>
#include <cstdio>

#define B_   8
#define L_   4096
#define DM_  1024
#define H_   16
#define D_   64
#define U_   45
#define BH_  (B_*H_)
#define ML_  (B_*L_)
#define NSPLIT 8
#define NP_  768           // padded QK-sample width: 16 heads * 48
#define CB_  4             // batches per chunk
#define CROWS_ (CB_*L_)    // 16384 rows per chunk
#define CAP_ 512           // candidate cap per (b,h)
#define DELTA_ 0.12f       // exact-recompute band (~9 sigma of bf16 GEMM err)

using f32x4   = __attribute__((ext_vector_type(4))) float;
using short8  = __attribute__((ext_vector_type(8))) short;
using ushort8 = __attribute__((ext_vector_type(8))) unsigned short;

__device__ __forceinline__ unsigned short f2bf(float f) {
  uint32_t u = __float_as_uint(f);
  u += 0x7fffu + ((u >> 16) & 1u);      // RNE; inputs finite
  return (unsigned short)(u >> 16);
}
__device__ __forceinline__ float bf2f(unsigned short h) {
  return __uint_as_float(((uint32_t)h) << 16);
}

__device__ __forceinline__ void gload16(const void* g, void* l) {
  __builtin_amdgcn_global_load_lds((const __attribute__((address_space(1))) void*)g,
                                   (__attribute__((address_space(3))) void*)l,
                                   16, 0, 0);
}

// ---------- split: q,k,v -> bf16 hi only ----------
__global__ __launch_bounds__(256) void split3h(const float* __restrict__ q,
    const float* __restrict__ k, const float* __restrict__ v,
    unsigned short* __restrict__ Xqh, unsigned short* __restrict__ Xkh,
    unsigned short* __restrict__ Xvh, int n4) {
  const int z = blockIdx.y;
  const float* __restrict__ X = (z == 0) ? q : ((z == 1) ? k : v);
  unsigned short* __restrict__ O = (z == 0) ? Xqh : ((z == 1) ? Xkh : Xvh);
  int i = blockIdx.x * 256 + threadIdx.x;
  const int stride = gridDim.x * 256;
  for (; i < n4; i += stride) {
    const float4 w = ((const float4*)X)[i];
    ushort4 hv;
    hv.x = f2bf(w.x); hv.y = f2bf(w.y); hv.z = f2bf(w.z); hv.w = f2bf(w.w);
    ((ushort4*)O)[i] = hv;
  }
}

// ---------- W (KxN) -> W^T bf16 (NxK) ----------
__global__ __launch_bounds__(256) void wT_single(const float* __restrict__ W,
                                                 unsigned short* __restrict__ WT) {
  const int idx = blockIdx.x * 256 + threadIdx.x;   // 1M threads
  const int n = idx >> 10, kk = idx & 1023;
  WT[idx] = f2bf(W[kk * 1024 + n]);
}

// ---------- plain bf16 GEMM, bf16 out: C = bf16(X*W + bias) ----------
__global__ __launch_bounds__(256) void gemm_plain(const unsigned short* __restrict__ Agh,
    const unsigned short* __restrict__ Bgh, const float* __restrict__ bias,
    unsigned short* __restrict__ C) {
  constexpr int K = 1024, N = 1024;
  __shared__ unsigned short sA[128 * 32];
  __shared__ unsigned short sB[128 * 32];
  const int tid = threadIdx.x, wid = tid >> 6, lane = tid & 63;
  const int m0 = blockIdx.y * 128, n0 = blockIdx.x * 128;
  const int wr = wid >> 1, wc = wid & 1;
  const int fr = lane & 15, fq = lane >> 4;
  const int srow = lane >> 2, scol = (lane & 3) * 8;
  f32x4 acc[4][4];
#pragma unroll
  for (int i = 0; i < 4; i++)
#pragma unroll
    for (int j = 0; j < 4; j++) acc[i][j] = f32x4{0.f, 0.f, 0.f, 0.f};

  for (int k0 = 0; k0 < K; k0 += 32) {
#pragma unroll
    for (int c = 0; c < 2; c++) {
      const int ch = wid * 2 + c;
      const int row = ch * 16 + srow;
      gload16(Agh + (size_t)(m0 + row) * K + (k0 + scol), &sA[ch * 512]);
      gload16(Bgh + (size_t)(n0 + row) * K + (k0 + scol), &sB[ch * 512]);
    }
    __syncthreads();
    short8 ah[4], bh[4];
#pragma unroll
    for (int i = 0; i < 4; i++) {
      ah[i] = *(const short8*)&sA[(wr * 64 + i * 16 + fr) * 32 + fq * 8];
      bh[i] = *(const short8*)&sB[(wc * 64 + i * 16 + fr) * 32 + fq * 8];
    }
#pragma unroll
    for (int i = 0; i < 4; i++)
#pragma unroll
      for (int j = 0; j < 4; j++)
        acc[i][j] = __builtin_amdgcn_mfma_f32_16x16x32_bf16(ah[i], bh[j], acc[i][j], 0, 0, 0);
    __syncthreads();
  }
#pragma unroll
  for (int j = 0; j < 4; j++) {
    const int col = n0 + wc * 64 + j * 16 + fr;
    const float bv = bias[col];
#pragma unroll
    for (int i = 0; i < 4; i++) {
      const int row = m0 + wr * 64 + i * 16 + fq * 4;
#pragma unroll
      for (int r = 0; r < 4; r++) C[(size_t)(row + r) * N + col] = f2bf(acc[i][j][r] + bv);
    }
  }
}

// ---------- plain bf16 GEMM: QKs = Xq * P_b (fp32 out, N=768) ----------
__global__ __launch_bounds__(256) void gemm_qk1(const unsigned short* __restrict__ Agh,
    const unsigned short* __restrict__ Pall_h, float* __restrict__ C, int chunk) {
  constexpr int K = 1024;
  __shared__ unsigned short sA[128 * 32];
  __shared__ unsigned short sB[128 * 32];
  const int tid = threadIdx.x, wid = tid >> 6, lane = tid & 63;
  const int m0 = blockIdx.y * 128, n0 = blockIdx.x * 128;
  const int batch = chunk * CB_ + (blockIdx.y >> 5);
  const unsigned short* __restrict__ Bgh = Pall_h + (size_t)batch * NP_ * K;
  const int wr = wid >> 1, wc = wid & 1;
  const int fr = lane & 15, fq = lane >> 4;
  const int srow = lane >> 2, scol = (lane & 3) * 8;
  f32x4 acc[4][4];
#pragma unroll
  for (int i = 0; i < 4; i++)
#pragma unroll
    for (int j = 0; j < 4; j++) acc[i][j] = f32x4{0.f, 0.f, 0.f, 0.f};

  for (int k0 = 0; k0 < K; k0 += 32) {
#pragma unroll
    for (int c = 0; c < 2; c++) {
      const int ch = wid * 2 + c;
      const int row = ch * 16 + srow;
      gload16(Agh + (size_t)(m0 + row) * K + (k0 + scol), &sA[ch * 512]);
      gload16(Bgh + (size_t)(n0 + row) * K + (k0 + scol), &sB[ch * 512]);
    }
    __syncthreads();
    short8 ah[4], bh[4];
#pragma unroll
    for (int i = 0; i < 4; i++) {
      ah[i] = *(const short8*)&sA[(wr * 64 + i * 16 + fr) * 32 + fq * 8];
      bh[i] = *(const short8*)&sB[(wc * 64 + i * 16 + fr) * 32 + fq * 8];
    }
#pragma unroll
    for (int i = 0; i < 4; i++)
#pragma unroll
      for (int j = 0; j < 4; j++)
        acc[i][j] = __builtin_amdgcn_mfma_f32_16x16x32_bf16(ah[i], bh[j], acc[i][j], 0, 0, 0);
    __syncthreads();
  }
#pragma unroll
  for (int j = 0; j < 4; j++) {
    const int col = n0 + wc * 64 + j * 16 + fr;
#pragma unroll
    for (int i = 0; i < 4; i++) {
      const int row = m0 + wr * 64 + i * 16 + fq * 4;
#pragma unroll
      for (int r = 0; r < 4; r++) C[(size_t)(row + r) * NP_ + col] = acc[i][j][r];
    }
  }
}

// ---------- ksel3: exact fp32 sampled-K rows, split-K column-parallel ----------
// grid (4 col-stripes, B_, 3 ug * 4 kc); partials to kpart[kc][b][u][1024]
__global__ __launch_bounds__(256) void ksel3(const float* __restrict__ X,
    const float* __restrict__ Wk, const int* __restrict__ sidx,
    float* __restrict__ kpart) {
  const int t = threadIdx.x;
  const int col = blockIdx.x * 256 + t;
  const int b = blockIdx.y;
  const int ug = blockIdx.z >> 2, kc = blockIdx.z & 3;
  __shared__ float Xs[15][256];
  __shared__ int rows[15];
  if (t < 15) rows[t] = sidx[ug * 15 + t];
  __syncthreads();
#pragma unroll
  for (int i = 0; i < 15; i++)
    Xs[i][t] = X[((size_t)b * L_ + rows[i]) * DM_ + kc * 256 + t];
  __syncthreads();
  float acc[15];
#pragma unroll
  for (int r = 0; r < 15; r++) acc[r] = 0.f;
  for (int k4 = 0; k4 < 64; k4++) {
    const int kb = kc * 256 + k4 * 4;
    const float w0 = Wk[(size_t)(kb + 0) * DM_ + col];
    const float w1 = Wk[(size_t)(kb + 1) * DM_ + col];
    const float w2 = Wk[(size_t)(kb + 2) * DM_ + col];
    const float w3 = Wk[(size_t)(kb + 3) * DM_ + col];
#pragma unroll
    for (int r = 0; r < 15; r++) {
      const float4 x = *(const float4*)&Xs[r][k4 * 4];
      acc[r] += x.x * w0 + x.y * w1 + x.z * w2 + x.w * w3;
    }
  }
  float* dst = kpart + (((size_t)kc * B_ + b) * U_ + ug * 15) * 1024 + col;
#pragma unroll
  for (int r = 0; r < 15; r++) dst[(size_t)r * 1024] = acc[r];
}

// combine: Ksamp[(b*16+h)*U_+u][d] = sum_kc kpart + bias (fixed order)
__global__ __launch_bounds__(256) void ksel_comb(const float* __restrict__ kpart,
    const float* __restrict__ bk, float* __restrict__ Ksamp) {
  const int idx = blockIdx.x * 256 + threadIdx.x;   // < 360*1024
  const int col = idx & 1023, ru = idx >> 10;
  const int b = ru / U_, u = ru - b * U_;
  const size_t o = ((size_t)b * U_ + u) * 1024 + col;
  const size_t stride = (size_t)B_ * U_ * 1024;
  float s = kpart[o] + kpart[o + stride] + kpart[o + 2 * stride] + kpart[o + 3 * stride]
          + bk[col];
  const int h = col >> 6, d = col & 63;
  Ksamp[((size_t)(b * 16 + h) * U_ + u) * 64 + d] = s;
}

// ---------- P^T[b][h*48+u][k] = sum_d Wq[k][h*64+d]*Ksamp (bf16 hi) ----------
__global__ __launch_bounds__(256) void pform_k(const float* __restrict__ Wq,
    const float* __restrict__ Ksamp, unsigned short* __restrict__ Ph) {
  const int bh = blockIdx.x, b = bh >> 4, h = bh & 15;
  __shared__ float Ks[U_][68];
  const int t = threadIdx.x;
  for (int e = t; e < U_ * 64; e += 256) {
    const int u = e >> 6, d = e & 63;
    Ks[u][d] = Ksamp[((size_t)bh * U_ + u) * 64 + d];
  }
  __syncthreads();
  for (int kc = 0; kc < 4; kc++) {
    const int k = kc * 256 + t;
    float wr[64];
#pragma unroll
    for (int dd = 0; dd < 16; dd++) {
      const float4 w4 = *(const float4*)&Wq[(size_t)k * DM_ + h * 64 + dd * 4];
      wr[dd * 4 + 0] = w4.x; wr[dd * 4 + 1] = w4.y;
      wr[dd * 4 + 2] = w4.z; wr[dd * 4 + 3] = w4.w;
    }
    for (int u = 0; u < 48; u++) {
      size_t o = ((size_t)b * NP_ + h * 48 + u) * 1024 + k;
      if (u < U_) {
        float acc = 0.f;
#pragma unroll
        for (int d = 0; d < 64; d++) acc += wr[d] * Ks[u][d];
        Ph[o] = f2bf(acc);
      } else {
        Ph[o] = 0;
      }
    }
  }
}

// ---------- M_approx = max - mean over u ----------
__global__ __launch_bounds__(256) void mpass_k(const float* __restrict__ QKs,
                                               float* __restrict__ Mbuf, int chunk) {
  const int idx = blockIdx.x * 256 + threadIdx.x;   // < CROWS_*16
  const int ll = idx >> 4, h = idx & 15;
  const float* row = QKs + (size_t)ll * NP_ + h * 48;
  float mx = row[0], sm = row[0];
#pragma unroll
  for (int u = 1; u < U_; u++) { const float v = row[u]; mx = fmaxf(mx, v); sm += v; }
  const int lg = chunk * CROWS_ + ll;
  const int b = lg >> 12, l = lg & 4095;
  Mbuf[((size_t)(b * 16 + h)) * L_ + l] = mx - sm * (1.f / (float)U_);
}

// ---------- select_a: approx top-45 -> thr; candidates = {M >= thr - DELTA} ----------
__global__ __launch_bounds__(256) void select_a(const float* __restrict__ Mbuf,
    int* __restrict__ list, int* __restrict__ cnt) {
  const int bh = blockIdx.x, t = threadIdx.x;
  __shared__ float vals[L_];
  __shared__ float rv[256];
  __shared__ int   ri[256];
  __shared__ int   scnt;
  __shared__ float sthr;
  if (t == 0) scnt = 0;
  for (int i = t; i < L_; i += 256) vals[i] = Mbuf[(size_t)bh * L_ + i];
  __syncthreads();
  for (int it = 0; it < U_; it++) {
    float bv = vals[t * 16]; int bi = t * 16;
#pragma unroll
    for (int jj = 1; jj < 16; jj++) {
      const float v = vals[t * 16 + jj];
      if (v > bv) { bv = v; bi = t * 16 + jj; }
    }
    rv[t] = bv; ri[t] = bi;
    __syncthreads();
    for (int s = 128; s > 0; s >>= 1) {
      if (t < s) {
        if (rv[t + s] > rv[t] || (rv[t + s] == rv[t] && ri[t + s] < ri[t])) {
          rv[t] = rv[t + s]; ri[t] = ri[t + s];
        }
      }
      __syncthreads();
    }
    if (t == 0) {
      list[(size_t)bh * CAP_ + it] = ri[0];
      vals[ri[0]] = -3.4e38f;
      if (it == U_ - 1) sthr = rv[0];
    }
    __syncthreads();
  }
  const float lim = sthr - DELTA_;
  for (int i = t; i < L_; i += 256) {
    if (vals[i] >= lim) {
      const int j = atomicAdd(&scnt, 1);
      if (U_ + j < CAP_) list[(size_t)bh * CAP_ + U_ + j] = i;
    }
  }
  __syncthreads();
  if (t == 0) cnt[bh] = min(U_ + scnt, CAP_);
}

// ---------- exactM2: fp32 recompute of M for candidates, 8 per block-group ----------
__global__ __launch_bounds__(256) void exactM2(const float* __restrict__ X,
    const float* __restrict__ Wq, const float* __restrict__ bq,
    const float* __restrict__ Ksamp, const int* __restrict__ list,
    const int* __restrict__ cnt, float* __restrict__ candM) {
  const int bh = blockIdx.x, g = blockIdx.y, b = bh >> 4, h = bh & 15;
  __shared__ float Ks[U_][68];
  __shared__ float Xs[8][256];
  __shared__ float red[4][8][64];
  __shared__ float qd[8][68];
  __shared__ float sc[8][45];
  __shared__ int rows[8];
  const int t = threadIdx.x, p = t >> 6, d = t & 63;
  for (int e = t; e < U_ * 64; e += 256) {
    const int u = e >> 6, dd = e & 63;
    Ks[u][dd] = Ksamp[((size_t)bh * U_ + u) * 64 + dd];
  }
  const int n = cnt[bh];
  for (int c0 = g * 8; c0 < n; c0 += 64) {
    const int nc = min(8, n - c0);
    __syncthreads();
    if (t < 8) rows[t] = list[(size_t)bh * CAP_ + c0 + min(t, nc - 1)];
    float acc[8];
#pragma unroll
    for (int r = 0; r < 8; r++) acc[r] = 0.f;
    for (int kc = 0; kc < 4; kc++) {
      __syncthreads();
#pragma unroll
      for (int i = 0; i < 8; i++)
        Xs[i][t] = X[((size_t)b * L_ + rows[i]) * DM_ + kc * 256 + t];
      __syncthreads();
#pragma unroll
      for (int k4 = 0; k4 < 16; k4++) {
        const int kb = kc * 256 + p * 64 + k4 * 4;
        const float w0 = Wq[(size_t)(kb + 0) * DM_ + h * 64 + d];
        const float w1 = Wq[(size_t)(kb + 1) * DM_ + h * 64 + d];
        const float w2 = Wq[(size_t)(kb + 2) * DM_ + h * 64 + d];
        const float w3 = Wq[(size_t)(kb + 3) * DM_ + h * 64 + d];
#pragma unroll
        for (int r = 0; r < 8; r++) {
          const float4 x = *(const float4*)&Xs[r][p * 64 + k4 * 4];
          acc[r] += x.x * w0 + x.y * w1 + x.z * w2 + x.w * w3;
        }
      }
    }
#pragma unroll
    for (int r = 0; r < 8; r++) red[p][r][d] = acc[r];
    __syncthreads();
    if (p == 0) {
#pragma unroll
      for (int r = 0; r < 8; r++)
        qd[r][d] = red[0][r][d] + red[1][r][d] + red[2][r][d] + red[3][r][d] + bq[h * 64 + d];
    }
    __syncthreads();
    for (int idx = t; idx < 8 * U_; idx += 256) {
      const int c = idx / U_, u = idx - c * U_;
      float s = 0.f;
#pragma unroll 8
      for (int dd = 0; dd < 64; dd++) s += qd[c][dd] * Ks[u][dd];
      sc[c][u] = s;
    }
    __syncthreads();
    if (t < nc) {
      float mx = sc[t][0], sm = sc[t][0];
      for (int u = 1; u < U_; u++) { mx = fmaxf(mx, sc[t][u]); sm += sc[t][u]; }
      candM[(size_t)bh * CAP_ + c0 + t] = mx - sm * (1.f / (float)U_);
    }
  }
}

// ---------- select_b: final top-45 over candidates (exact M, idx tie-break) ----------
__global__ __launch_bounds__(256) void select_b(const float* __restrict__ candM,
    const int* __restrict__ list, const int* __restrict__ cnt, int* __restrict__ topidx) {
  const int bh = blockIdx.x, t = threadIdx.x;
  __shared__ float mv[CAP_];
  __shared__ int   ml[CAP_];
  __shared__ float rv[256];
  __shared__ int   ri[256];
  const int n = cnt[bh];
  for (int i = t; i < CAP_; i += 256) {
    mv[i] = (i < n) ? candM[(size_t)bh * CAP_ + i] : -3.4e38f;
    ml[i] = (i < n) ? list[(size_t)bh * CAP_ + i] : 0x7fffffff;
  }
  __syncthreads();
  for (int it = 0; it < U_; it++) {
    float bv = mv[t]; int bi = ml[t]; int bj = t;
    {
      const float v = mv[t + 256]; const int l2 = ml[t + 256];
      if (v > bv || (v == bv && l2 < bi)) { bv = v; bi = l2; bj = t + 256; }
    }
    rv[t] = bv; ri[t] = bj;
    __syncthreads();
    for (int s = 128; s > 0; s >>= 1) {
      if (t < s) {
        const float v2 = rv[t + s];
        const int slot2 = ri[t + s];
        if (v2 > rv[t] || (v2 == rv[t] && ml[slot2] < ml[ri[t]])) {
          rv[t] = v2; ri[t] = slot2;
        }
      }
      __syncthreads();
    }
    if (t == 0) {
      topidx[bh * U_ + it] = ml[ri[0]];
      mv[ri[0]] = -3.4e38f;
    }
    __syncthreads();
  }
}

// ---------- qsel2: exact selected Q rows -> bf16, column-parallel ----------
__global__ __launch_bounds__(256) void qsel2(const float* __restrict__ X,
    const float* __restrict__ Wq, const float* __restrict__ bq,
    const int* __restrict__ topidx, unsigned short* __restrict__ Qbf) {
  const int bh = blockIdx.x, ug = blockIdx.y;
  const int b = bh >> 4, h = bh & 15;
  __shared__ float Xs[15][256];
  __shared__ float red[4][15][64];
  __shared__ int rows[15];
  const int t = threadIdx.x, p = t >> 6, d = t & 63;
  if (t < 15) rows[t] = topidx[bh * U_ + ug * 15 + t];
  float acc[15];
#pragma unroll
  for (int r = 0; r < 15; r++) acc[r] = 0.f;
  for (int kc = 0; kc < 4; kc++) {
    __syncthreads();
#pragma unroll
    for (int i = 0; i < 15; i++)
      Xs[i][t] = X[((size_t)b * L_ + rows[i]) * DM_ + kc * 256 + t];
    __syncthreads();
#pragma unroll
    for (int k4 = 0; k4 < 16; k4++) {
      const int kb = kc * 256 + p * 64 + k4 * 4;
      const float w0 = Wq[(size_t)(kb + 0) * DM_ + h * 64 + d];
      const float w1 = Wq[(size_t)(kb + 1) * DM_ + h * 64 + d];
      const float w2 = Wq[(size_t)(kb + 2) * DM_ + h * 64 + d];
      const float w3 = Wq[(size_t)(kb + 3) * DM_ + h * 64 + d];
#pragma unroll
      for (int r = 0; r < 15; r++) {
        const float4 x = *(const float4*)&Xs[r][p * 64 + k4 * 4];
        acc[r] += x.x * w0 + x.y * w1 + x.z * w2 + x.w * w3;
      }
    }
  }
#pragma unroll
  for (int r = 0; r < 15; r++) red[p][r][d] = acc[r];
  __syncthreads();
  if (p == 0) {
    const float bias = bq[h * 64 + d];
#pragma unroll
    for (int r = 0; r < 15; r++)
      Qbf[((size_t)bh * 48 + ug * 15 + r) * 64 + d] =
          f2bf(red[0][r][d] + red[1][r][d] + red[2][r][d] + red[3][r][d] + bias);
  }
  if (ug == 2 && t < 192) Qbf[((size_t)bh * 48 + U_) * 64 + t] = 0;  // pad rows 45..47
}

// ---------- V mean from bf16 V ----------
__global__ __launch_bounds__(256) void vmean_partial(const unsigned short* __restrict__ Vbf,
                                                     float* __restrict__ partial) {
  const int col = blockIdx.x * 256 + threadIdx.x;
  const int s = blockIdx.y, b = blockIdx.z;
  const unsigned short* src = Vbf + ((size_t)b * L_ + s * 64) * DM_ + col;
  float acc = 0.f;
#pragma unroll 8
  for (int l = 0; l < 64; l++) acc += bf2f(src[(size_t)l * DM_]);
  partial[((size_t)b * 64 + s) * DM_ + col] = acc;
}
__global__ __launch_bounds__(256) void vmean_combine(const float* __restrict__ partial,
                                                     float* __restrict__ Vm) {
  const int idx = blockIdx.x * 256 + threadIdx.x;  // 8192
  const int b = idx >> 10, col = idx & 1023;
  float acc = 0.f;
  for (int s = 0; s < 64; s++) acc += partial[((size_t)b * 64 + s) * DM_ + col];
  Vm[idx] = acc * (1.f / (float)L_);
}

// ---------- stage1: MFMA QK^T (swapped), VALU softmax+PV; no-max softmax ----------
__global__ __launch_bounds__(256) void attn_stage1(const unsigned short* __restrict__ Qbf,
    const unsigned short* __restrict__ Kbf, const unsigned short* __restrict__ Vbf,
    float* __restrict__ part) {
  const int bh = blockIdx.x, split = blockIdx.y;
  const int b = bh >> 4, h = bh & 15;
  __shared__ unsigned short sQ[48][72];
  __shared__ unsigned short sK[64][72];
  __shared__ unsigned short sV[64][72];
  __shared__ float es[64][52];
  const int tid = threadIdx.x, wid = tid >> 6, lane = tid & 63;
  const int fr = lane & 15, fq = lane >> 4;
  for (int e = tid; e < 48 * 8; e += 256) {
    const int r = e >> 3, c8 = (e & 7) * 8;
    *(ushort8*)&sQ[r][c8] = *(const ushort8*)&Qbf[((size_t)bh * 48 + r) * 64 + c8];
  }
  __syncthreads();
  short8 qf[3][2];
#pragma unroll
  for (int nt = 0; nt < 3; nt++)
#pragma unroll
    for (int kh = 0; kh < 2; kh++)
      qf[nt][kh] = *(const short8*)&sQ[nt * 16 + fr][kh * 32 + fq * 8];

  float S[12], ctx[12];
#pragma unroll
  for (int i = 0; i < 12; i++) { S[i] = 0.f; ctx[i] = 0.f; }

  for (int t = 0; t < 8; t++) {
    const int k0 = split * 512 + t * 64;
    if (t) __syncthreads();                 // prev tile's es/sV fully consumed
    for (int e = tid; e < 64 * 8; e += 256) {
      const int r = e >> 3, c8 = (e & 7) * 8;
      const size_t gsrc = ((size_t)b * L_ + k0 + r) * DM_ + h * 64 + c8;
      *(ushort8*)&sK[r][c8] = *(const ushort8*)&Kbf[gsrc];
      *(ushort8*)&sV[r][c8] = *(const ushort8*)&Vbf[gsrc];
    }
    __syncthreads();
    // QK^T: this wave's 16 keys (m = wid*16..+15), all 48 q (3 n-tiles)
    short8 kf0 = *(const short8*)&sK[wid * 16 + fr][fq * 8];
    short8 kf1 = *(const short8*)&sK[wid * 16 + fr][32 + fq * 8];
    f32x4 accq[3];
#pragma unroll
    for (int nt = 0; nt < 3; nt++) {
      accq[nt] = f32x4{0.f, 0.f, 0.f, 0.f};
      accq[nt] = __builtin_amdgcn_mfma_f32_16x16x32_bf16(kf0, qf[nt][0], accq[nt], 0, 0, 0);
      accq[nt] = __builtin_amdgcn_mfma_f32_16x16x32_bf16(kf1, qf[nt][1], accq[nt], 0, 0, 0);
    }
    // es[key][q] = exp(score/8); |score| bounded (~3.3) -> no max subtraction
#pragma unroll
    for (int nt = 0; nt < 3; nt++)
#pragma unroll
      for (int r = 0; r < 4; r++)
        es[wid * 16 + fq * 4 + r][nt * 16 + fr] = expf(accq[nt][r] * 0.125f);
    __syncthreads();
    // PV + S: this wave's 12 q (q = wid*12..+11), lane = d
    const int q0 = wid * 12;
    for (int k = 0; k < 64; k++) {
      const float v = bf2f(sV[k][lane]);
      const float4 e0 = *(const float4*)&es[k][q0];
      const float4 e1 = *(const float4*)&es[k][q0 + 4];
      const float4 e2 = *(const float4*)&es[k][q0 + 8];
      S[0] += e0.x; S[1] += e0.y; S[2]  += e0.z; S[3]  += e0.w;
      S[4] += e1.x; S[5] += e1.y; S[6]  += e1.z; S[7]  += e1.w;
      S[8] += e2.x; S[9] += e2.y; S[10] += e2.z; S[11] += e2.w;
      ctx[0] += e0.x * v; ctx[1] += e0.y * v; ctx[2]  += e0.z * v; ctx[3]  += e0.w * v;
      ctx[4] += e1.x * v; ctx[5] += e1.y * v; ctx[6]  += e1.z * v; ctx[7]  += e1.w * v;
      ctx[8] += e2.x * v; ctx[9] += e2.y * v; ctx[10] += e2.z * v; ctx[11] += e2.w * v;
    }
  }
#pragma unroll
  for (int i = 0; i < 12; i++) {
    const int u = wid * 12 + i;
    if (u < U_) {
      float* pb = part + ((size_t)(bh * NSPLIT + split) * U_ + u) * 65;
      if (lane == 0) pb[0] = S[i];
      pb[1 + lane] = ctx[i];
    }
  }
}

// ---------- combine splits; dctx = ctx/S - Vmean ----------
__global__ __launch_bounds__(256) void attn_stage2(const float* __restrict__ part,
    const float* __restrict__ Vm, float* __restrict__ dctx) {
  const int bh = blockIdx.x;
  const int wid = threadIdx.x >> 6, lane = threadIdx.x & 63;
  for (int u = wid; u < U_; u += 4) {
    float S = 0.f, c = 0.f;
#pragma unroll
    for (int sp = 0; sp < NSPLIT; sp++) {
      const float* pb = part + ((size_t)(bh * NSPLIT + sp) * U_ + u) * 65;
      S += pb[0];
      c += pb[1 + lane];
    }
    dctx[((size_t)bh * U_ + u) * 64 + lane] = c / S - Vm[bh * 64 + lane];
  }
}

// ---------- base[b][:] = concat_h(Vmean) @ Wo + bo ----------
__global__ __launch_bounds__(256) void base_k(const float* __restrict__ Vm,
    const float* __restrict__ Wo, const float* __restrict__ bo, float* __restrict__ base) {
  const int b = blockIdx.y;
  const int j = blockIdx.x * 256 + threadIdx.x;
  float acc = bo[j];
#pragma unroll 8
  for (int i = 0; i < DM_; i++) acc += Vm[b * DM_ + i] * Wo[(size_t)i * DM_ + j];
  base[b * DM_ + j] = acc;
}

// ---------- out[b,l,:] = base[b,:] ----------
__global__ __launch_bounds__(256) void fill_out(const float* __restrict__ base,
                                                float* __restrict__ out) {
  const size_t g = ((size_t)blockIdx.x * 256 + threadIdx.x) * 4;
  const int b = (int)(g >> 22), j = (int)(g & 1023);
  *(float4*)&out[g] = *(const float4*)&base[(b << 10) + j];
}

// ---------- out += (ctx-Vmean) @ Wo_block[h] on selected rows ----------
__global__ __launch_bounds__(256) void scatter_k(const float* __restrict__ dctx,
    const float* __restrict__ Wo, const int* __restrict__ topidx, float* __restrict__ out) {
  const int bh = blockIdx.x, b = bh >> 4, h = bh & 15;
  __shared__ float dc[U_ * 64];
  __shared__ int topl[U_];
  for (int e = threadIdx.x; e < U_ * 64; e += 256) dc[e] = dctx[(size_t)bh * U_ * 64 + e];
  if (threadIdx.x < U_) topl[threadIdx.x] = topidx[bh * U_ + threadIdx.x];
  __syncthreads();
  const int j4 = threadIdx.x * 4;
  for (int up = 0; up < 6; up++) {
    f32x4 a[8];
#pragma unroll
    for (int i = 0; i < 8; i++) a[i] = f32x4{0.f, 0.f, 0.f, 0.f};
    for (int d = 0; d < 64; d++) {
      const float4 w = *(const float4*)&Wo[(size_t)(h * 64 + d) * DM_ + j4];
#pragma unroll
      for (int i = 0; i < 8; i++) {
        const int u = up * 8 + i;
        if (u < U_) {
          const float cc = dc[u * 64 + d];
          a[i].x += cc * w.x; a[i].y += cc * w.y; a[i].z += cc * w.z; a[i].w += cc * w.w;
        }
      }
    }
#pragma unroll
    for (int i = 0; i < 8; i++) {
      const int u = up * 8 + i;
      if (u < U_) {
        float* row = out + ((size_t)b * L_ + topl[u]) * DM_ + j4;
        atomicAdd(row + 0, a[i].x); atomicAdd(row + 1, a[i].y);
        atomicAdd(row + 2, a[i].z); atomicAdd(row + 3, a[i].w);
      }
    }
  }
}

extern "C" void kernel_launch(void* const* d_in, const int* in_sizes, int n_in,
                              void* d_out, int out_size, void* d_ws, size_t ws_size,
                              hipStream_t stream) {
  const float* queries = (const float*)d_in[0];
  const float* keys    = (const float*)d_in[1];
  const float* values  = (const float*)d_in[2];
  const float* Wq = (const float*)d_in[3]; const float* bq = (const float*)d_in[4];
  const float* Wk = (const float*)d_in[5]; const float* bk = (const float*)d_in[6];
  const float* Wv = (const float*)d_in[7]; const float* bv = (const float*)d_in[8];
  const float* Wo = (const float*)d_in[9]; const float* bo = (const float*)d_in[10];
  const int* sidx = (const int*)d_in[11];

  // K,V live as bf16 in d_out (67.1 MB each) until the epilogue
  unsigned short* Kbf = (unsigned short*)d_out;
  unsigned short* Vbf = Kbf + (size_t)ML_ * DM_;

  uint8_t* p = (uint8_t*)d_ws;
  auto carve = [&](size_t bytes) { uint8_t* r = p; p += (bytes + 255) & ~(size_t)255; return r; };
  unsigned short* Xqh = (unsigned short*)carve((size_t)CROWS_ * DM_ * 2);   // 33.6 MB
  unsigned short* Xkh = (unsigned short*)carve((size_t)CROWS_ * DM_ * 2);
  unsigned short* Xvh = (unsigned short*)carve((size_t)CROWS_ * DM_ * 2);
  float* QKs = (float*)carve((size_t)CROWS_ * NP_ * 4);                     // 50.3 MB
  unsigned short* Ph = (unsigned short*)carve((size_t)B_ * NP_ * DM_ * 2);  // 12.6 MB
  unsigned short* WkT = (unsigned short*)carve((size_t)DM_ * DM_ * 2);
  unsigned short* WvT = (unsigned short*)carve((size_t)DM_ * DM_ * 2);
  float* Mbuf  = (float*)carve((size_t)BH_ * L_ * 4);                       // 2.1 MB
  float* Ksamp = (float*)carve((size_t)BH_ * U_ * 64 * 4);                  // 1.5 MB
  float* kpart = (float*)carve((size_t)4 * B_ * U_ * 1024 * 4);             // 5.9 MB
  int*   list  = (int*)carve((size_t)BH_ * CAP_ * 4);                       // 256 KB
  float* candM = (float*)carve((size_t)BH_ * CAP_ * 4);                     // 256 KB
  int*   cntb  = (int*)carve((size_t)BH_ * 4);
  int*   topidx = (int*)carve((size_t)BH_ * U_ * 4);
  float* Vm    = (float*)carve((size_t)BH_ * 64 * 4);
  unsigned short* Qbf = (unsigned short*)carve((size_t)BH_ * 48 * 64 * 2);  // 786 KB
  const size_t need = (size_t)(p - (uint8_t*)d_ws);
  if (ws_size < need)
    fprintf(stderr, "ATHENA_WS: need %zu have %zu (WILL FAULT)\n", need, ws_size);

  // late-phase buffers alias QKs (dead after mpass)
  uint8_t* ap = (uint8_t*)QKs;
  auto acarve = [&](size_t bytes) { uint8_t* r = ap; ap += (bytes + 255) & ~(size_t)255; return r; };
  float* part  = (float*)acarve((size_t)BH_ * NSPLIT * U_ * 65 * 4);        // 12 MB
  float* dctx  = (float*)acarve((size_t)BH_ * U_ * 64 * 4);
  float* vpart = (float*)acarve((size_t)B_ * 64 * DM_ * 4);                 // 2.1 MB
  float* base  = (float*)acarve((size_t)B_ * DM_ * 4);

  ksel3<<<dim3(4, B_, 12), 256, 0, stream>>>(keys, Wk, sidx, kpart);
  ksel_comb<<<(B_ * U_ * 1024) / 256, 256, 0, stream>>>(kpart, bk, Ksamp);
  pform_k<<<BH_, 256, 0, stream>>>(Wq, Ksamp, Ph);
  wT_single<<<4096, 256, 0, stream>>>(Wk, WkT);
  wT_single<<<4096, 256, 0, stream>>>(Wv, WvT);

  const int n4 = (int)((size_t)CROWS_ * DM_ / 4);
  for (int c = 0; c < 2; c++) {
    const size_t off = (size_t)c * CROWS_ * DM_;
    split3h<<<dim3(2048, 3), 256, 0, stream>>>(queries + off, keys + off, values + off,
                                               Xqh, Xkh, Xvh, n4);
    gemm_plain<<<dim3(8, 128), 256, 0, stream>>>(Xkh, WkT, bk, Kbf + off);
    gemm_plain<<<dim3(8, 128), 256, 0, stream>>>(Xvh, WvT, bv, Vbf + off);
    gemm_qk1<<<dim3(6, 128), 256, 0, stream>>>(Xqh, Ph, QKs, c);
    mpass_k<<<(CROWS_ * 16) / 256, 256, 0, stream>>>(QKs, Mbuf, c);
  }

  select_a<<<BH_, 256, 0, stream>>>(Mbuf, list, cntb);
  exactM2<<<dim3(BH_, 8), 256, 0, stream>>>(queries, Wq, bq, Ksamp, list, cntb, candM);
  select_b<<<BH_, 256, 0, stream>>>(candM, list, cntb, topidx);
  qsel2<<<dim3(BH_, 3), 256, 0, stream>>>(queries, Wq, bq, topidx, Qbf);
  vmean_partial<<<dim3(DM_ / 256, 64, B_), 256, 0, stream>>>(Vbf, vpart);
  vmean_combine<<<(B_ * DM_) / 256, 256, 0, stream>>>(vpart, Vm);
  attn_stage1<<<dim3(BH_, NSPLIT), 256, 0, stream>>>(Qbf, Kbf, Vbf, part);
  attn_stage2<<<BH_, 256, 0, stream>>>(part, Vm, dctx);
  base_k<<<dim3(DM_ / 256, B_), 256, 0, stream>>>(Vm, Wo, bo, base);
  fill_out<<<(int)((size_t)ML_ * DM_ / 4 / 256), 256, 0, stream>>>(base, (float*)d_out);
  scatter_k<<<BH_, 256, 0, stream>>>(dctx, Wo, topidx, (float*)d_out);
}

// Round 9
// 1171.181 us; speedup vs baseline: 1.8278x; 1.0294x over previous
//
#include <hip/hip_runtime.h>
#include <cstdint>
#include <cstdio>

#define B_   8
#define L_   4096
#define DM_  1024
#define H_   16
#define D_   64
#define U_   45
#define BH_  (B_*H_)
#define ML_  (B_*L_)
#define NSPLIT 8
#define NP_  768           // padded QK-sample width: 16 heads * 48
#define CB_  4             // batches per chunk
#define CROWS_ (CB_*L_)    // 16384 rows per chunk
#define CAP_ 512           // candidate cap per (b,h)
#define DELTA_ 0.12f       // exact-recompute band (~9 sigma of bf16 GEMM err)

using f32x4   = __attribute__((ext_vector_type(4))) float;
using short8  = __attribute__((ext_vector_type(8))) short;
using ushort8 = __attribute__((ext_vector_type(8))) unsigned short;

__device__ __forceinline__ unsigned short f2bf(float f) {
  uint32_t u = __float_as_uint(f);
  u += 0x7fffu + ((u >> 16) & 1u);      // RNE; inputs finite
  return (unsigned short)(u >> 16);
}
__device__ __forceinline__ float bf2f(unsigned short h) {
  return __uint_as_float(((uint32_t)h) << 16);
}

__device__ __forceinline__ void gload16(const void* g, void* l) {
  __builtin_amdgcn_global_load_lds((const __attribute__((address_space(1))) void*)g,
                                   (__attribute__((address_space(3))) void*)l,
                                   16, 0, 0);
}

// ---------- split: q,k,v -> bf16 hi only ----------
__global__ __launch_bounds__(256) void split3h(const float* __restrict__ q,
    const float* __restrict__ k, const float* __restrict__ v,
    unsigned short* __restrict__ Xqh, unsigned short* __restrict__ Xkh,
    unsigned short* __restrict__ Xvh, int n4) {
  const int z = blockIdx.y;
  const float* __restrict__ X = (z == 0) ? q : ((z == 1) ? k : v);
  unsigned short* __restrict__ O = (z == 0) ? Xqh : ((z == 1) ? Xkh : Xvh);
  int i = blockIdx.x * 256 + threadIdx.x;
  const int stride = gridDim.x * 256;
  for (; i < n4; i += stride) {
    const float4 w = ((const float4*)X)[i];
    ushort4 hv;
    hv.x = f2bf(w.x); hv.y = f2bf(w.y); hv.z = f2bf(w.z); hv.w = f2bf(w.w);
    ((ushort4*)O)[i] = hv;
  }
}

// ---------- W (KxN) -> W^T bf16 (NxK) ----------
__global__ __launch_bounds__(256) void wT_single(const float* __restrict__ W,
                                                 unsigned short* __restrict__ WT) {
  const int idx = blockIdx.x * 256 + threadIdx.x;   // 1M threads
  const int n = idx >> 10, kk = idx & 1023;
  WT[idx] = f2bf(W[kk * 1024 + n]);
}

// ---------- plain bf16 GEMM, bf16 out: C = bf16(X*W + bias) ----------
__global__ __launch_bounds__(256) void gemm_plain(const unsigned short* __restrict__ Agh,
    const unsigned short* __restrict__ Bgh, const float* __restrict__ bias,
    unsigned short* __restrict__ C) {
  constexpr int K = 1024, N = 1024;
  __shared__ unsigned short sA[128 * 32];
  __shared__ unsigned short sB[128 * 32];
  const int tid = threadIdx.x, wid = tid >> 6, lane = tid & 63;
  const int m0 = blockIdx.y * 128, n0 = blockIdx.x * 128;
  const int wr = wid >> 1, wc = wid & 1;
  const int fr = lane & 15, fq = lane >> 4;
  const int srow = lane >> 2, scol = (lane & 3) * 8;
  f32x4 acc[4][4];
#pragma unroll
  for (int i = 0; i < 4; i++)
#pragma unroll
    for (int j = 0; j < 4; j++) acc[i][j] = f32x4{0.f, 0.f, 0.f, 0.f};

  for (int k0 = 0; k0 < K; k0 += 32) {
#pragma unroll
    for (int c = 0; c < 2; c++) {
      const int ch = wid * 2 + c;
      const int row = ch * 16 + srow;
      gload16(Agh + (size_t)(m0 + row) * K + (k0 + scol), &sA[ch * 512]);
      gload16(Bgh + (size_t)(n0 + row) * K + (k0 + scol), &sB[ch * 512]);
    }
    __syncthreads();
    short8 ah[4], bh[4];
#pragma unroll
    for (int i = 0; i < 4; i++) {
      ah[i] = *(const short8*)&sA[(wr * 64 + i * 16 + fr) * 32 + fq * 8];
      bh[i] = *(const short8*)&sB[(wc * 64 + i * 16 + fr) * 32 + fq * 8];
    }
#pragma unroll
    for (int i = 0; i < 4; i++)
#pragma unroll
      for (int j = 0; j < 4; j++)
        acc[i][j] = __builtin_amdgcn_mfma_f32_16x16x32_bf16(ah[i], bh[j], acc[i][j], 0, 0, 0);
    __syncthreads();
  }
#pragma unroll
  for (int j = 0; j < 4; j++) {
    const int col = n0 + wc * 64 + j * 16 + fr;
    const float bv = bias[col];
#pragma unroll
    for (int i = 0; i < 4; i++) {
      const int row = m0 + wr * 64 + i * 16 + fq * 4;
#pragma unroll
      for (int r = 0; r < 4; r++) C[(size_t)(row + r) * N + col] = f2bf(acc[i][j][r] + bv);
    }
  }
}

// ---------- plain bf16 GEMM: QKs = Xq * P_b (fp32 out, N=768) ----------
__global__ __launch_bounds__(256) void gemm_qk1(const unsigned short* __restrict__ Agh,
    const unsigned short* __restrict__ Pall_h, float* __restrict__ C, int chunk) {
  constexpr int K = 1024;
  __shared__ unsigned short sA[128 * 32];
  __shared__ unsigned short sB[128 * 32];
  const int tid = threadIdx.x, wid = tid >> 6, lane = tid & 63;
  const int m0 = blockIdx.y * 128, n0 = blockIdx.x * 128;
  const int batch = chunk * CB_ + (blockIdx.y >> 5);
  const unsigned short* __restrict__ Bgh = Pall_h + (size_t)batch * NP_ * K;
  const int wr = wid >> 1, wc = wid & 1;
  const int fr = lane & 15, fq = lane >> 4;
  const int srow = lane >> 2, scol = (lane & 3) * 8;
  f32x4 acc[4][4];
#pragma unroll
  for (int i = 0; i < 4; i++)
#pragma unroll
    for (int j = 0; j < 4; j++) acc[i][j] = f32x4{0.f, 0.f, 0.f, 0.f};

  for (int k0 = 0; k0 < K; k0 += 32) {
#pragma unroll
    for (int c = 0; c < 2; c++) {
      const int ch = wid * 2 + c;
      const int row = ch * 16 + srow;
      gload16(Agh + (size_t)(m0 + row) * K + (k0 + scol), &sA[ch * 512]);
      gload16(Bgh + (size_t)(n0 + row) * K + (k0 + scol), &sB[ch * 512]);
    }
    __syncthreads();
    short8 ah[4], bh[4];
#pragma unroll
    for (int i = 0; i < 4; i++) {
      ah[i] = *(const short8*)&sA[(wr * 64 + i * 16 + fr) * 32 + fq * 8];
      bh[i] = *(const short8*)&sB[(wc * 64 + i * 16 + fr) * 32 + fq * 8];
    }
#pragma unroll
    for (int i = 0; i < 4; i++)
#pragma unroll
      for (int j = 0; j < 4; j++)
        acc[i][j] = __builtin_amdgcn_mfma_f32_16x16x32_bf16(ah[i], bh[j], acc[i][j], 0, 0, 0);
    __syncthreads();
  }
#pragma unroll
  for (int j = 0; j < 4; j++) {
    const int col = n0 + wc * 64 + j * 16 + fr;
#pragma unroll
    for (int i = 0; i < 4; i++) {
      const int row = m0 + wr * 64 + i * 16 + fq * 4;
#pragma unroll
      for (int r = 0; r < 4; r++) C[(size_t)(row + r) * NP_ + col] = acc[i][j][r];
    }
  }
}

// ---------- ksel3: exact fp32 sampled-K rows, split-K column-parallel ----------
__global__ __launch_bounds__(256) void ksel3(const float* __restrict__ X,
    const float* __restrict__ Wk, const int* __restrict__ sidx,
    float* __restrict__ kpart) {
  const int t = threadIdx.x;
  const int col = blockIdx.x * 256 + t;
  const int b = blockIdx.y;
  const int ug = blockIdx.z >> 2, kc = blockIdx.z & 3;
  __shared__ float Xs[15][256];
  __shared__ int rows[15];
  if (t < 15) rows[t] = sidx[ug * 15 + t];
  __syncthreads();
#pragma unroll
  for (int i = 0; i < 15; i++)
    Xs[i][t] = X[((size_t)b * L_ + rows[i]) * DM_ + kc * 256 + t];
  __syncthreads();
  float acc[15];
#pragma unroll
  for (int r = 0; r < 15; r++) acc[r] = 0.f;
  for (int k4 = 0; k4 < 64; k4++) {
    const int kb = kc * 256 + k4 * 4;
    const float w0 = Wk[(size_t)(kb + 0) * DM_ + col];
    const float w1 = Wk[(size_t)(kb + 1) * DM_ + col];
    const float w2 = Wk[(size_t)(kb + 2) * DM_ + col];
    const float w3 = Wk[(size_t)(kb + 3) * DM_ + col];
#pragma unroll
    for (int r = 0; r < 15; r++) {
      const float4 x = *(const float4*)&Xs[r][k4 * 4];
      acc[r] += x.x * w0 + x.y * w1 + x.z * w2 + x.w * w3;
    }
  }
  float* dst = kpart + (((size_t)kc * B_ + b) * U_ + ug * 15) * 1024 + col;
#pragma unroll
  for (int r = 0; r < 15; r++) dst[(size_t)r * 1024] = acc[r];
}

// combine: Ksamp = sum_kc kpart + bias (fixed order)
__global__ __launch_bounds__(256) void ksel_comb(const float* __restrict__ kpart,
    const float* __restrict__ bk, float* __restrict__ Ksamp) {
  const int idx = blockIdx.x * 256 + threadIdx.x;   // < 360*1024
  const int col = idx & 1023, ru = idx >> 10;
  const int b = ru / U_, u = ru - b * U_;
  const size_t o = ((size_t)b * U_ + u) * 1024 + col;
  const size_t stride = (size_t)B_ * U_ * 1024;
  float s = kpart[o] + kpart[o + stride] + kpart[o + 2 * stride] + kpart[o + 3 * stride]
          + bk[col];
  const int h = col >> 6, d = col & 63;
  Ksamp[((size_t)(b * 16 + h) * U_ + u) * 64 + d] = s;
}

// ---------- P^T[b][h*48+u][k] = sum_d Wq[k][h*64+d]*Ksamp (bf16 hi) ----------
__global__ __launch_bounds__(256) void pform_k(const float* __restrict__ Wq,
    const float* __restrict__ Ksamp, unsigned short* __restrict__ Ph) {
  const int bh = blockIdx.x, b = bh >> 4, h = bh & 15;
  __shared__ float Ks[U_][68];
  const int t = threadIdx.x;
  for (int e = t; e < U_ * 64; e += 256) {
    const int u = e >> 6, d = e & 63;
    Ks[u][d] = Ksamp[((size_t)bh * U_ + u) * 64 + d];
  }
  __syncthreads();
  for (int kc = 0; kc < 4; kc++) {
    const int k = kc * 256 + t;
    float wr[64];
#pragma unroll
    for (int dd = 0; dd < 16; dd++) {
      const float4 w4 = *(const float4*)&Wq[(size_t)k * DM_ + h * 64 + dd * 4];
      wr[dd * 4 + 0] = w4.x; wr[dd * 4 + 1] = w4.y;
      wr[dd * 4 + 2] = w4.z; wr[dd * 4 + 3] = w4.w;
    }
    for (int u = 0; u < 48; u++) {
      size_t o = ((size_t)b * NP_ + h * 48 + u) * 1024 + k;
      if (u < U_) {
        float acc = 0.f;
#pragma unroll
        for (int d = 0; d < 64; d++) acc += wr[d] * Ks[u][d];
        Ph[o] = f2bf(acc);
      } else {
        Ph[o] = 0;
      }
    }
  }
}

// ---------- M_approx = max - mean over u ----------
__global__ __launch_bounds__(256) void mpass_k(const float* __restrict__ QKs,
                                               float* __restrict__ Mbuf, int chunk) {
  const int idx = blockIdx.x * 256 + threadIdx.x;   // < CROWS_*16
  const int ll = idx >> 4, h = idx & 15;
  const float* row = QKs + (size_t)ll * NP_ + h * 48;
  float mx = row[0], sm = row[0];
#pragma unroll
  for (int u = 1; u < U_; u++) { const float v = row[u]; mx = fmaxf(mx, v); sm += v; }
  const int lg = chunk * CROWS_ + ll;
  const int b = lg >> 12, l = lg & 4095;
  Mbuf[((size_t)(b * 16 + h)) * L_ + l] = mx - sm * (1.f / (float)U_);
}

// ---------- select_a: approx top-45 -> thr; candidates = {M >= thr - DELTA} ----------
__global__ __launch_bounds__(256) void select_a(const float* __restrict__ Mbuf,
    int* __restrict__ list, int* __restrict__ cnt) {
  const int bh = blockIdx.x, t = threadIdx.x;
  __shared__ float vals[L_];
  __shared__ float rv[256];
  __shared__ int   ri[256];
  __shared__ int   scnt;
  __shared__ float sthr;
  if (t == 0) scnt = 0;
  for (int i = t; i < L_; i += 256) vals[i] = Mbuf[(size_t)bh * L_ + i];
  __syncthreads();
  for (int it = 0; it < U_; it++) {
    float bv = vals[t * 16]; int bi = t * 16;
#pragma unroll
    for (int jj = 1; jj < 16; jj++) {
      const float v = vals[t * 16 + jj];
      if (v > bv) { bv = v; bi = t * 16 + jj; }
    }
    rv[t] = bv; ri[t] = bi;
    __syncthreads();
    for (int s = 128; s > 0; s >>= 1) {
      if (t < s) {
        if (rv[t + s] > rv[t] || (rv[t + s] == rv[t] && ri[t + s] < ri[t])) {
          rv[t] = rv[t + s]; ri[t] = ri[t + s];
        }
      }
      __syncthreads();
    }
    if (t == 0) {
      list[(size_t)bh * CAP_ + it] = ri[0];
      vals[ri[0]] = -3.4e38f;
      if (it == U_ - 1) sthr = rv[0];
    }
    __syncthreads();
  }
  const float lim = sthr - DELTA_;
  for (int i = t; i < L_; i += 256) {
    if (vals[i] >= lim) {
      const int j = atomicAdd(&scnt, 1);
      if (U_ + j < CAP_) list[(size_t)bh * CAP_ + U_ + j] = i;
    }
  }
  __syncthreads();
  if (t == 0) cnt[bh] = min(U_ + scnt, CAP_);
}

// ---------- exactM2: fp32 recompute of M for candidates ----------
__global__ __launch_bounds__(256) void exactM2(const float* __restrict__ X,
    const float* __restrict__ Wq, const float* __restrict__ bq,
    const float* __restrict__ Ksamp, const int* __restrict__ list,
    const int* __restrict__ cnt, float* __restrict__ candM) {
  const int bh = blockIdx.x, g = blockIdx.y, b = bh >> 4, h = bh & 15;
  __shared__ float Ks[U_][68];
  __shared__ float Xs[8][256];
  __shared__ float red[4][8][64];
  __shared__ float qd[8][68];
  __shared__ float sc[8][45];
  __shared__ int rows[8];
  const int t = threadIdx.x, p = t >> 6, d = t & 63;
  for (int e = t; e < U_ * 64; e += 256) {
    const int u = e >> 6, dd = e & 63;
    Ks[u][dd] = Ksamp[((size_t)bh * U_ + u) * 64 + dd];
  }
  const int n = cnt[bh];
  for (int c0 = g * 8; c0 < n; c0 += 64) {
    const int nc = min(8, n - c0);
    __syncthreads();
    if (t < 8) rows[t] = list[(size_t)bh * CAP_ + c0 + min(t, nc - 1)];
    float acc[8];
#pragma unroll
    for (int r = 0; r < 8; r++) acc[r] = 0.f;
    for (int kc = 0; kc < 4; kc++) {
      __syncthreads();
#pragma unroll
      for (int i = 0; i < 8; i++)
        Xs[i][t] = X[((size_t)b * L_ + rows[i]) * DM_ + kc * 256 + t];
      __syncthreads();
#pragma unroll
      for (int k4 = 0; k4 < 16; k4++) {
        const int kb = kc * 256 + p * 64 + k4 * 4;
        const float w0 = Wq[(size_t)(kb + 0) * DM_ + h * 64 + d];
        const float w1 = Wq[(size_t)(kb + 1) * DM_ + h * 64 + d];
        const float w2 = Wq[(size_t)(kb + 2) * DM_ + h * 64 + d];
        const float w3 = Wq[(size_t)(kb + 3) * DM_ + h * 64 + d];
#pragma unroll
        for (int r = 0; r < 8; r++) {
          const float4 x = *(const float4*)&Xs[r][p * 64 + k4 * 4];
          acc[r] += x.x * w0 + x.y * w1 + x.z * w2 + x.w * w3;
        }
      }
    }
#pragma unroll
    for (int r = 0; r < 8; r++) red[p][r][d] = acc[r];
    __syncthreads();
    if (p == 0) {
#pragma unroll
      for (int r = 0; r < 8; r++)
        qd[r][d] = red[0][r][d] + red[1][r][d] + red[2][r][d] + red[3][r][d] + bq[h * 64 + d];
    }
    __syncthreads();
    for (int idx = t; idx < 8 * U_; idx += 256) {
      const int c = idx / U_, u = idx - c * U_;
      float s = 0.f;
#pragma unroll 8
      for (int dd = 0; dd < 64; dd++) s += qd[c][dd] * Ks[u][dd];
      sc[c][u] = s;
    }
    __syncthreads();
    if (t < nc) {
      float mx = sc[t][0], sm = sc[t][0];
      for (int u = 1; u < U_; u++) { mx = fmaxf(mx, sc[t][u]); sm += sc[t][u]; }
      candM[(size_t)bh * CAP_ + c0 + t] = mx - sm * (1.f / (float)U_);
    }
  }
}

// ---------- select_b: final top-45 over candidates (exact M, idx tie-break) ----------
__global__ __launch_bounds__(256) void select_b(const float* __restrict__ candM,
    const int* __restrict__ list, const int* __restrict__ cnt, int* __restrict__ topidx) {
  const int bh = blockIdx.x, t = threadIdx.x;
  __shared__ float mv[CAP_];
  __shared__ int   ml[CAP_];
  __shared__ float rv[256];
  __shared__ int   ri[256];
  const int n = cnt[bh];
  for (int i = t; i < CAP_; i += 256) {
    mv[i] = (i < n) ? candM[(size_t)bh * CAP_ + i] : -3.4e38f;
    ml[i] = (i < n) ? list[(size_t)bh * CAP_ + i] : 0x7fffffff;
  }
  __syncthreads();
  for (int it = 0; it < U_; it++) {
    float bv = mv[t]; int bi = ml[t]; int bj = t;
    {
      const float v = mv[t + 256]; const int l2 = ml[t + 256];
      if (v > bv || (v == bv && l2 < bi)) { bv = v; bi = l2; bj = t + 256; }
    }
    rv[t] = bv; ri[t] = bj;
    __syncthreads();
    for (int s = 128; s > 0; s >>= 1) {
      if (t < s) {
        const float v2 = rv[t + s];
        const int slot2 = ri[t + s];
        if (v2 > rv[t] || (v2 == rv[t] && ml[slot2] < ml[ri[t]])) {
          rv[t] = v2; ri[t] = slot2;
        }
      }
      __syncthreads();
    }
    if (t == 0) {
      topidx[bh * U_ + it] = ml[ri[0]];
      mv[ri[0]] = -3.4e38f;
    }
    __syncthreads();
  }
}

// ---------- qsel2: exact selected Q rows -> bf16, column-parallel ----------
__global__ __launch_bounds__(256) void qsel2(const float* __restrict__ X,
    const float* __restrict__ Wq, const float* __restrict__ bq,
    const int* __restrict__ topidx, unsigned short* __restrict__ Qbf) {
  const int bh = blockIdx.x, ug = blockIdx.y;
  const int b = bh >> 4, h = bh & 15;
  __shared__ float Xs[15][256];
  __shared__ float red[4][15][64];
  __shared__ int rows[15];
  const int t = threadIdx.x, p = t >> 6, d = t & 63;
  if (t < 15) rows[t] = topidx[bh * U_ + ug * 15 + t];
  float acc[15];
#pragma unroll
  for (int r = 0; r < 15; r++) acc[r] = 0.f;
  for (int kc = 0; kc < 4; kc++) {
    __syncthreads();
#pragma unroll
    for (int i = 0; i < 15; i++)
      Xs[i][t] = X[((size_t)b * L_ + rows[i]) * DM_ + kc * 256 + t];
    __syncthreads();
#pragma unroll
    for (int k4 = 0; k4 < 16; k4++) {
      const int kb = kc * 256 + p * 64 + k4 * 4;
      const float w0 = Wq[(size_t)(kb + 0) * DM_ + h * 64 + d];
      const float w1 = Wq[(size_t)(kb + 1) * DM_ + h * 64 + d];
      const float w2 = Wq[(size_t)(kb + 2) * DM_ + h * 64 + d];
      const float w3 = Wq[(size_t)(kb + 3) * DM_ + h * 64 + d];
#pragma unroll
      for (int r = 0; r < 15; r++) {
        const float4 x = *(const float4*)&Xs[r][p * 64 + k4 * 4];
        acc[r] += x.x * w0 + x.y * w1 + x.z * w2 + x.w * w3;
      }
    }
  }
#pragma unroll
  for (int r = 0; r < 15; r++) red[p][r][d] = acc[r];
  __syncthreads();
  if (p == 0) {
    const float bias = bq[h * 64 + d];
#pragma unroll
    for (int r = 0; r < 15; r++)
      Qbf[((size_t)bh * 48 + ug * 15 + r) * 64 + d] =
          f2bf(red[0][r][d] + red[1][r][d] + red[2][r][d] + red[3][r][d] + bias);
  }
  if (ug == 2 && t < 192) Qbf[((size_t)bh * 48 + U_) * 64 + t] = 0;  // pad rows 45..47
}

// ---------- V mean from bf16 V ----------
__global__ __launch_bounds__(256) void vmean_partial(const unsigned short* __restrict__ Vbf,
                                                     float* __restrict__ partial) {
  const int col = blockIdx.x * 256 + threadIdx.x;
  const int s = blockIdx.y, b = blockIdx.z;
  const unsigned short* src = Vbf + ((size_t)b * L_ + s * 64) * DM_ + col;
  float acc = 0.f;
#pragma unroll 8
  for (int l = 0; l < 64; l++) acc += bf2f(src[(size_t)l * DM_]);
  partial[((size_t)b * 64 + s) * DM_ + col] = acc;
}
__global__ __launch_bounds__(256) void vmean_combine(const float* __restrict__ partial,
                                                     float* __restrict__ Vm) {
  const int idx = blockIdx.x * 256 + threadIdx.x;  // 8192
  const int b = idx >> 10, col = idx & 1023;
  float acc = 0.f;
  for (int s = 0; s < 64; s++) acc += partial[((size_t)b * 64 + s) * DM_ + col];
  Vm[idx] = acc * (1.f / (float)L_);
}

// ---------- stage1: MFMA QK^T (swapped), VALU softmax+PV; no-max softmax ----------
__global__ __launch_bounds__(256) void attn_stage1(const unsigned short* __restrict__ Qbf,
    const unsigned short* __restrict__ Kbf, const unsigned short* __restrict__ Vbf,
    float* __restrict__ part) {
  const int bh = blockIdx.x, split = blockIdx.y;
  const int b = bh >> 4, h = bh & 15;
  __shared__ unsigned short sQ[48][72];
  __shared__ unsigned short sK[64][72];
  __shared__ unsigned short sV[64][72];
  __shared__ float es[64][52];
  const int tid = threadIdx.x, wid = tid >> 6, lane = tid & 63;
  const int fr = lane & 15, fq = lane >> 4;
  for (int e = tid; e < 48 * 8; e += 256) {
    const int r = e >> 3, c8 = (e & 7) * 8;
    *(ushort8*)&sQ[r][c8] = *(const ushort8*)&Qbf[((size_t)bh * 48 + r) * 64 + c8];
  }
  __syncthreads();
  short8 qf[3][2];
#pragma unroll
  for (int nt = 0; nt < 3; nt++)
#pragma unroll
    for (int kh = 0; kh < 2; kh++)
      qf[nt][kh] = *(const short8*)&sQ[nt * 16 + fr][kh * 32 + fq * 8];

  float S[12], ctx[12];
#pragma unroll
  for (int i = 0; i < 12; i++) { S[i] = 0.f; ctx[i] = 0.f; }

  for (int t = 0; t < 8; t++) {
    const int k0 = split * 512 + t * 64;
    if (t) __syncthreads();                 // prev tile's es/sV fully consumed
    for (int e = tid; e < 64 * 8; e += 256) {
      const int r = e >> 3, c8 = (e & 7) * 8;
      const size_t gsrc = ((size_t)b * L_ + k0 + r) * DM_ + h * 64 + c8;
      *(ushort8*)&sK[r][c8] = *(const ushort8*)&Kbf[gsrc];
      *(ushort8*)&sV[r][c8] = *(const ushort8*)&Vbf[gsrc];
    }
    __syncthreads();
    short8 kf0 = *(const short8*)&sK[wid * 16 + fr][fq * 8];
    short8 kf1 = *(const short8*)&sK[wid * 16 + fr][32 + fq * 8];
    f32x4 accq[3];
#pragma unroll
    for (int nt = 0; nt < 3; nt++) {
      accq[nt] = f32x4{0.f, 0.f, 0.f, 0.f};
      accq[nt] = __builtin_amdgcn_mfma_f32_16x16x32_bf16(kf0, qf[nt][0], accq[nt], 0, 0, 0);
      accq[nt] = __builtin_amdgcn_mfma_f32_16x16x32_bf16(kf1, qf[nt][1], accq[nt], 0, 0, 0);
    }
#pragma unroll
    for (int nt = 0; nt < 3; nt++)
#pragma unroll
      for (int r = 0; r < 4; r++)
        es[wid * 16 + fq * 4 + r][nt * 16 + fr] = expf(accq[nt][r] * 0.125f);
    __syncthreads();
    const int q0 = wid * 12;
    for (int k = 0; k < 64; k++) {
      const float v = bf2f(sV[k][lane]);
      const float4 e0 = *(const float4*)&es[k][q0];
      const float4 e1 = *(const float4*)&es[k][q0 + 4];
      const float4 e2 = *(const float4*)&es[k][q0 + 8];
      S[0] += e0.x; S[1] += e0.y; S[2]  += e0.z; S[3]  += e0.w;
      S[4] += e1.x; S[5] += e1.y; S[6]  += e1.z; S[7]  += e1.w;
      S[8] += e2.x; S[9] += e2.y; S[10] += e2.z; S[11] += e2.w;
      ctx[0] += e0.x * v; ctx[1] += e0.y * v; ctx[2]  += e0.z * v; ctx[3]  += e0.w * v;
      ctx[4] += e1.x * v; ctx[5] += e1.y * v; ctx[6]  += e1.z * v; ctx[7]  += e1.w * v;
      ctx[8] += e2.x * v; ctx[9] += e2.y * v; ctx[10] += e2.z * v; ctx[11] += e2.w * v;
    }
  }
#pragma unroll
  for (int i = 0; i < 12; i++) {
    const int u = wid * 12 + i;
    if (u < U_) {
      float* pb = part + ((size_t)(bh * NSPLIT + split) * U_ + u) * 65;
      if (lane == 0) pb[0] = S[i];
      pb[1 + lane] = ctx[i];
    }
  }
}

// ---------- combine splits; dctx = ctx/S - Vmean ----------
__global__ __launch_bounds__(256) void attn_stage2(const float* __restrict__ part,
    const float* __restrict__ Vm, float* __restrict__ dctx) {
  const int bh = blockIdx.x;
  const int wid = threadIdx.x >> 6, lane = threadIdx.x & 63;
  for (int u = wid; u < U_; u += 4) {
    float S = 0.f, c = 0.f;
#pragma unroll
    for (int sp = 0; sp < NSPLIT; sp++) {
      const float* pb = part + ((size_t)(bh * NSPLIT + sp) * U_ + u) * 65;
      S += pb[0];
      c += pb[1 + lane];
    }
    dctx[((size_t)bh * U_ + u) * 64 + lane] = c / S - Vm[bh * 64 + lane];
  }
}

// ---------- base[b][:] = concat_h(Vmean) @ Wo + bo ----------
__global__ __launch_bounds__(256) void base_k(const float* __restrict__ Vm,
    const float* __restrict__ Wo, const float* __restrict__ bo, float* __restrict__ base) {
  const int b = blockIdx.y;
  const int j = blockIdx.x * 256 + threadIdx.x;
  float acc = bo[j];
#pragma unroll 8
  for (int i = 0; i < DM_; i++) acc += Vm[b * DM_ + i] * Wo[(size_t)i * DM_ + j];
  base[b * DM_ + j] = acc;
}

// ---------- out[b,l,:] = base[b,:] ----------
__global__ __launch_bounds__(256) void fill_out(const float* __restrict__ base,
                                                float* __restrict__ out) {
  const size_t g = ((size_t)blockIdx.x * 256 + threadIdx.x) * 4;
  const int b = (int)(g >> 22), j = (int)(g & 1023);
  *(float4*)&out[g] = *(const float4*)&base[(b << 10) + j];
}

// ---------- gemm_upd: rowupd[bh][u][:] = dctx[bh] @ Wo_h ----------
// grid (4 col-chunks, BH_); thread = one col of chunk
__global__ __launch_bounds__(256) void gemm_upd(const float* __restrict__ dctx,
    const float* __restrict__ Wo, float* __restrict__ rowupd) {
  const int bh = blockIdx.y, h = bh & 15;
  const int col = blockIdx.x * 256 + threadIdx.x;
  __shared__ float dc[U_][68];
  for (int e = threadIdx.x; e < U_ * 64; e += 256) {
    const int u = e >> 6, d = e & 63;
    dc[u][d] = dctx[(size_t)bh * U_ * 64 + e];
  }
  __syncthreads();
  float acc[U_];
#pragma unroll
  for (int u = 0; u < U_; u++) acc[u] = 0.f;
  for (int d = 0; d < 64; d++) {
    const float w = Wo[(size_t)(h * 64 + d) * DM_ + col];
#pragma unroll
    for (int u = 0; u < U_; u++) acc[u] += dc[u][d] * w;   // dc broadcast read
  }
#pragma unroll
  for (int u = 0; u < U_; u++)
    rowupd[((size_t)bh * U_ + u) * DM_ + col] = acc[u];
}

// ---------- build_list: per selected row, head-mask + slot; unique-row list ----------
__global__ __launch_bounds__(256) void build_list(const int* __restrict__ topidx,
    int* __restrict__ rowmask, unsigned char* __restrict__ slotU,
    int* __restrict__ uniq, int* __restrict__ uniqCnt) {
  const int i = blockIdx.x * 256 + threadIdx.x;
  if (i >= BH_ * U_) return;
  const int bh = i / U_, u = i - bh * U_;
  const int b = bh >> 4, h = bh & 15;
  const int key = b * L_ + topidx[i];
  slotU[key * 16 + h] = (unsigned char)u;
  const int old = atomicOr(&rowmask[key], 1 << h);
  if (old == 0) {
    const int q = atomicAdd(uniqCnt, 1);
    uniq[q] = key;
  }
}

// ---------- scatter3: one block per unique row; fixed h-order sum; plain write ----------
__global__ __launch_bounds__(256) void scatter3(const float* __restrict__ rowupd,
    const float* __restrict__ base, const int* __restrict__ rowmask,
    const unsigned char* __restrict__ slotU, const int* __restrict__ uniq,
    const int* __restrict__ uniqCnt, float* __restrict__ out) {
  const int idx = blockIdx.x;
  if (idx >= *uniqCnt) return;
  const int key = uniq[idx];
  const int b = key >> 12;                       // L_ = 4096
  const int mask = rowmask[key];
  const int j4 = threadIdx.x * 4;
  float4 a = *(const float4*)&base[b * DM_ + j4];
#pragma unroll
  for (int h = 0; h < 16; h++) {
    if (mask & (1 << h)) {
      const int u = slotU[key * 16 + h];
      const float4 r = *(const float4*)&rowupd[((size_t)(b * 16 + h) * U_ + u) * DM_ + j4];
      a.x += r.x; a.y += r.y; a.z += r.z; a.w += r.w;
    }
  }
  *(float4*)&out[(size_t)key * DM_ + j4] = a;
}

extern "C" void kernel_launch(void* const* d_in, const int* in_sizes, int n_in,
                              void* d_out, int out_size, void* d_ws, size_t ws_size,
                              hipStream_t stream) {
  const float* queries = (const float*)d_in[0];
  const float* keys    = (const float*)d_in[1];
  const float* values  = (const float*)d_in[2];
  const float* Wq = (const float*)d_in[3]; const float* bq = (const float*)d_in[4];
  const float* Wk = (const float*)d_in[5]; const float* bk = (const float*)d_in[6];
  const float* Wv = (const float*)d_in[7]; const float* bv = (const float*)d_in[8];
  const float* Wo = (const float*)d_in[9]; const float* bo = (const float*)d_in[10];
  const int* sidx = (const int*)d_in[11];

  // K,V live as bf16 in d_out (67.1 MB each) until the epilogue
  unsigned short* Kbf = (unsigned short*)d_out;
  unsigned short* Vbf = Kbf + (size_t)ML_ * DM_;

  uint8_t* p = (uint8_t*)d_ws;
  auto carve = [&](size_t bytes) { uint8_t* r = p; p += (bytes + 255) & ~(size_t)255; return r; };
  unsigned short* Xqh = (unsigned short*)carve((size_t)CROWS_ * DM_ * 2);   // 33.6 MB
  unsigned short* Xkh = (unsigned short*)carve((size_t)CROWS_ * DM_ * 2);
  unsigned short* Xvh = (unsigned short*)carve((size_t)CROWS_ * DM_ * 2);
  float* QKs = (float*)carve((size_t)CROWS_ * NP_ * 4);                     // 50.3 MB
  unsigned short* Ph = (unsigned short*)carve((size_t)B_ * NP_ * DM_ * 2);  // 12.6 MB
  unsigned short* WkT = (unsigned short*)carve((size_t)DM_ * DM_ * 2);
  unsigned short* WvT = (unsigned short*)carve((size_t)DM_ * DM_ * 2);
  float* Mbuf  = (float*)carve((size_t)BH_ * L_ * 4);                       // 2.1 MB
  float* Ksamp = (float*)carve((size_t)BH_ * U_ * 64 * 4);                  // 1.5 MB
  float* kpart = (float*)carve((size_t)4 * B_ * U_ * 1024 * 4);             // 5.9 MB
  int*   list  = (int*)carve((size_t)BH_ * CAP_ * 4);                       // 256 KB
  float* candM = (float*)carve((size_t)BH_ * CAP_ * 4);                     // 256 KB
  int*   cntb  = (int*)carve((size_t)BH_ * 4);
  int*   topidx = (int*)carve((size_t)BH_ * U_ * 4);
  float* Vm    = (float*)carve((size_t)BH_ * 64 * 4);
  unsigned short* Qbf = (unsigned short*)carve((size_t)BH_ * 48 * 64 * 2);  // 786 KB
  int*   rowmask = (int*)carve((size_t)B_ * L_ * 4);                        // 128 KB (memset)
  int*   uniqCnt = (int*)carve(256);                                        // (memset)
  unsigned char* slotU = (unsigned char*)carve((size_t)B_ * L_ * 16);       // 512 KB
  int*   uniq  = (int*)carve((size_t)BH_ * U_ * 4);                         // 23 KB
  const size_t need = (size_t)(p - (uint8_t*)d_ws);
  if (ws_size < need)
    fprintf(stderr, "ATHENA_WS: need %zu have %zu (WILL FAULT)\n", need, ws_size);

  // late-phase buffers alias QKs (dead after mpass)
  uint8_t* ap = (uint8_t*)QKs;
  auto acarve = [&](size_t bytes) { uint8_t* r = ap; ap += (bytes + 255) & ~(size_t)255; return r; };
  float* part  = (float*)acarve((size_t)BH_ * NSPLIT * U_ * 65 * 4);        // 12 MB
  float* dctx  = (float*)acarve((size_t)BH_ * U_ * 64 * 4);
  float* vpart = (float*)acarve((size_t)B_ * 64 * DM_ * 4);                 // 2.1 MB
  float* base  = (float*)acarve((size_t)B_ * DM_ * 4);
  float* rowupd = (float*)acarve((size_t)BH_ * U_ * DM_ * 4);               // 23.6 MB

  ksel3<<<dim3(4, B_, 12), 256, 0, stream>>>(keys, Wk, sidx, kpart);
  ksel_comb<<<(B_ * U_ * 1024) / 256, 256, 0, stream>>>(kpart, bk, Ksamp);
  pform_k<<<BH_, 256, 0, stream>>>(Wq, Ksamp, Ph);
  wT_single<<<4096, 256, 0, stream>>>(Wk, WkT);
  wT_single<<<4096, 256, 0, stream>>>(Wv, WvT);

  const int n4 = (int)((size_t)CROWS_ * DM_ / 4);
  for (int c = 0; c < 2; c++) {
    const size_t off = (size_t)c * CROWS_ * DM_;
    split3h<<<dim3(2048, 3), 256, 0, stream>>>(queries + off, keys + off, values + off,
                                               Xqh, Xkh, Xvh, n4);
    gemm_plain<<<dim3(8, 128), 256, 0, stream>>>(Xkh, WkT, bk, Kbf + off);
    gemm_plain<<<dim3(8, 128), 256, 0, stream>>>(Xvh, WvT, bv, Vbf + off);
    gemm_qk1<<<dim3(6, 128), 256, 0, stream>>>(Xqh, Ph, QKs, c);
    mpass_k<<<(CROWS_ * 16) / 256, 256, 0, stream>>>(QKs, Mbuf, c);
  }

  select_a<<<BH_, 256, 0, stream>>>(Mbuf, list, cntb);
  exactM2<<<dim3(BH_, 8), 256, 0, stream>>>(queries, Wq, bq, Ksamp, list, cntb, candM);
  select_b<<<BH_, 256, 0, stream>>>(candM, list, cntb, topidx);
  qsel2<<<dim3(BH_, 3), 256, 0, stream>>>(queries, Wq, bq, topidx, Qbf);
  vmean_partial<<<dim3(DM_ / 256, 64, B_), 256, 0, stream>>>(Vbf, vpart);
  vmean_combine<<<(B_ * DM_) / 256, 256, 0, stream>>>(vpart, Vm);
  attn_stage1<<<dim3(BH_, NSPLIT), 256, 0, stream>>>(Qbf, Kbf, Vbf, part);
  attn_stage2<<<BH_, 256, 0, stream>>>(part, Vm, dctx);
  base_k<<<dim3(DM_ / 256, B_), 256, 0, stream>>>(Vm, Wo, bo, base);

  // epilogue: deterministic, atomic-free
  hipMemsetAsync(rowmask, 0, (size_t)B_ * L_ * 4 + 256, stream);  // rowmask + uniqCnt
  gemm_upd<<<dim3(4, BH_), 256, 0, stream>>>(dctx, Wo, rowupd);
  build_list<<<(BH_ * U_ + 255) / 256, 256, 0, stream>>>(topidx, rowmask, slotU, uniq, uniqCnt);
  fill_out<<<(int)((size_t)ML_ * DM_ / 4 / 256), 256, 0, stream>>>(base, (float*)d_out);
  scatter3<<<BH_ * U_, 256, 0, stream>>>(rowupd, base, rowmask, slotU, uniq, uniqCnt,
                                         (float*)d_out);
}

// Round 10
// 1101.289 us; speedup vs baseline: 1.9437x; 1.0635x over previous
//
#include <hip/hip_runtime.h>
#include <cstdint>
#include <cstdio>

#define B_   8
#define L_   4096
#define DM_  1024
#define H_   16
#define D_   64
#define U_   45
#define BH_  (B_*H_)
#define ML_  (B_*L_)
#define NSPLIT 8
#define NP_  768           // padded QK-sample width: 16 heads * 48
#define CB_  4             // batches per chunk
#define CROWS_ (CB_*L_)    // 16384 rows per chunk
#define CAP_ 512           // candidate cap per (b,h)
#define DELTA_ 0.12f       // exact-recompute band (~9 sigma of bf16 GEMM err)

using f32x4   = __attribute__((ext_vector_type(4))) float;
using short8  = __attribute__((ext_vector_type(8))) short;
using ushort8 = __attribute__((ext_vector_type(8))) unsigned short;

__device__ __forceinline__ unsigned short f2bf(float f) {
  uint32_t u = __float_as_uint(f);
  u += 0x7fffu + ((u >> 16) & 1u);      // RNE; inputs finite
  return (unsigned short)(u >> 16);
}
__device__ __forceinline__ float bf2f(unsigned short h) {
  return __uint_as_float(((uint32_t)h) << 16);
}

__device__ __forceinline__ void gload16(const void* g, void* l) {
  __builtin_amdgcn_global_load_lds((const __attribute__((address_space(1))) void*)g,
                                   (__attribute__((address_space(3))) void*)l,
                                   16, 0, 0);
}

// ---------- split: q,k,v -> bf16 hi only ----------
__global__ __launch_bounds__(256) void split3h(const float* __restrict__ q,
    const float* __restrict__ k, const float* __restrict__ v,
    unsigned short* __restrict__ Xqh, unsigned short* __restrict__ Xkh,
    unsigned short* __restrict__ Xvh, int n4) {
  const int z = blockIdx.y;
  const float* __restrict__ X = (z == 0) ? q : ((z == 1) ? k : v);
  unsigned short* __restrict__ O = (z == 0) ? Xqh : ((z == 1) ? Xkh : Xvh);
  int i = blockIdx.x * 256 + threadIdx.x;
  const int stride = gridDim.x * 256;
  for (; i < n4; i += stride) {
    const float4 w = ((const float4*)X)[i];
    ushort4 hv;
    hv.x = f2bf(w.x); hv.y = f2bf(w.y); hv.z = f2bf(w.z); hv.w = f2bf(w.w);
    ((ushort4*)O)[i] = hv;
  }
}

// ---------- W (KxN) -> W^T bf16 (NxK) ----------
__global__ __launch_bounds__(256) void wT_single(const float* __restrict__ W,
                                                 unsigned short* __restrict__ WT) {
  const int idx = blockIdx.x * 256 + threadIdx.x;   // 1M threads
  const int n = idx >> 10, kk = idx & 1023;
  WT[idx] = f2bf(W[kk * 1024 + n]);
}

// ---------- plain bf16 GEMM, bf16 out: C = bf16(X*W + bias) ----------
__global__ __launch_bounds__(256) void gemm_plain(const unsigned short* __restrict__ Agh,
    const unsigned short* __restrict__ Bgh, const float* __restrict__ bias,
    unsigned short* __restrict__ C) {
  constexpr int K = 1024, N = 1024;
  __shared__ unsigned short sA[128 * 32];
  __shared__ unsigned short sB[128 * 32];
  const int tid = threadIdx.x, wid = tid >> 6, lane = tid & 63;
  const int m0 = blockIdx.y * 128, n0 = blockIdx.x * 128;
  const int wr = wid >> 1, wc = wid & 1;
  const int fr = lane & 15, fq = lane >> 4;
  const int srow = lane >> 2, scol = (lane & 3) * 8;
  f32x4 acc[4][4];
#pragma unroll
  for (int i = 0; i < 4; i++)
#pragma unroll
    for (int j = 0; j < 4; j++) acc[i][j] = f32x4{0.f, 0.f, 0.f, 0.f};

  for (int k0 = 0; k0 < K; k0 += 32) {
#pragma unroll
    for (int c = 0; c < 2; c++) {
      const int ch = wid * 2 + c;
      const int row = ch * 16 + srow;
      gload16(Agh + (size_t)(m0 + row) * K + (k0 + scol), &sA[ch * 512]);
      gload16(Bgh + (size_t)(n0 + row) * K + (k0 + scol), &sB[ch * 512]);
    }
    __syncthreads();
    short8 ah[4], bh[4];
#pragma unroll
    for (int i = 0; i < 4; i++) {
      ah[i] = *(const short8*)&sA[(wr * 64 + i * 16 + fr) * 32 + fq * 8];
      bh[i] = *(const short8*)&sB[(wc * 64 + i * 16 + fr) * 32 + fq * 8];
    }
#pragma unroll
    for (int i = 0; i < 4; i++)
#pragma unroll
      for (int j = 0; j < 4; j++)
        acc[i][j] = __builtin_amdgcn_mfma_f32_16x16x32_bf16(ah[i], bh[j], acc[i][j], 0, 0, 0);
    __syncthreads();
  }
#pragma unroll
  for (int j = 0; j < 4; j++) {
    const int col = n0 + wc * 64 + j * 16 + fr;
    const float bv = bias[col];
#pragma unroll
    for (int i = 0; i < 4; i++) {
      const int row = m0 + wr * 64 + i * 16 + fq * 4;
#pragma unroll
      for (int r = 0; r < 4; r++) C[(size_t)(row + r) * N + col] = f2bf(acc[i][j][r] + bv);
    }
  }
}

// ---------- plain bf16 GEMM: QKs = Xq * P_b (fp32 out, N=768) ----------
__global__ __launch_bounds__(256) void gemm_qk1(const unsigned short* __restrict__ Agh,
    const unsigned short* __restrict__ Pall_h, float* __restrict__ C, int chunk) {
  constexpr int K = 1024;
  __shared__ unsigned short sA[128 * 32];
  __shared__ unsigned short sB[128 * 32];
  const int tid = threadIdx.x, wid = tid >> 6, lane = tid & 63;
  const int m0 = blockIdx.y * 128, n0 = blockIdx.x * 128;
  const int batch = chunk * CB_ + (blockIdx.y >> 5);
  const unsigned short* __restrict__ Bgh = Pall_h + (size_t)batch * NP_ * K;
  const int wr = wid >> 1, wc = wid & 1;
  const int fr = lane & 15, fq = lane >> 4;
  const int srow = lane >> 2, scol = (lane & 3) * 8;
  f32x4 acc[4][4];
#pragma unroll
  for (int i = 0; i < 4; i++)
#pragma unroll
    for (int j = 0; j < 4; j++) acc[i][j] = f32x4{0.f, 0.f, 0.f, 0.f};

  for (int k0 = 0; k0 < K; k0 += 32) {
#pragma unroll
    for (int c = 0; c < 2; c++) {
      const int ch = wid * 2 + c;
      const int row = ch * 16 + srow;
      gload16(Agh + (size_t)(m0 + row) * K + (k0 + scol), &sA[ch * 512]);
      gload16(Bgh + (size_t)(n0 + row) * K + (k0 + scol), &sB[ch * 512]);
    }
    __syncthreads();
    short8 ah[4], bh[4];
#pragma unroll
    for (int i = 0; i < 4; i++) {
      ah[i] = *(const short8*)&sA[(wr * 64 + i * 16 + fr) * 32 + fq * 8];
      bh[i] = *(const short8*)&sB[(wc * 64 + i * 16 + fr) * 32 + fq * 8];
    }
#pragma unroll
    for (int i = 0; i < 4; i++)
#pragma unroll
      for (int j = 0; j < 4; j++)
        acc[i][j] = __builtin_amdgcn_mfma_f32_16x16x32_bf16(ah[i], bh[j], acc[i][j], 0, 0, 0);
    __syncthreads();
  }
#pragma unroll
  for (int j = 0; j < 4; j++) {
    const int col = n0 + wc * 64 + j * 16 + fr;
#pragma unroll
    for (int i = 0; i < 4; i++) {
      const int row = m0 + wr * 64 + i * 16 + fq * 4;
#pragma unroll
      for (int r = 0; r < 4; r++) C[(size_t)(row + r) * NP_ + col] = acc[i][j][r];
    }
  }
}

// ---------- ksel3: exact fp32 sampled-K rows, split-K column-parallel ----------
__global__ __launch_bounds__(256) void ksel3(const float* __restrict__ X,
    const float* __restrict__ Wk, const int* __restrict__ sidx,
    float* __restrict__ kpart) {
  const int t = threadIdx.x;
  const int col = blockIdx.x * 256 + t;
  const int b = blockIdx.y;
  const int ug = blockIdx.z >> 2, kc = blockIdx.z & 3;
  __shared__ float Xs[15][256];
  __shared__ int rows[15];
  if (t < 15) rows[t] = sidx[ug * 15 + t];
  __syncthreads();
#pragma unroll
  for (int i = 0; i < 15; i++)
    Xs[i][t] = X[((size_t)b * L_ + rows[i]) * DM_ + kc * 256 + t];
  __syncthreads();
  float acc[15];
#pragma unroll
  for (int r = 0; r < 15; r++) acc[r] = 0.f;
  for (int k4 = 0; k4 < 64; k4++) {
    const int kb = kc * 256 + k4 * 4;
    const float w0 = Wk[(size_t)(kb + 0) * DM_ + col];
    const float w1 = Wk[(size_t)(kb + 1) * DM_ + col];
    const float w2 = Wk[(size_t)(kb + 2) * DM_ + col];
    const float w3 = Wk[(size_t)(kb + 3) * DM_ + col];
#pragma unroll
    for (int r = 0; r < 15; r++) {
      const float4 x = *(const float4*)&Xs[r][k4 * 4];
      acc[r] += x.x * w0 + x.y * w1 + x.z * w2 + x.w * w3;
    }
  }
  float* dst = kpart + (((size_t)kc * B_ + b) * U_ + ug * 15) * 1024 + col;
#pragma unroll
  for (int r = 0; r < 15; r++) dst[(size_t)r * 1024] = acc[r];
}

// combine: Ksamp = sum_kc kpart + bias (fixed order)
__global__ __launch_bounds__(256) void ksel_comb(const float* __restrict__ kpart,
    const float* __restrict__ bk, float* __restrict__ Ksamp) {
  const int idx = blockIdx.x * 256 + threadIdx.x;   // < 360*1024
  const int col = idx & 1023, ru = idx >> 10;
  const int b = ru / U_, u = ru - b * U_;
  const size_t o = ((size_t)b * U_ + u) * 1024 + col;
  const size_t stride = (size_t)B_ * U_ * 1024;
  float s = kpart[o] + kpart[o + stride] + kpart[o + 2 * stride] + kpart[o + 3 * stride]
          + bk[col];
  const int h = col >> 6, d = col & 63;
  Ksamp[((size_t)(b * 16 + h) * U_ + u) * 64 + d] = s;
}

// ---------- P^T[b][h*48+u][k] = sum_d Wq[k][h*64+d]*Ksamp (bf16 hi) ----------
__global__ __launch_bounds__(256) void pform_k(const float* __restrict__ Wq,
    const float* __restrict__ Ksamp, unsigned short* __restrict__ Ph) {
  const int bh = blockIdx.x, b = bh >> 4, h = bh & 15;
  __shared__ float Ks[U_][68];
  const int t = threadIdx.x;
  for (int e = t; e < U_ * 64; e += 256) {
    const int u = e >> 6, d = e & 63;
    Ks[u][d] = Ksamp[((size_t)bh * U_ + u) * 64 + d];
  }
  __syncthreads();
  for (int kc = 0; kc < 4; kc++) {
    const int k = kc * 256 + t;
    float wr[64];
#pragma unroll
    for (int dd = 0; dd < 16; dd++) {
      const float4 w4 = *(const float4*)&Wq[(size_t)k * DM_ + h * 64 + dd * 4];
      wr[dd * 4 + 0] = w4.x; wr[dd * 4 + 1] = w4.y;
      wr[dd * 4 + 2] = w4.z; wr[dd * 4 + 3] = w4.w;
    }
    for (int u = 0; u < 48; u++) {
      size_t o = ((size_t)b * NP_ + h * 48 + u) * 1024 + k;
      if (u < U_) {
        float acc = 0.f;
#pragma unroll
        for (int d = 0; d < 64; d++) acc += wr[d] * Ks[u][d];
        Ph[o] = f2bf(acc);
      } else {
        Ph[o] = 0;
      }
    }
  }
}

// ---------- M_approx = max - mean over u ----------
__global__ __launch_bounds__(256) void mpass_k(const float* __restrict__ QKs,
                                               float* __restrict__ Mbuf, int chunk) {
  const int idx = blockIdx.x * 256 + threadIdx.x;   // < CROWS_*16
  const int ll = idx >> 4, h = idx & 15;
  const float* row = QKs + (size_t)ll * NP_ + h * 48;
  float mx = row[0], sm = row[0];
#pragma unroll
  for (int u = 1; u < U_; u++) { const float v = row[u]; mx = fmaxf(mx, v); sm += v; }
  const int lg = chunk * CROWS_ + ll;
  const int b = lg >> 12, l = lg & 4095;
  Mbuf[((size_t)(b * 16 + h)) * L_ + l] = mx - sm * (1.f / (float)U_);
}

// ---------- select_a: approx top-45 -> thr; candidates = {M >= thr - DELTA} ----------
__global__ __launch_bounds__(256) void select_a(const float* __restrict__ Mbuf,
    int* __restrict__ list, int* __restrict__ cnt) {
  const int bh = blockIdx.x, t = threadIdx.x;
  __shared__ float vals[L_];
  __shared__ float rv[256];
  __shared__ int   ri[256];
  __shared__ int   scnt;
  __shared__ float sthr;
  if (t == 0) scnt = 0;
  for (int i = t; i < L_; i += 256) vals[i] = Mbuf[(size_t)bh * L_ + i];
  __syncthreads();
  for (int it = 0; it < U_; it++) {
    float bv = vals[t * 16]; int bi = t * 16;
#pragma unroll
    for (int jj = 1; jj < 16; jj++) {
      const float v = vals[t * 16 + jj];
      if (v > bv) { bv = v; bi = t * 16 + jj; }
    }
    rv[t] = bv; ri[t] = bi;
    __syncthreads();
    for (int s = 128; s > 0; s >>= 1) {
      if (t < s) {
        if (rv[t + s] > rv[t] || (rv[t + s] == rv[t] && ri[t + s] < ri[t])) {
          rv[t] = rv[t + s]; ri[t] = ri[t + s];
        }
      }
      __syncthreads();
    }
    if (t == 0) {
      list[(size_t)bh * CAP_ + it] = ri[0];
      vals[ri[0]] = -3.4e38f;
      if (it == U_ - 1) sthr = rv[0];
    }
    __syncthreads();
  }
  const float lim = sthr - DELTA_;
  for (int i = t; i < L_; i += 256) {
    if (vals[i] >= lim) {
      const int j = atomicAdd(&scnt, 1);
      if (U_ + j < CAP_) list[(size_t)bh * CAP_ + U_ + j] = i;
    }
  }
  __syncthreads();
  if (t == 0) cnt[bh] = min(U_ + scnt, CAP_);
}

// ---------- exactM2: fp32 recompute of M for candidates ----------
__global__ __launch_bounds__(256) void exactM2(const float* __restrict__ X,
    const float* __restrict__ Wq, const float* __restrict__ bq,
    const float* __restrict__ Ksamp, const int* __restrict__ list,
    const int* __restrict__ cnt, float* __restrict__ candM) {
  const int bh = blockIdx.x, g = blockIdx.y, b = bh >> 4, h = bh & 15;
  __shared__ float Ks[U_][68];
  __shared__ float Xs[8][256];
  __shared__ float red[4][8][64];
  __shared__ float qd[8][68];
  __shared__ float sc[8][45];
  __shared__ int rows[8];
  const int t = threadIdx.x, p = t >> 6, d = t & 63;
  for (int e = t; e < U_ * 64; e += 256) {
    const int u = e >> 6, dd = e & 63;
    Ks[u][dd] = Ksamp[((size_t)bh * U_ + u) * 64 + dd];
  }
  const int n = cnt[bh];
  const int stride = 8 * gridDim.y;
  for (int c0 = g * 8; c0 < n; c0 += stride) {
    const int nc = min(8, n - c0);
    __syncthreads();
    if (t < 8) rows[t] = list[(size_t)bh * CAP_ + c0 + min(t, nc - 1)];
    float acc[8];
#pragma unroll
    for (int r = 0; r < 8; r++) acc[r] = 0.f;
    for (int kc = 0; kc < 4; kc++) {
      __syncthreads();
#pragma unroll
      for (int i = 0; i < 8; i++)
        Xs[i][t] = X[((size_t)b * L_ + rows[i]) * DM_ + kc * 256 + t];
      __syncthreads();
#pragma unroll
      for (int k4 = 0; k4 < 16; k4++) {
        const int kb = kc * 256 + p * 64 + k4 * 4;
        const float w0 = Wq[(size_t)(kb + 0) * DM_ + h * 64 + d];
        const float w1 = Wq[(size_t)(kb + 1) * DM_ + h * 64 + d];
        const float w2 = Wq[(size_t)(kb + 2) * DM_ + h * 64 + d];
        const float w3 = Wq[(size_t)(kb + 3) * DM_ + h * 64 + d];
#pragma unroll
        for (int r = 0; r < 8; r++) {
          const float4 x = *(const float4*)&Xs[r][p * 64 + k4 * 4];
          acc[r] += x.x * w0 + x.y * w1 + x.z * w2 + x.w * w3;
        }
      }
    }
#pragma unroll
    for (int r = 0; r < 8; r++) red[p][r][d] = acc[r];
    __syncthreads();
    if (p == 0) {
#pragma unroll
      for (int r = 0; r < 8; r++)
        qd[r][d] = red[0][r][d] + red[1][r][d] + red[2][r][d] + red[3][r][d] + bq[h * 64 + d];
    }
    __syncthreads();
    for (int idx = t; idx < 8 * U_; idx += 256) {
      const int c = idx / U_, u = idx - c * U_;
      float s = 0.f;
#pragma unroll 8
      for (int dd = 0; dd < 64; dd++) s += qd[c][dd] * Ks[u][dd];
      sc[c][u] = s;
    }
    __syncthreads();
    if (t < nc) {
      float mx = sc[t][0], sm = sc[t][0];
      for (int u = 1; u < U_; u++) { mx = fmaxf(mx, sc[t][u]); sm += sc[t][u]; }
      candM[(size_t)bh * CAP_ + c0 + t] = mx - sm * (1.f / (float)U_);
    }
  }
}

// ---------- select_b: final top-45 over candidates (exact M, idx tie-break) ----------
__global__ __launch_bounds__(256) void select_b(const float* __restrict__ candM,
    const int* __restrict__ list, const int* __restrict__ cnt, int* __restrict__ topidx) {
  const int bh = blockIdx.x, t = threadIdx.x;
  __shared__ float mv[CAP_];
  __shared__ int   ml[CAP_];
  __shared__ float rv[256];
  __shared__ int   ri[256];
  const int n = cnt[bh];
  for (int i = t; i < CAP_; i += 256) {
    mv[i] = (i < n) ? candM[(size_t)bh * CAP_ + i] : -3.4e38f;
    ml[i] = (i < n) ? list[(size_t)bh * CAP_ + i] : 0x7fffffff;
  }
  __syncthreads();
  for (int it = 0; it < U_; it++) {
    float bv = mv[t]; int bi = ml[t]; int bj = t;
    {
      const float v = mv[t + 256]; const int l2 = ml[t + 256];
      if (v > bv || (v == bv && l2 < bi)) { bv = v; bi = l2; bj = t + 256; }
    }
    rv[t] = bv; ri[t] = bj;
    __syncthreads();
    for (int s = 128; s > 0; s >>= 1) {
      if (t < s) {
        const float v2 = rv[t + s];
        const int slot2 = ri[t + s];
        if (v2 > rv[t] || (v2 == rv[t] && ml[slot2] < ml[ri[t]])) {
          rv[t] = v2; ri[t] = slot2;
        }
      }
      __syncthreads();
    }
    if (t == 0) {
      topidx[bh * U_ + it] = ml[ri[0]];
      mv[ri[0]] = -3.4e38f;
    }
    __syncthreads();
  }
}

// ---------- qsel3: exact selected Q rows, split-K partials ----------
// grid (BH_, 12): z = ug*4+kc; thread = (p = k-subchunk, d); 16 partials per output
__global__ __launch_bounds__(256) void qsel3(const float* __restrict__ X,
    const float* __restrict__ Wq, const int* __restrict__ topidx,
    float* __restrict__ qpart) {
  const int bh = blockIdx.x;
  const int ug = blockIdx.y >> 2, kc = blockIdx.y & 3;
  const int b = bh >> 4, h = bh & 15;
  __shared__ float Xs[15][256];
  __shared__ int rows[15];
  const int t = threadIdx.x, p = t >> 6, d = t & 63;
  if (t < 15) rows[t] = topidx[bh * U_ + ug * 15 + t];
  __syncthreads();
#pragma unroll
  for (int i = 0; i < 15; i++)
    Xs[i][t] = X[((size_t)b * L_ + rows[i]) * DM_ + kc * 256 + t];
  __syncthreads();
  float acc[15];
#pragma unroll
  for (int r = 0; r < 15; r++) acc[r] = 0.f;
#pragma unroll
  for (int k4 = 0; k4 < 16; k4++) {
    const int kb = kc * 256 + p * 64 + k4 * 4;
    const float w0 = Wq[(size_t)(kb + 0) * DM_ + h * 64 + d];
    const float w1 = Wq[(size_t)(kb + 1) * DM_ + h * 64 + d];
    const float w2 = Wq[(size_t)(kb + 2) * DM_ + h * 64 + d];
    const float w3 = Wq[(size_t)(kb + 3) * DM_ + h * 64 + d];
#pragma unroll
    for (int r = 0; r < 15; r++) {
      const float4 x = *(const float4*)&Xs[r][p * 64 + k4 * 4];
      acc[r] += x.x * w0 + x.y * w1 + x.z * w2 + x.w * w3;
    }
  }
  const int p16 = kc * 4 + p;       // partial slot 0..15
  float* dst = qpart + (((size_t)p16 * BH_ + bh) * 48 + ug * 15) * 64 + d;
#pragma unroll
  for (int r = 0; r < 15; r++) dst[(size_t)r * 64] = acc[r];
}

// combine 16 partials (fixed order) + bias -> bf16 Qbf; zero pad rows
__global__ __launch_bounds__(256) void qsel_comb(const float* __restrict__ qpart,
    const float* __restrict__ bq, unsigned short* __restrict__ Qbf) {
  const int idx = blockIdx.x * 256 + threadIdx.x;   // < BH_*48*64
  const int d = idx & 63, u48 = (idx >> 6) % 48, bh = idx / (48 * 64);
  const int h = bh & 15;
  if (u48 < U_) {
    const size_t o = (((size_t)bh) * 48 + u48) * 64 + d;
    const size_t stride = (size_t)BH_ * 48 * 64;
    float s = bq[h * 64 + d];
#pragma unroll
    for (int p16 = 0; p16 < 16; p16++) s += qpart[o + (size_t)p16 * stride];
    Qbf[o] = f2bf(s);
  } else {
    Qbf[(((size_t)bh) * 48 + u48) * 64 + d] = 0;
  }
}

// ---------- V mean from bf16 V ----------
__global__ __launch_bounds__(256) void vmean_partial(const unsigned short* __restrict__ Vbf,
                                                     float* __restrict__ partial) {
  const int col = blockIdx.x * 256 + threadIdx.x;
  const int s = blockIdx.y, b = blockIdx.z;
  const unsigned short* src = Vbf + ((size_t)b * L_ + s * 64) * DM_ + col;
  float acc = 0.f;
#pragma unroll 8
  for (int l = 0; l < 64; l++) acc += bf2f(src[(size_t)l * DM_]);
  partial[((size_t)b * 64 + s) * DM_ + col] = acc;
}
__global__ __launch_bounds__(256) void vmean_combine(const float* __restrict__ partial,
                                                     float* __restrict__ Vm) {
  const int idx = blockIdx.x * 256 + threadIdx.x;  // 8192
  const int b = idx >> 10, col = idx & 1023;
  float acc = 0.f;
  for (int s = 0; s < 64; s++) acc += partial[((size_t)b * 64 + s) * DM_ + col];
  Vm[idx] = acc * (1.f / (float)L_);
}

// ---------- stage1: MFMA QK^T (swapped), VALU softmax+PV; no-max softmax ----------
__global__ __launch_bounds__(256) void attn_stage1(const unsigned short* __restrict__ Qbf,
    const unsigned short* __restrict__ Kbf, const unsigned short* __restrict__ Vbf,
    float* __restrict__ part) {
  const int bh = blockIdx.x, split = blockIdx.y;
  const int b = bh >> 4, h = bh & 15;
  __shared__ unsigned short sQ[48][72];
  __shared__ unsigned short sK[64][72];
  __shared__ unsigned short sV[64][72];
  __shared__ float es[64][52];
  const int tid = threadIdx.x, wid = tid >> 6, lane = tid & 63;
  const int fr = lane & 15, fq = lane >> 4;
  for (int e = tid; e < 48 * 8; e += 256) {
    const int r = e >> 3, c8 = (e & 7) * 8;
    *(ushort8*)&sQ[r][c8] = *(const ushort8*)&Qbf[((size_t)bh * 48 + r) * 64 + c8];
  }
  __syncthreads();
  short8 qf[3][2];
#pragma unroll
  for (int nt = 0; nt < 3; nt++)
#pragma unroll
    for (int kh = 0; kh < 2; kh++)
      qf[nt][kh] = *(const short8*)&sQ[nt * 16 + fr][kh * 32 + fq * 8];

  float S[12], ctx[12];
#pragma unroll
  for (int i = 0; i < 12; i++) { S[i] = 0.f; ctx[i] = 0.f; }

  for (int t = 0; t < 8; t++) {
    const int k0 = split * 512 + t * 64;
    if (t) __syncthreads();                 // prev tile's es/sV fully consumed
    for (int e = tid; e < 64 * 8; e += 256) {
      const int r = e >> 3, c8 = (e & 7) * 8;
      const size_t gsrc = ((size_t)b * L_ + k0 + r) * DM_ + h * 64 + c8;
      *(ushort8*)&sK[r][c8] = *(const ushort8*)&Kbf[gsrc];
      *(ushort8*)&sV[r][c8] = *(const ushort8*)&Vbf[gsrc];
    }
    __syncthreads();
    short8 kf0 = *(const short8*)&sK[wid * 16 + fr][fq * 8];
    short8 kf1 = *(const short8*)&sK[wid * 16 + fr][32 + fq * 8];
    f32x4 accq[3];
#pragma unroll
    for (int nt = 0; nt < 3; nt++) {
      accq[nt] = f32x4{0.f, 0.f, 0.f, 0.f};
      accq[nt] = __builtin_amdgcn_mfma_f32_16x16x32_bf16(kf0, qf[nt][0], accq[nt], 0, 0, 0);
      accq[nt] = __builtin_amdgcn_mfma_f32_16x16x32_bf16(kf1, qf[nt][1], accq[nt], 0, 0, 0);
    }
#pragma unroll
    for (int nt = 0; nt < 3; nt++)
#pragma unroll
      for (int r = 0; r < 4; r++)
        es[wid * 16 + fq * 4 + r][nt * 16 + fr] = expf(accq[nt][r] * 0.125f);
    __syncthreads();
    const int q0 = wid * 12;
    for (int k = 0; k < 64; k++) {
      const float v = bf2f(sV[k][lane]);
      const float4 e0 = *(const float4*)&es[k][q0];
      const float4 e1 = *(const float4*)&es[k][q0 + 4];
      const float4 e2 = *(const float4*)&es[k][q0 + 8];
      S[0] += e0.x; S[1] += e0.y; S[2]  += e0.z; S[3]  += e0.w;
      S[4] += e1.x; S[5] += e1.y; S[6]  += e1.z; S[7]  += e1.w;
      S[8] += e2.x; S[9] += e2.y; S[10] += e2.z; S[11] += e2.w;
      ctx[0] += e0.x * v; ctx[1] += e0.y * v; ctx[2]  += e0.z * v; ctx[3]  += e0.w * v;
      ctx[4] += e1.x * v; ctx[5] += e1.y * v; ctx[6]  += e1.z * v; ctx[7]  += e1.w * v;
      ctx[8] += e2.x * v; ctx[9] += e2.y * v; ctx[10] += e2.z * v; ctx[11] += e2.w * v;
    }
  }
#pragma unroll
  for (int i = 0; i < 12; i++) {
    const int u = wid * 12 + i;
    if (u < U_) {
      float* pb = part + ((size_t)(bh * NSPLIT + split) * U_ + u) * 65;
      if (lane == 0) pb[0] = S[i];
      pb[1 + lane] = ctx[i];
    }
  }
}

// ---------- combine splits; dctx = ctx/S - Vmean ----------
__global__ __launch_bounds__(256) void attn_stage2(const float* __restrict__ part,
    const float* __restrict__ Vm, float* __restrict__ dctx) {
  const int bh = blockIdx.x;
  const int wid = threadIdx.x >> 6, lane = threadIdx.x & 63;
  for (int u = wid; u < U_; u += 4) {
    float S = 0.f, c = 0.f;
#pragma unroll
    for (int sp = 0; sp < NSPLIT; sp++) {
      const float* pb = part + ((size_t)(bh * NSPLIT + sp) * U_ + u) * 65;
      S += pb[0];
      c += pb[1 + lane];
    }
    dctx[((size_t)bh * U_ + u) * 64 + lane] = c / S - Vm[bh * 64 + lane];
  }
}

// ---------- base[b][:] = concat_h(Vmean) @ Wo + bo ----------
__global__ __launch_bounds__(256) void base_k(const float* __restrict__ Vm,
    const float* __restrict__ Wo, const float* __restrict__ bo, float* __restrict__ base) {
  const int b = blockIdx.y;
  const int j = blockIdx.x * 256 + threadIdx.x;
  float acc = bo[j];
#pragma unroll 8
  for (int i = 0; i < DM_; i++) acc += Vm[b * DM_ + i] * Wo[(size_t)i * DM_ + j];
  base[b * DM_ + j] = acc;
}

// ---------- out[b,l,:] = base[b,:] ----------
__global__ __launch_bounds__(256) void fill_out(const float* __restrict__ base,
                                                float* __restrict__ out) {
  const size_t g = ((size_t)blockIdx.x * 256 + threadIdx.x) * 4;
  const int b = (int)(g >> 22), j = (int)(g & 1023);
  *(float4*)&out[g] = *(const float4*)&base[(b << 10) + j];
}

// ---------- gemm_upd: rowupd[bh][u][:] = dctx[bh] @ Wo_h ----------
__global__ __launch_bounds__(256) void gemm_upd(const float* __restrict__ dctx,
    const float* __restrict__ Wo, float* __restrict__ rowupd) {
  const int bh = blockIdx.y, h = bh & 15;
  const int col = blockIdx.x * 256 + threadIdx.x;
  __shared__ float dc[U_][68];
  for (int e = threadIdx.x; e < U_ * 64; e += 256) {
    const int u = e >> 6, d = e & 63;
    dc[u][d] = dctx[(size_t)bh * U_ * 64 + e];
  }
  __syncthreads();
  float acc[U_];
#pragma unroll
  for (int u = 0; u < U_; u++) acc[u] = 0.f;
  for (int d = 0; d < 64; d++) {
    const float w = Wo[(size_t)(h * 64 + d) * DM_ + col];
#pragma unroll
    for (int u = 0; u < U_; u++) acc[u] += dc[u][d] * w;   // dc broadcast read
  }
#pragma unroll
  for (int u = 0; u < U_; u++)
    rowupd[((size_t)bh * U_ + u) * DM_ + col] = acc[u];
}

// ---------- build_list: per selected row, head-mask + slot; unique-row list ----------
__global__ __launch_bounds__(256) void build_list(const int* __restrict__ topidx,
    int* __restrict__ rowmask, unsigned char* __restrict__ slotU,
    int* __restrict__ uniq, int* __restrict__ uniqCnt) {
  const int i = blockIdx.x * 256 + threadIdx.x;
  if (i >= BH_ * U_) return;
  const int bh = i / U_, u = i - bh * U_;
  const int b = bh >> 4, h = bh & 15;
  const int key = b * L_ + topidx[i];
  slotU[key * 16 + h] = (unsigned char)u;
  const int old = atomicOr(&rowmask[key], 1 << h);
  if (old == 0) {
    const int q = atomicAdd(uniqCnt, 1);
    uniq[q] = key;
  }
}

// ---------- scatter3: one block per unique row; fixed h-order sum; plain write ----------
__global__ __launch_bounds__(256) void scatter3(const float* __restrict__ rowupd,
    const float* __restrict__ base, const int* __restrict__ rowmask,
    const unsigned char* __restrict__ slotU, const int* __restrict__ uniq,
    const int* __restrict__ uniqCnt, float* __restrict__ out) {
  const int idx = blockIdx.x;
  if (idx >= *uniqCnt) return;
  const int key = uniq[idx];
  const int b = key >> 12;                       // L_ = 4096
  const int mask = rowmask[key];
  const int j4 = threadIdx.x * 4;
  float4 a = *(const float4*)&base[b * DM_ + j4];
#pragma unroll
  for (int h = 0; h < 16; h++) {
    if (mask & (1 << h)) {
      const int u = slotU[key * 16 + h];
      const float4 r = *(const float4*)&rowupd[((size_t)(b * 16 + h) * U_ + u) * DM_ + j4];
      a.x += r.x; a.y += r.y; a.z += r.z; a.w += r.w;
    }
  }
  *(float4*)&out[(size_t)key * DM_ + j4] = a;
}

extern "C" void kernel_launch(void* const* d_in, const int* in_sizes, int n_in,
                              void* d_out, int out_size, void* d_ws, size_t ws_size,
                              hipStream_t stream) {
  const float* queries = (const float*)d_in[0];
  const float* keys    = (const float*)d_in[1];
  const float* values  = (const float*)d_in[2];
  const float* Wq = (const float*)d_in[3]; const float* bq = (const float*)d_in[4];
  const float* Wk = (const float*)d_in[5]; const float* bk = (const float*)d_in[6];
  const float* Wv = (const float*)d_in[7]; const float* bv = (const float*)d_in[8];
  const float* Wo = (const float*)d_in[9]; const float* bo = (const float*)d_in[10];
  const int* sidx = (const int*)d_in[11];

  // K,V live as bf16 in d_out (67.1 MB each) until the epilogue
  unsigned short* Kbf = (unsigned short*)d_out;
  unsigned short* Vbf = Kbf + (size_t)ML_ * DM_;

  uint8_t* p = (uint8_t*)d_ws;
  auto carve = [&](size_t bytes) { uint8_t* r = p; p += (bytes + 255) & ~(size_t)255; return r; };
  unsigned short* Xqh = (unsigned short*)carve((size_t)CROWS_ * DM_ * 2);   // 33.6 MB
  unsigned short* Xkh = (unsigned short*)carve((size_t)CROWS_ * DM_ * 2);
  unsigned short* Xvh = (unsigned short*)carve((size_t)CROWS_ * DM_ * 2);
  float* QKs = (float*)carve((size_t)CROWS_ * NP_ * 4);                     // 50.3 MB
  unsigned short* Ph = (unsigned short*)carve((size_t)B_ * NP_ * DM_ * 2);  // 12.6 MB
  unsigned short* WkT = (unsigned short*)carve((size_t)DM_ * DM_ * 2);
  unsigned short* WvT = (unsigned short*)carve((size_t)DM_ * DM_ * 2);
  float* Mbuf  = (float*)carve((size_t)BH_ * L_ * 4);                       // 2.1 MB
  float* Ksamp = (float*)carve((size_t)BH_ * U_ * 64 * 4);                  // 1.5 MB
  float* kpart = (float*)carve((size_t)4 * B_ * U_ * 1024 * 4);             // 5.9 MB
  float* qpart = (float*)carve((size_t)16 * BH_ * 48 * 64 * 4);             // 25.2 MB
  int*   list  = (int*)carve((size_t)BH_ * CAP_ * 4);                       // 256 KB
  float* candM = (float*)carve((size_t)BH_ * CAP_ * 4);                     // 256 KB
  int*   cntb  = (int*)carve((size_t)BH_ * 4);
  int*   topidx = (int*)carve((size_t)BH_ * U_ * 4);
  float* Vm    = (float*)carve((size_t)BH_ * 64 * 4);
  unsigned short* Qbf = (unsigned short*)carve((size_t)BH_ * 48 * 64 * 2);  // 786 KB
  int*   rowmask = (int*)carve((size_t)B_ * L_ * 4);                        // 128 KB (memset)
  int*   uniqCnt = (int*)carve(256);                                        // (memset)
  unsigned char* slotU = (unsigned char*)carve((size_t)B_ * L_ * 16);       // 512 KB
  int*   uniq  = (int*)carve((size_t)BH_ * U_ * 4);                         // 23 KB
  const size_t need = (size_t)(p - (uint8_t*)d_ws);
  if (ws_size < need)
    fprintf(stderr, "ATHENA_WS: need %zu have %zu (WILL FAULT)\n", need, ws_size);

  // late-phase buffers alias QKs (dead after mpass)
  uint8_t* ap = (uint8_t*)QKs;
  auto acarve = [&](size_t bytes) { uint8_t* r = ap; ap += (bytes + 255) & ~(size_t)255; return r; };
  float* part  = (float*)acarve((size_t)BH_ * NSPLIT * U_ * 65 * 4);        // 12 MB
  float* dctx  = (float*)acarve((size_t)BH_ * U_ * 64 * 4);
  float* vpart = (float*)acarve((size_t)B_ * 64 * DM_ * 4);                 // 2.1 MB
  float* base  = (float*)acarve((size_t)B_ * DM_ * 4);
  float* rowupd = (float*)acarve((size_t)BH_ * U_ * DM_ * 4);               // 23.6 MB

  ksel3<<<dim3(4, B_, 12), 256, 0, stream>>>(keys, Wk, sidx, kpart);
  ksel_comb<<<(B_ * U_ * 1024) / 256, 256, 0, stream>>>(kpart, bk, Ksamp);
  pform_k<<<BH_, 256, 0, stream>>>(Wq, Ksamp, Ph);
  wT_single<<<4096, 256, 0, stream>>>(Wk, WkT);
  wT_single<<<4096, 256, 0, stream>>>(Wv, WvT);

  const int n4 = (int)((size_t)CROWS_ * DM_ / 4);
  for (int c = 0; c < 2; c++) {
    const size_t off = (size_t)c * CROWS_ * DM_;
    split3h<<<dim3(2048, 3), 256, 0, stream>>>(queries + off, keys + off, values + off,
                                               Xqh, Xkh, Xvh, n4);
    gemm_plain<<<dim3(8, 128), 256, 0, stream>>>(Xkh, WkT, bk, Kbf + off);
    gemm_plain<<<dim3(8, 128), 256, 0, stream>>>(Xvh, WvT, bv, Vbf + off);
    gemm_qk1<<<dim3(6, 128), 256, 0, stream>>>(Xqh, Ph, QKs, c);
    mpass_k<<<(CROWS_ * 16) / 256, 256, 0, stream>>>(QKs, Mbuf, c);
  }

  select_a<<<BH_, 256, 0, stream>>>(Mbuf, list, cntb);
  exactM2<<<dim3(BH_, 16), 256, 0, stream>>>(queries, Wq, bq, Ksamp, list, cntb, candM);
  select_b<<<BH_, 256, 0, stream>>>(candM, list, cntb, topidx);
  qsel3<<<dim3(BH_, 12), 256, 0, stream>>>(queries, Wq, topidx, qpart);
  qsel_comb<<<(BH_ * 48 * 64) / 256, 256, 0, stream>>>(qpart, bq, Qbf);
  vmean_partial<<<dim3(DM_ / 256, 64, B_), 256, 0, stream>>>(Vbf, vpart);
  vmean_combine<<<(B_ * DM_) / 256, 256, 0, stream>>>(vpart, Vm);
  attn_stage1<<<dim3(BH_, NSPLIT), 256, 0, stream>>>(Qbf, Kbf, Vbf, part);
  attn_stage2<<<BH_, 256, 0, stream>>>(part, Vm, dctx);
  base_k<<<dim3(DM_ / 256, B_), 256, 0, stream>>>(Vm, Wo, bo, base);

  // epilogue: deterministic, atomic-free
  hipMemsetAsync(rowmask, 0, (size_t)B_ * L_ * 4 + 256, stream);  // rowmask + uniqCnt
  gemm_upd<<<dim3(4, BH_), 256, 0, stream>>>(dctx, Wo, rowupd);
  build_list<<<(BH_ * U_ + 255) / 256, 256, 0, stream>>>(topidx, rowmask, slotU, uniq, uniqCnt);
  fill_out<<<(int)((size_t)ML_ * DM_ / 4 / 256), 256, 0, stream>>>(base, (float*)d_out);
  scatter3<<<BH_ * U_, 256, 0, stream>>>(rowupd, base, rowmask, slotU, uniq, uniqCnt,
                                         (float*)d_out);
}